// Round 14
// baseline (411.682 us; speedup 1.0000x reference)
//
#include <hip/hip_runtime.h>
#include <hip/hip_bf16.h>
#include <math.h>
#include <stdint.h>

#define B_   4
#define T_   2048
#define D_   1024
#define QH   16
#define KVH  4
#define HD_  64
#define R_   (B_*T_)      // 8192 rows
#define DFF  2048
#define QKVW 1536         // fused q(1024) + kv(512) output width

typedef short short8 __attribute__((ext_vector_type(8)));
typedef short short4v __attribute__((ext_vector_type(4)));
typedef float f32x4 __attribute__((ext_vector_type(4)));

static __device__ __forceinline__ unsigned short f2bu(float x) {
    __hip_bfloat16 h = __float2bfloat16(x);
    return *reinterpret_cast<unsigned short*>(&h);
}

// swizzled byte offset within a 128B/row LDS tile
#define KSWZ(row, cbyte) (((row) << 7) + ((cbyte) ^ (((row) & 7) << 4)))

__device__ __forceinline__ void gload_lds16(const void* g, void* l) {
    typedef __attribute__((address_space(1))) void gv_t;
    typedef __attribute__((address_space(3))) void lv_t;
    __builtin_amdgcn_global_load_lds((gv_t*)g, (lv_t*)l, 16, 0, 0);
}

// ---------------- f32 -> bf16 cast (weights) ----------------
__global__ __launch_bounds__(256) void castw(const float* __restrict__ src,
                                             __hip_bfloat16* __restrict__ dst, int n4) {
    int i = blockIdx.x * 256 + threadIdx.x;
    if (i >= n4) return;
    float4 v = *(const float4*)&src[i*4];
    ushort4 o = { f2bu(v.x), f2bu(v.y), f2bu(v.z), f2bu(v.w) };
    *(ushort4*)&dst[i*4] = o;
}

// ---------------- LayerNorm -> bf16 out: one block per row ----------------
__global__ __launch_bounds__(256) void ln_bf16(const float* __restrict__ x,
                                               const float* __restrict__ g,
                                               const float* __restrict__ bta,
                                               __hip_bfloat16* __restrict__ out) {
    int row = blockIdx.x;
    int tid = threadIdx.x;
    const float* xr = x + (size_t)row * D_;
    int c = tid * 4;
    float4 v = *(const float4*)&xr[c];
    float s = v.x + v.y + v.z + v.w;
#pragma unroll
    for (int off = 32; off >= 1; off >>= 1) s += __shfl_xor(s, off);
    __shared__ float sm[4], sv[4];
    int wid = tid >> 6, lane = tid & 63;
    if (lane == 0) sm[wid] = s;
    __syncthreads();
    float mean = (sm[0] + sm[1] + sm[2] + sm[3]) * (1.0f / D_);
    float d0 = v.x - mean, d1 = v.y - mean, d2 = v.z - mean, d3 = v.w - mean;
    float qq = d0*d0 + d1*d1 + d2*d2 + d3*d3;
#pragma unroll
    for (int off = 32; off >= 1; off >>= 1) qq += __shfl_xor(qq, off);
    if (lane == 0) sv[wid] = qq;
    __syncthreads();
    float var = (sv[0] + sv[1] + sv[2] + sv[3]) * (1.0f / D_);
    float rstd = rsqrtf(var + 1e-5f);
    float4 gg = *(const float4*)&g[c];
    float4 bb = *(const float4*)&bta[c];
    ushort4 o = { f2bu(d0 * rstd * gg.x + bb.x),
                  f2bu(d1 * rstd * gg.y + bb.y),
                  f2bu(d2 * rstd * gg.z + bb.z),
                  f2bu(d3 * rstd * gg.w + bb.w) };
    *(ushort4*)&(out + (size_t)row * D_)[c] = o;
}

// ---------------- bf16 MFMA GEMM: C = res + act(A(MxK) * W(NxK)^T + bias) ----------------
// MODE: 0 plain f32 out; 1 +res f32; 2 +bias,gelu -> bf16; 3 +bias,+res f32
template<int MODE>
__global__ __launch_bounds__(256) void gemm_mfma(const __hip_bfloat16* __restrict__ A,
                                                 const __hip_bfloat16* __restrict__ W,
                                                 const float* __restrict__ bias,
                                                 const float* __restrict__ res,
                                                 float* __restrict__ Cf,
                                                 __hip_bfloat16* __restrict__ Cb,
                                                 int M, int N, int K) {
    __shared__ __hip_bfloat16 At[128*32];
    __shared__ __hip_bfloat16 Bt[128*32];
    int tid = threadIdx.x;
    int w = tid >> 6, lane = tid & 63;
    int l15 = lane & 15, lhi = lane >> 4;
    int bm = blockIdx.y * 128, bn = blockIdx.x * 128;
    int wr = w >> 1, wc = w & 1;
    f32x4 acc[4][4] = {};

    for (int k0 = 0; k0 < K; k0 += 32) {
#pragma unroll
        for (int iss = 0; iss < 2; ++iss) {
            int off = (iss*256 + tid) * 8;     // element offset in 128x32 tile
            int row = off >> 5, col = off & 31;
            gload_lds16(A + (size_t)(bm + row) * K + k0 + col, &At[off]);
            gload_lds16(W + (size_t)(bn + row) * K + k0 + col, &Bt[off]);
        }
        __syncthreads();
        short8 af[4], bf[4];
#pragma unroll
        for (int m = 0; m < 4; ++m) af[m] = *(const short8*)&At[(wr*64 + m*16 + l15)*32 + lhi*8];
#pragma unroll
        for (int n = 0; n < 4; ++n) bf[n] = *(const short8*)&Bt[(wc*64 + n*16 + l15)*32 + lhi*8];
#pragma unroll
        for (int m = 0; m < 4; ++m)
#pragma unroll
            for (int n = 0; n < 4; ++n)
                acc[m][n] = __builtin_amdgcn_mfma_f32_16x16x32_bf16(af[m], bf[n], acc[m][n], 0, 0, 0);
        __syncthreads();
    }

#pragma unroll
    for (int m = 0; m < 4; ++m) {
#pragma unroll
        for (int j = 0; j < 4; ++j) {
            int row = bm + wr*64 + m*16 + lhi*4 + j;
#pragma unroll
            for (int n = 0; n < 4; ++n) {
                int col = bn + wc*64 + n*16 + l15;
                float val = acc[m][n][j];
                if (MODE == 2 || MODE == 3) val += bias[col];
                if (MODE == 2) val = 0.5f * val * (1.0f + erff(val * 0.70710678118654752f));
                if (MODE == 1 || MODE == 3) val += res[(size_t)row * N + col];
                if (MODE == 2) Cb[(size_t)row * N + col] = __float2bfloat16(val);
                else           Cf[(size_t)row * N + col] = val;
            }
        }
    }
}

// ---------------- RoPE + cast q -> qb bf16 [B*QH][T][HD], pre-scaled by log2e/8 (exp2 domain) ----
__global__ __launch_bounds__(256) void rope_cast_q(const float* __restrict__ qkv,
                                                   const float* __restrict__ cosb,
                                                   const float* __restrict__ sinb,
                                                   __hip_bfloat16* __restrict__ qb) {
    const float QS = 0.125f * 1.44269504088896340736f;
    int idx = blockIdx.x * 256 + threadIdx.x;   // total 64*2048*32
    int d2 = idx & 31;
    int t  = (idx >> 5) & (T_ - 1);
    int bh = idx >> 16;          // 0..63
    int b = bh >> 4, h = bh & 15;
    float c0 = cosb[t*HD_ + 2*d2],     s0 = sinb[t*HD_ + 2*d2];
    float c1 = cosb[t*HD_ + 2*d2 + 1], s1 = sinb[t*HD_ + 2*d2 + 1];
    const float* p = qkv + (size_t)(b*T_ + t) * QKVW + h*HD_ + 2*d2;
    float x0 = p[0], x1 = p[1];
    float r0 = (x0*c0 - x1*s0) * QS;
    float r1 = (x1*c1 + x0*s1) * QS;
    __hip_bfloat16* qo = qb + ((size_t)bh * T_ + t) * HD_ + 2*d2;
    qo[0] = __float2bfloat16(r0);
    qo[1] = __float2bfloat16(r1);
}

// ---------------- RoPE+cast k -> kb [B*KVH][T][HD]; v -> vbt [B*KVH][HD][T] ----------------
__global__ __launch_bounds__(256) void rope_cast_kv(const float* __restrict__ qkv,
                                                    const float* __restrict__ cosb,
                                                    const float* __restrict__ sinb,
                                                    __hip_bfloat16* __restrict__ kb,
                                                    __hip_bfloat16* __restrict__ vbt) {
    int idx = blockIdx.x * 256 + threadIdx.x;   // total 16*2048*32
    int d2 = idx & 31;
    int t  = (idx >> 5) & (T_ - 1);
    int bk = idx >> 16;          // 0..15
    int b = bk >> 2, kh = bk & 3;
    float c0 = cosb[t*HD_ + 2*d2],     s0 = sinb[t*HD_ + 2*d2];
    float c1 = cosb[t*HD_ + 2*d2 + 1], s1 = sinb[t*HD_ + 2*d2 + 1];
    const float* p = qkv + (size_t)(b*T_ + t) * QKVW + 1024 + kh*(2*HD_) + 2*d2;
    float k0 = p[0], k1 = p[1];
    float v0 = p[HD_], v1 = p[HD_ + 1];
    float r0 = k0*c0 - k1*s0;
    float r1 = k1*c1 + k0*s1;
    __hip_bfloat16* ko = kb + ((size_t)bk * T_ + t) * HD_ + 2*d2;
    ko[0] = __float2bfloat16(r0);
    ko[1] = __float2bfloat16(r1);
    vbt[((size_t)bk * HD_ + 2*d2    ) * T_ + t] = __float2bfloat16(v0);
    vbt[((size_t)bk * HD_ + 2*d2 + 1) * T_ + t] = __float2bfloat16(v1);
}

// ---------------- Flash attention: QBLK=64, swapped operands, dbuf prefetch staging ----------------
// QK^T as mfma(K,Q): lane(l15,lhi) holds S[key=cb*16+lhi*4+r][qrow=l15].
// PV as mfma(V^T,P): lane holds O^T[d=cb*16+lhi*4+r][qrow=l15].
// K/V double-buffered, staged via global_load_lds with pre-swizzled SOURCE (linear LDS dest);
// prefetch of tile t+1 issued before computing tile t; one __syncthreads per tile drains vmcnt.
// Softmax in exp2 domain (Q pre-scaled by log2e/8). Ps rows per-wave (same-wave RW, no barrier).
__global__ __launch_bounds__(256) void attn_mfma(const __hip_bfloat16* __restrict__ qb,
                                                 const __hip_bfloat16* __restrict__ kb,
                                                 const __hip_bfloat16* __restrict__ vbt,
                                                 __hip_bfloat16* __restrict__ ob) {
    __shared__ __hip_bfloat16 Ks[2][64*64];   // [key][d]   swizzled, 2x8KB
    __shared__ __hip_bfloat16 Vs[2][64*64];   // [d][key]   swizzled, 2x8KB
    __shared__ __hip_bfloat16 Ps[64*64];      // [qrow][key] swizzled, per-wave rows, 8KB
    char* PsB = (char*)Ps;
    int tid = threadIdx.x;
    int w = tid >> 6, lane = tid & 63;
    int l15 = lane & 15, lhi = lane >> 4;
    int bh = blockIdx.y;
    int b = bh >> 4, h = bh & 15;
    int bk = b * KVH + (h >> 2);
    int qt0 = blockIdx.x * 64;

    const __hip_bfloat16* qrow = qb + ((size_t)bh * T_ + qt0 + w*16 + l15) * HD_;
    short8 qf0 = *(const short8*)(qrow + lhi*8);
    short8 qf1 = *(const short8*)(qrow + 32 + lhi*8);

    f32x4 oacc[4] = {};          // O^T[d=cb*16+lhi*4+r][qrow=l15]
    float m_run = -INFINITY, l_run = 0.0f;

    const __hip_bfloat16* kbase = kb  + (size_t)bk * T_ * HD_;
    const __hip_bfloat16* vbase = vbt + (size_t)bk * HD_ * T_;
    // pre-swizzled source addressing for gload_lds (linear LDS dest = chunk + lane*16)
    int lrow = lane >> 3;                         // row within 8-row chunk
    int sce  = (((lane & 7) * 16) ^ (lrow << 4)) >> 1;  // swizzled source col (elements)

#define STAGE(buf, s0) do { \
    _Pragma("unroll") \
    for (int c = 0; c < 2; ++c) { \
        int rw = (w + 4*c)*8 + lrow; \
        int ldsoff = (w + 4*c)*1024 + lane*16; \
        gload_lds16(kbase + (size_t)((s0) + rw)*HD_ + sce, (char*)Ks[buf] + ldsoff); \
        gload_lds16(vbase + (size_t)rw*T_ + (s0) + sce,    (char*)Vs[buf] + ldsoff); \
    } } while(0)

    STAGE(0, 0);
    __syncthreads();    // drains vmcnt before first compute
    int cur = 0;
    const int NT = T_/64;

    for (int it = 0; it < NT; ++it) {
        if (it + 1 < NT) STAGE(cur^1, (it+1)*64);   // prefetch next tile (other buffer)
        char* KsB = (char*)Ks[cur];
        char* VsB = (char*)Vs[cur];

        // S^T = K Q^T
        f32x4 accs[4];
#pragma unroll
        for (int cb = 0; cb < 4; ++cb) {
            f32x4 z = {0.f, 0.f, 0.f, 0.f};
            short8 k0 = *(const short8*)(KsB + KSWZ(cb*16 + l15, lhi*16));
            short8 k1 = *(const short8*)(KsB + KSWZ(cb*16 + l15, 64 + lhi*16));
            __builtin_amdgcn_s_setprio(1);
            z = __builtin_amdgcn_mfma_f32_16x16x32_bf16(k0, qf0, z, 0, 0, 0);
            z = __builtin_amdgcn_mfma_f32_16x16x32_bf16(k1, qf1, z, 0, 0, 0);
            __builtin_amdgcn_s_setprio(0);
            accs[cb] = z;
        }

        // online softmax (exp2 domain) for q-row l15
        float mx = -INFINITY;
#pragma unroll
        for (int cb = 0; cb < 4; ++cb)
#pragma unroll
            for (int r = 0; r < 4; ++r) mx = fmaxf(mx, accs[cb][r]);
        mx = fmaxf(mx, __shfl_xor(mx, 16));
        mx = fmaxf(mx, __shfl_xor(mx, 32));
        float mn = fmaxf(m_run, mx);
        float cr = exp2f(m_run - mn);
        m_run = mn;
        float rs = 0.0f;
        int pr = w*16 + l15;               // per-wave P row
#pragma unroll
        for (int cb = 0; cb < 4; ++cb) {
            f32x4 p;
#pragma unroll
            for (int r = 0; r < 4; ++r) { p[r] = exp2f(accs[cb][r] - mn); rs += p[r]; }
            short4v pk = { (short)f2bu(p[0]), (short)f2bu(p[1]),
                           (short)f2bu(p[2]), (short)f2bu(p[3]) };
            *(short4v*)(PsB + KSWZ(pr, cb*32 + lhi*8)) = pk;
        }
        rs += __shfl_xor(rs, 16);
        rs += __shfl_xor(rs, 32);
        l_run = l_run * cr + rs;
#pragma unroll
        for (int cb = 0; cb < 4; ++cb)
#pragma unroll
            for (int r = 0; r < 4; ++r) oacc[cb][r] *= cr;
        // no barrier: P write->read is same-wave (lgkmcnt-ordered)

        // O^T += V^T P^T
#pragma unroll
        for (int kk = 0; kk < 2; ++kk) {
            short8 pf = *(const short8*)(PsB + KSWZ(w*16 + l15, kk*64 + lhi*16));
            __builtin_amdgcn_s_setprio(1);
#pragma unroll
            for (int cb = 0; cb < 4; ++cb) {
                short8 vf = *(const short8*)(VsB + KSWZ(cb*16 + l15, kk*64 + lhi*16));
                oacc[cb] = __builtin_amdgcn_mfma_f32_16x16x32_bf16(vf, pf, oacc[cb], 0, 0, 0);
            }
            __builtin_amdgcn_s_setprio(0);
        }
        __syncthreads();   // drains prefetch vmcnt + all waves done with cur tiles
        cur ^= 1;
    }
#undef STAGE

    float inv = 1.0f / l_run;
    int t = qt0 + w*16 + l15;
    __hip_bfloat16* orow = ob + (size_t)(b*T_ + t) * D_ + h*HD_;
#pragma unroll
    for (int cb = 0; cb < 4; ++cb) {
        short4v okv = { (short)f2bu(oacc[cb][0] * inv), (short)f2bu(oacc[cb][1] * inv),
                        (short)f2bu(oacc[cb][2] * inv), (short)f2bu(oacc[cb][3] * inv) };
        *(short4v*)&orow[cb*16 + lhi*4] = okv;
    }
}

extern "C" void kernel_launch(void* const* d_in, const int* in_sizes, int n_in,
                              void* d_out, int out_size, void* d_ws, size_t ws_size,
                              hipStream_t stream) {
    const float* x    = (const float*)d_in[0];
    const float* cosb = (const float*)d_in[1];
    const float* sinb = (const float*)d_in[2];
    const float* Wq   = (const float*)d_in[3];
    const float* Wkv  = (const float*)d_in[4];
    const float* Wo   = (const float*)d_in[5];
    const float* ln1g = (const float*)d_in[6];
    const float* ln1b = (const float*)d_in[7];
    const float* ln2g = (const float*)d_in[8];
    const float* ln2b = (const float*)d_in[9];
    const float* W1   = (const float*)d_in[10];
    const float* b1   = (const float*)d_in[11];
    const float* W2   = (const float*)d_in[12];
    const float* b2   = (const float*)d_in[13];
    float* out = (float*)d_out;

    float* ws = (float*)d_ws;
    const size_t M = 1024 * 1024;
    __hip_bfloat16* hb   = (__hip_bfloat16*)(ws);
    float*          x2   = ws + 4*M;
    float*          qkv  = ws + 12*M;
    __hip_bfloat16* gbuf = (__hip_bfloat16*)(ws + 12*M);
    __hip_bfloat16* ob   = (__hip_bfloat16*)(ws + 20*M);
    __hip_bfloat16* qb   = (__hip_bfloat16*)(ws + 24*M);
    __hip_bfloat16* kbb  = (__hip_bfloat16*)(ws + 28*M);
    __hip_bfloat16* vbt  = (__hip_bfloat16*)(ws + 29*M);
    __hip_bfloat16* Wqkvb= (__hip_bfloat16*)(ws + 30*M);
    __hip_bfloat16* Wob  = (__hip_bfloat16*)(ws + 30*M + 3*M/4);
    __hip_bfloat16* W1b  = (__hip_bfloat16*)(ws + 31*M + M/4);
    __hip_bfloat16* W2b  = (__hip_bfloat16*)(ws + 32*M + M/4);

    // 0. weight casts (bf16)
    castw<<<(1024*1024/4 + 255)/256, 256, 0, stream>>>(Wq,  Wqkvb,              1024*1024/4);
    castw<<<( 512*1024/4 + 255)/256, 256, 0, stream>>>(Wkv, Wqkvb + 1024*1024,   512*1024/4);
    castw<<<(1024*1024/4 + 255)/256, 256, 0, stream>>>(Wo,  Wob,               1024*1024/4);
    castw<<<(2048*1024/4 + 255)/256, 256, 0, stream>>>(W1,  W1b,               2048*1024/4);
    castw<<<(2048*1024/4 + 255)/256, 256, 0, stream>>>(W2,  W2b,               2048*1024/4);

    // 1. LN1 -> hb (bf16)
    ln_bf16<<<R_, 256, 0, stream>>>(x, ln1g, ln1b, hb);
    // 2. qkv = hb @ Wqkvb^T (f32 out)
    gemm_mfma<0><<<dim3(QKVW/128, R_/128), 256, 0, stream>>>(hb, Wqkvb, nullptr, nullptr, qkv, nullptr, R_, QKVW, D_);
    // 3. RoPE + bf16 cast (q in exp2 domain)
    rope_cast_q <<<(R_*QH*32)/256,  256, 0, stream>>>(qkv, cosb, sinb, qb);
    rope_cast_kv<<<(R_*KVH*32)/256, 256, 0, stream>>>(qkv, cosb, sinb, kbb, vbt);
    // 4. attention -> ob (bf16)
    attn_mfma<<<dim3(T_/64, B_*QH), 256, 0, stream>>>(qb, kbb, vbt, ob);
    // 5. x2 = x + ob @ Wob^T
    gemm_mfma<1><<<dim3(D_/128, R_/128), 256, 0, stream>>>(ob, Wob, nullptr, x, x2, nullptr, R_, D_, D_);
    // 6. LN2 -> hb (bf16)
    ln_bf16<<<R_, 256, 0, stream>>>(x2, ln2g, ln2b, hb);
    // 7. gbuf = gelu(hb @ W1b^T + b1) (bf16 out)
    gemm_mfma<2><<<dim3(DFF/128, R_/128), 256, 0, stream>>>(hb, W1b, b1, nullptr, nullptr, gbuf, R_, DFF, D_);
    // 8. out = x2 + gbuf @ W2b^T + b2
    gemm_mfma<3><<<dim3(D_/128, R_/128), 256, 0, stream>>>(gbuf, W2b, b2, x2, out, nullptr, R_, D_, DFF);
}

// Round 15
// 399.844 us; speedup vs baseline: 1.0296x; 1.0296x over previous
//
#include <hip/hip_runtime.h>
#include <hip/hip_bf16.h>
#include <math.h>
#include <stdint.h>

#define B_   4
#define T_   2048
#define D_   1024
#define QH   16
#define KVH  4
#define HD_  64
#define R_   (B_*T_)      // 8192 rows
#define DFF  2048
#define QKVW 1536         // fused q(1024) + kv(512) output width

typedef short short8 __attribute__((ext_vector_type(8)));
typedef short short4v __attribute__((ext_vector_type(4)));
typedef float f32x4 __attribute__((ext_vector_type(4)));

static __device__ __forceinline__ unsigned short f2bu(float x) {
    __hip_bfloat16 h = __float2bfloat16(x);
    return *reinterpret_cast<unsigned short*>(&h);
}

// swizzled byte offset within a [64][64]-bf16 (128B/row) LDS tile
#define KSWZ(row, cbyte) (((row) << 7) + ((cbyte) ^ (((row) & 7) << 4)))

__device__ __forceinline__ void gload_lds16(const void* g, void* l) {
    typedef __attribute__((address_space(1))) void gv_t;
    typedef __attribute__((address_space(3))) void lv_t;
    __builtin_amdgcn_global_load_lds((gv_t*)g, (lv_t*)l, 16, 0, 0);
}

// ---------------- f32 -> bf16 cast (weights) ----------------
__global__ __launch_bounds__(256) void castw(const float* __restrict__ src,
                                             __hip_bfloat16* __restrict__ dst, int n4) {
    int i = blockIdx.x * 256 + threadIdx.x;
    if (i >= n4) return;
    float4 v = *(const float4*)&src[i*4];
    ushort4 o = { f2bu(v.x), f2bu(v.y), f2bu(v.z), f2bu(v.w) };
    *(ushort4*)&dst[i*4] = o;
}

// ---------------- LayerNorm -> bf16 out: one block per row ----------------
__global__ __launch_bounds__(256) void ln_bf16(const float* __restrict__ x,
                                               const float* __restrict__ g,
                                               const float* __restrict__ bta,
                                               __hip_bfloat16* __restrict__ out) {
    int row = blockIdx.x;
    int tid = threadIdx.x;
    const float* xr = x + (size_t)row * D_;
    int c = tid * 4;
    float4 v = *(const float4*)&xr[c];
    float s = v.x + v.y + v.z + v.w;
#pragma unroll
    for (int off = 32; off >= 1; off >>= 1) s += __shfl_xor(s, off);
    __shared__ float sm[4], sv[4];
    int wid = tid >> 6, lane = tid & 63;
    if (lane == 0) sm[wid] = s;
    __syncthreads();
    float mean = (sm[0] + sm[1] + sm[2] + sm[3]) * (1.0f / D_);
    float d0 = v.x - mean, d1 = v.y - mean, d2 = v.z - mean, d3 = v.w - mean;
    float qq = d0*d0 + d1*d1 + d2*d2 + d3*d3;
#pragma unroll
    for (int off = 32; off >= 1; off >>= 1) qq += __shfl_xor(qq, off);
    if (lane == 0) sv[wid] = qq;
    __syncthreads();
    float var = (sv[0] + sv[1] + sv[2] + sv[3]) * (1.0f / D_);
    float rstd = rsqrtf(var + 1e-5f);
    float4 gg = *(const float4*)&g[c];
    float4 bb = *(const float4*)&bta[c];
    ushort4 o = { f2bu(d0 * rstd * gg.x + bb.x),
                  f2bu(d1 * rstd * gg.y + bb.y),
                  f2bu(d2 * rstd * gg.z + bb.z),
                  f2bu(d3 * rstd * gg.w + bb.w) };
    *(ushort4*)&(out + (size_t)row * D_)[c] = o;
}

// ---------------- bf16 MFMA GEMM: C = res + act(A(MxK) * W(NxK)^T + bias) ----------------
// MODE: 0 plain f32 out; 1 +res f32; 2 +bias,gelu -> bf16; 3 +bias,+res f32
template<int MODE>
__global__ __launch_bounds__(256) void gemm_mfma(const __hip_bfloat16* __restrict__ A,
                                                 const __hip_bfloat16* __restrict__ W,
                                                 const float* __restrict__ bias,
                                                 const float* __restrict__ res,
                                                 float* __restrict__ Cf,
                                                 __hip_bfloat16* __restrict__ Cb,
                                                 int M, int N, int K) {
    __shared__ __hip_bfloat16 At[128*32];
    __shared__ __hip_bfloat16 Bt[128*32];
    int tid = threadIdx.x;
    int w = tid >> 6, lane = tid & 63;
    int l15 = lane & 15, lhi = lane >> 4;
    int bm = blockIdx.y * 128, bn = blockIdx.x * 128;
    int wr = w >> 1, wc = w & 1;
    f32x4 acc[4][4] = {};

    for (int k0 = 0; k0 < K; k0 += 32) {
#pragma unroll
        for (int iss = 0; iss < 2; ++iss) {
            int off = (iss*256 + tid) * 8;     // element offset in 128x32 tile
            int row = off >> 5, col = off & 31;
            gload_lds16(A + (size_t)(bm + row) * K + k0 + col, &At[off]);
            gload_lds16(W + (size_t)(bn + row) * K + k0 + col, &Bt[off]);
        }
        __syncthreads();
        short8 af[4], bf[4];
#pragma unroll
        for (int m = 0; m < 4; ++m) af[m] = *(const short8*)&At[(wr*64 + m*16 + l15)*32 + lhi*8];
#pragma unroll
        for (int n = 0; n < 4; ++n) bf[n] = *(const short8*)&Bt[(wc*64 + n*16 + l15)*32 + lhi*8];
#pragma unroll
        for (int m = 0; m < 4; ++m)
#pragma unroll
            for (int n = 0; n < 4; ++n)
                acc[m][n] = __builtin_amdgcn_mfma_f32_16x16x32_bf16(af[m], bf[n], acc[m][n], 0, 0, 0);
        __syncthreads();
    }

#pragma unroll
    for (int m = 0; m < 4; ++m) {
#pragma unroll
        for (int j = 0; j < 4; ++j) {
            int row = bm + wr*64 + m*16 + lhi*4 + j;
#pragma unroll
            for (int n = 0; n < 4; ++n) {
                int col = bn + wc*64 + n*16 + l15;
                float val = acc[m][n][j];
                if (MODE == 2 || MODE == 3) val += bias[col];
                if (MODE == 2) val = 0.5f * val * (1.0f + erff(val * 0.70710678118654752f));
                if (MODE == 1 || MODE == 3) val += res[(size_t)row * N + col];
                if (MODE == 2) Cb[(size_t)row * N + col] = __float2bfloat16(val);
                else           Cf[(size_t)row * N + col] = val;
            }
        }
    }
}

// ---------------- RoPE + cast q (from fused qkv f32) -> qb bf16 [B*QH][T][HD], pre-scaled 1/8 ----
__global__ __launch_bounds__(256) void rope_cast_q(const float* __restrict__ qkv,
                                                   const float* __restrict__ cosb,
                                                   const float* __restrict__ sinb,
                                                   __hip_bfloat16* __restrict__ qb) {
    int idx = blockIdx.x * 256 + threadIdx.x;   // total 64*2048*32
    int d2 = idx & 31;
    int t  = (idx >> 5) & (T_ - 1);
    int bh = idx >> 16;          // 0..63
    int b = bh >> 4, h = bh & 15;
    float c0 = cosb[t*HD_ + 2*d2],     s0 = sinb[t*HD_ + 2*d2];
    float c1 = cosb[t*HD_ + 2*d2 + 1], s1 = sinb[t*HD_ + 2*d2 + 1];
    const float* p = qkv + (size_t)(b*T_ + t) * QKVW + h*HD_ + 2*d2;
    float x0 = p[0], x1 = p[1];
    float r0 = (x0*c0 - x1*s0) * 0.125f;
    float r1 = (x1*c1 + x0*s1) * 0.125f;
    __hip_bfloat16* qo = qb + ((size_t)bh * T_ + t) * HD_ + 2*d2;
    qo[0] = __float2bfloat16(r0);
    qo[1] = __float2bfloat16(r1);
}

// ---------------- RoPE+cast k -> kb [B*KVH][T][HD]; v -> vbt [B*KVH][HD][T] ----------------
__global__ __launch_bounds__(256) void rope_cast_kv(const float* __restrict__ qkv,
                                                    const float* __restrict__ cosb,
                                                    const float* __restrict__ sinb,
                                                    __hip_bfloat16* __restrict__ kb,
                                                    __hip_bfloat16* __restrict__ vbt) {
    int idx = blockIdx.x * 256 + threadIdx.x;   // total 16*2048*32
    int d2 = idx & 31;
    int t  = (idx >> 5) & (T_ - 1);
    int bk = idx >> 16;          // 0..15
    int b = bk >> 2, kh = bk & 3;
    float c0 = cosb[t*HD_ + 2*d2],     s0 = sinb[t*HD_ + 2*d2];
    float c1 = cosb[t*HD_ + 2*d2 + 1], s1 = sinb[t*HD_ + 2*d2 + 1];
    const float* p = qkv + (size_t)(b*T_ + t) * QKVW + 1024 + kh*(2*HD_) + 2*d2;
    float k0 = p[0], k1 = p[1];
    float v0 = p[HD_], v1 = p[HD_ + 1];
    float r0 = k0*c0 - k1*s0;
    float r1 = k1*c1 + k0*s1;
    __hip_bfloat16* ko = kb + ((size_t)bk * T_ + t) * HD_ + 2*d2;
    ko[0] = __float2bfloat16(r0);
    ko[1] = __float2bfloat16(r1);
    vbt[((size_t)bk * HD_ + 2*d2    ) * T_ + t] = __float2bfloat16(v0);
    vbt[((size_t)bk * HD_ + 2*d2 + 1) * T_ + t] = __float2bfloat16(v1);
}

// ---------------- Flash attention: R10 structure + T13 defer-max ----------------
// QBLK=64 (4 waves x 16 q-rows), KVBLK=64, swapped MFMA operands, swizzled LDS.
// QK^T as mfma(K,Q): lane(l15,lhi) holds S[key=cb*16+lhi*4+r][qrow=l15].
// PV as mfma(V^T,P): lane holds O^T[d=cb*16+lhi*4+r][qrow=l15].
// Defer-max (THR=8): keep m_run fixed while tile-max <= m_run+8 (P bounded by e^8,
// exact softmax by shift invariance); rescale path only when bound exceeded.
__global__ __launch_bounds__(256) void attn_mfma(const __hip_bfloat16* __restrict__ qb,
                                                 const __hip_bfloat16* __restrict__ kb,
                                                 const __hip_bfloat16* __restrict__ vbt,
                                                 __hip_bfloat16* __restrict__ ob) {
    __shared__ __hip_bfloat16 Ks[64*64];   // [key][d]   swizzled
    __shared__ __hip_bfloat16 Vs[64*64];   // [d][key]   swizzled
    __shared__ __hip_bfloat16 Ps[64*64];   // [qrow][key] swizzled, per-wave rows
    char* KsB = (char*)Ks; char* VsB = (char*)Vs; char* PsB = (char*)Ps;
    int tid = threadIdx.x;
    int w = tid >> 6, lane = tid & 63;
    int l15 = lane & 15, lhi = lane >> 4;
    int bh = blockIdx.y;
    int b = bh >> 4, h = bh & 15;
    int bk = b * KVH + (h >> 2);
    int qt0 = blockIdx.x * 64;

    const __hip_bfloat16* qrow = qb + ((size_t)bh * T_ + qt0 + w*16 + l15) * HD_;
    short8 qf0 = *(const short8*)(qrow + lhi*8);
    short8 qf1 = *(const short8*)(qrow + 32 + lhi*8);

    f32x4 oacc[4] = {};          // O^T[d=cb*16+lhi*4+r][qrow=l15]
    float m_run = -INFINITY, l_run = 0.0f;

    int sr = tid >> 2;                 // staging row 0..63
    int scB = (tid & 3) * 32;          // staging col byte {0,32,64,96}
    const __hip_bfloat16* kbase = kb  + (size_t)bk * T_ * HD_;
    const __hip_bfloat16* vbase = vbt + (size_t)bk * HD_ * T_;
    int sce = (tid & 3) * 16;          // element offset for global side

    for (int s0 = 0; s0 < T_; s0 += 64) {
        *(short8*)(KsB + KSWZ(sr, scB))      = *(const short8*)(kbase + (size_t)(s0+sr)*HD_ + sce);
        *(short8*)(KsB + KSWZ(sr, scB + 16)) = *(const short8*)(kbase + (size_t)(s0+sr)*HD_ + sce + 8);
        *(short8*)(VsB + KSWZ(sr, scB))      = *(const short8*)(vbase + (size_t)sr*T_ + s0 + sce);
        *(short8*)(VsB + KSWZ(sr, scB + 16)) = *(const short8*)(vbase + (size_t)sr*T_ + s0 + sce + 8);
        __syncthreads();

        // S^T = K Q^T
        f32x4 accs[4];
#pragma unroll
        for (int cb = 0; cb < 4; ++cb) {
            f32x4 z = {0.f, 0.f, 0.f, 0.f};
            short8 k0 = *(const short8*)(KsB + KSWZ(cb*16 + l15, lhi*16));
            short8 k1 = *(const short8*)(KsB + KSWZ(cb*16 + l15, 64 + lhi*16));
            z = __builtin_amdgcn_mfma_f32_16x16x32_bf16(k0, qf0, z, 0, 0, 0);
            z = __builtin_amdgcn_mfma_f32_16x16x32_bf16(k1, qf1, z, 0, 0, 0);
            accs[cb] = z;
        }

        // tile max for q-row l15 (16 lane-local scores; lhi groups partition keys)
        float mx = -INFINITY;
#pragma unroll
        for (int cb = 0; cb < 4; ++cb)
#pragma unroll
            for (int r = 0; r < 4; ++r) mx = fmaxf(mx, accs[cb][r]);
        mx = fmaxf(mx, __shfl_xor(mx, 16));
        mx = fmaxf(mx, __shfl_xor(mx, 32));

        // defer-max: rescale only when tile max exceeds m_run + 8
        if (!__all(mx <= m_run + 8.0f)) {
            float mn = fmaxf(m_run, mx);
            float cr = __expf(m_run - mn);
            m_run = mn;
            l_run *= cr;
#pragma unroll
            for (int cb = 0; cb < 4; ++cb)
#pragma unroll
                for (int r = 0; r < 4; ++r) oacc[cb][r] *= cr;
        }

        float rs = 0.0f;
        int pr = w*16 + l15;               // per-wave P row
#pragma unroll
        for (int cb = 0; cb < 4; ++cb) {
            f32x4 p;
#pragma unroll
            for (int r = 0; r < 4; ++r) { p[r] = __expf(accs[cb][r] - m_run); rs += p[r]; }
            short4v pk = { (short)f2bu(p[0]), (short)f2bu(p[1]),
                           (short)f2bu(p[2]), (short)f2bu(p[3]) };
            *(short4v*)(PsB + KSWZ(pr, cb*32 + lhi*8)) = pk;
        }
        rs += __shfl_xor(rs, 16);
        rs += __shfl_xor(rs, 32);
        l_run += rs;
        // no barrier needed: P write->read is same-wave (lgkmcnt-ordered)

        // O^T += V^T P^T
#pragma unroll
        for (int kk = 0; kk < 2; ++kk) {
            short8 pf = *(const short8*)(PsB + KSWZ(w*16 + l15, kk*64 + lhi*16));
#pragma unroll
            for (int cb = 0; cb < 4; ++cb) {
                short8 vf = *(const short8*)(VsB + KSWZ(cb*16 + l15, kk*64 + lhi*16));
                oacc[cb] = __builtin_amdgcn_mfma_f32_16x16x32_bf16(vf, pf, oacc[cb], 0, 0, 0);
            }
        }
        __syncthreads();   // all waves done with Ks/Vs before restage
    }

    float inv = 1.0f / l_run;
    int t = qt0 + w*16 + l15;
    __hip_bfloat16* orow = ob + (size_t)(b*T_ + t) * D_ + h*HD_;
#pragma unroll
    for (int cb = 0; cb < 4; ++cb) {
        short4v okv = { (short)f2bu(oacc[cb][0] * inv), (short)f2bu(oacc[cb][1] * inv),
                        (short)f2bu(oacc[cb][2] * inv), (short)f2bu(oacc[cb][3] * inv) };
        *(short4v*)&orow[cb*16 + lhi*4] = okv;
    }
}

extern "C" void kernel_launch(void* const* d_in, const int* in_sizes, int n_in,
                              void* d_out, int out_size, void* d_ws, size_t ws_size,
                              hipStream_t stream) {
    const float* x    = (const float*)d_in[0];
    const float* cosb = (const float*)d_in[1];
    const float* sinb = (const float*)d_in[2];
    const float* Wq   = (const float*)d_in[3];
    const float* Wkv  = (const float*)d_in[4];
    const float* Wo   = (const float*)d_in[5];
    const float* ln1g = (const float*)d_in[6];
    const float* ln1b = (const float*)d_in[7];
    const float* ln2g = (const float*)d_in[8];
    const float* ln2b = (const float*)d_in[9];
    const float* W1   = (const float*)d_in[10];
    const float* b1   = (const float*)d_in[11];
    const float* W2   = (const float*)d_in[12];
    const float* b2   = (const float*)d_in[13];
    float* out = (float*)d_out;

    float* ws = (float*)d_ws;
    const size_t M = 1024 * 1024;
    __hip_bfloat16* hb   = (__hip_bfloat16*)(ws);
    float*          x2   = ws + 4*M;
    float*          qkv  = ws + 12*M;
    __hip_bfloat16* gbuf = (__hip_bfloat16*)(ws + 12*M);
    __hip_bfloat16* ob   = (__hip_bfloat16*)(ws + 20*M);
    __hip_bfloat16* qb   = (__hip_bfloat16*)(ws + 24*M);
    __hip_bfloat16* kbb  = (__hip_bfloat16*)(ws + 28*M);
    __hip_bfloat16* vbt  = (__hip_bfloat16*)(ws + 29*M);
    __hip_bfloat16* Wqkvb= (__hip_bfloat16*)(ws + 30*M);
    __hip_bfloat16* Wob  = (__hip_bfloat16*)(ws + 30*M + 3*M/4);
    __hip_bfloat16* W1b  = (__hip_bfloat16*)(ws + 31*M + M/4);
    __hip_bfloat16* W2b  = (__hip_bfloat16*)(ws + 32*M + M/4);

    // 0. weight casts (bf16)
    castw<<<(1024*1024/4 + 255)/256, 256, 0, stream>>>(Wq,  Wqkvb,              1024*1024/4);
    castw<<<( 512*1024/4 + 255)/256, 256, 0, stream>>>(Wkv, Wqkvb + 1024*1024,   512*1024/4);
    castw<<<(1024*1024/4 + 255)/256, 256, 0, stream>>>(Wo,  Wob,               1024*1024/4);
    castw<<<(2048*1024/4 + 255)/256, 256, 0, stream>>>(W1,  W1b,               2048*1024/4);
    castw<<<(2048*1024/4 + 255)/256, 256, 0, stream>>>(W2,  W2b,               2048*1024/4);

    // 1. LN1 -> hb (bf16)
    ln_bf16<<<R_, 256, 0, stream>>>(x, ln1g, ln1b, hb);
    // 2. qkv = hb @ Wqkvb^T (f32 out)
    gemm_mfma<0><<<dim3(QKVW/128, R_/128), 256, 0, stream>>>(hb, Wqkvb, nullptr, nullptr, qkv, nullptr, R_, QKVW, D_);
    // 3. RoPE + bf16 cast
    rope_cast_q <<<(R_*QH*32)/256,  256, 0, stream>>>(qkv, cosb, sinb, qb);
    rope_cast_kv<<<(R_*KVH*32)/256, 256, 0, stream>>>(qkv, cosb, sinb, kbb, vbt);
    // 4. attention -> ob (bf16)
    attn_mfma<<<dim3(T_/64, B_*QH), 256, 0, stream>>>(qb, kbb, vbt, ob);
    // 5. x2 = x + ob @ Wob^T
    gemm_mfma<1><<<dim3(D_/128, R_/128), 256, 0, stream>>>(ob, Wob, nullptr, x, x2, nullptr, R_, D_, D_);
    // 6. LN2 -> hb (bf16)
    ln_bf16<<<R_, 256, 0, stream>>>(x2, ln2g, ln2b, hb);
    // 7. gbuf = gelu(hb @ W1b^T + b1) (bf16 out)
    gemm_mfma<2><<<dim3(DFF/128, R_/128), 256, 0, stream>>>(hb, W1b, b1, nullptr, nullptr, gbuf, R_, DFF, D_);
    // 8. out = x2 + gbuf @ W2b^T + b2
    gemm_mfma<3><<<dim3(D_/128, R_/128), 256, 0, stream>>>(gbuf, W2b, b2, x2, out, nullptr, R_, D_, DFF);
}

// Round 16
// 379.696 us; speedup vs baseline: 1.0842x; 1.0531x over previous
//
#include <hip/hip_runtime.h>
#include <hip/hip_bf16.h>
#include <math.h>
#include <stdint.h>

#define B_   4
#define T_   2048
#define D_   1024
#define QH   16
#define KVH  4
#define HD_  64
#define R_   (B_*T_)      // 8192 rows
#define DFF  2048
#define QKVW 1536         // fused q(1024) + kv(512) output width

typedef short short8 __attribute__((ext_vector_type(8)));
typedef short short4v __attribute__((ext_vector_type(4)));
typedef float f32x4 __attribute__((ext_vector_type(4)));

static __device__ __forceinline__ unsigned short f2bu(float x) {
    __hip_bfloat16 h = __float2bfloat16(x);
    return *reinterpret_cast<unsigned short*>(&h);
}

// swizzled byte offset within a [64][64]-bf16 (128B/row) LDS tile
#define KSWZ(row, cbyte) (((row) << 7) + ((cbyte) ^ (((row) & 7) << 4)))

__device__ __forceinline__ void gload_lds16(const void* g, void* l) {
    typedef __attribute__((address_space(1))) void gv_t;
    typedef __attribute__((address_space(3))) void lv_t;
    __builtin_amdgcn_global_load_lds((gv_t*)g, (lv_t*)l, 16, 0, 0);
}

// ---------------- f32 -> bf16 cast (weights) ----------------
__global__ __launch_bounds__(256) void castw(const float* __restrict__ src,
                                             __hip_bfloat16* __restrict__ dst, int n4) {
    int i = blockIdx.x * 256 + threadIdx.x;
    if (i >= n4) return;
    float4 v = *(const float4*)&src[i*4];
    ushort4 o = { f2bu(v.x), f2bu(v.y), f2bu(v.z), f2bu(v.w) };
    *(ushort4*)&dst[i*4] = o;
}

// ---------------- LayerNorm -> bf16 out: one block per row ----------------
__global__ __launch_bounds__(256) void ln_bf16(const float* __restrict__ x,
                                               const float* __restrict__ g,
                                               const float* __restrict__ bta,
                                               __hip_bfloat16* __restrict__ out) {
    int row = blockIdx.x;
    int tid = threadIdx.x;
    const float* xr = x + (size_t)row * D_;
    int c = tid * 4;
    float4 v = *(const float4*)&xr[c];
    float s = v.x + v.y + v.z + v.w;
#pragma unroll
    for (int off = 32; off >= 1; off >>= 1) s += __shfl_xor(s, off);
    __shared__ float sm[4], sv[4];
    int wid = tid >> 6, lane = tid & 63;
    if (lane == 0) sm[wid] = s;
    __syncthreads();
    float mean = (sm[0] + sm[1] + sm[2] + sm[3]) * (1.0f / D_);
    float d0 = v.x - mean, d1 = v.y - mean, d2 = v.z - mean, d3 = v.w - mean;
    float qq = d0*d0 + d1*d1 + d2*d2 + d3*d3;
#pragma unroll
    for (int off = 32; off >= 1; off >>= 1) qq += __shfl_xor(qq, off);
    if (lane == 0) sv[wid] = qq;
    __syncthreads();
    float var = (sv[0] + sv[1] + sv[2] + sv[3]) * (1.0f / D_);
    float rstd = rsqrtf(var + 1e-5f);
    float4 gg = *(const float4*)&g[c];
    float4 bb = *(const float4*)&bta[c];
    ushort4 o = { f2bu(d0 * rstd * gg.x + bb.x),
                  f2bu(d1 * rstd * gg.y + bb.y),
                  f2bu(d2 * rstd * gg.z + bb.z),
                  f2bu(d3 * rstd * gg.w + bb.w) };
    *(ushort4*)&(out + (size_t)row * D_)[c] = o;
}

// ---------------- bf16 MFMA GEMM: C = res + act(A(MxK) * W(NxK)^T + bias) ----------------
// MODE: 1 +res f32; 2 +bias,gelu -> bf16; 3 +bias,+res f32
template<int MODE>
__global__ __launch_bounds__(256) void gemm_mfma(const __hip_bfloat16* __restrict__ A,
                                                 const __hip_bfloat16* __restrict__ W,
                                                 const float* __restrict__ bias,
                                                 const float* __restrict__ res,
                                                 float* __restrict__ Cf,
                                                 __hip_bfloat16* __restrict__ Cb,
                                                 int M, int N, int K) {
    __shared__ __hip_bfloat16 At[128*32];
    __shared__ __hip_bfloat16 Bt[128*32];
    int tid = threadIdx.x;
    int w = tid >> 6, lane = tid & 63;
    int l15 = lane & 15, lhi = lane >> 4;
    int bm = blockIdx.y * 128, bn = blockIdx.x * 128;
    int wr = w >> 1, wc = w & 1;
    f32x4 acc[4][4] = {};

    for (int k0 = 0; k0 < K; k0 += 32) {
#pragma unroll
        for (int iss = 0; iss < 2; ++iss) {
            int off = (iss*256 + tid) * 8;     // element offset in 128x32 tile
            int row = off >> 5, col = off & 31;
            gload_lds16(A + (size_t)(bm + row) * K + k0 + col, &At[off]);
            gload_lds16(W + (size_t)(bn + row) * K + k0 + col, &Bt[off]);
        }
        __syncthreads();
        short8 af[4], bf[4];
#pragma unroll
        for (int m = 0; m < 4; ++m) af[m] = *(const short8*)&At[(wr*64 + m*16 + l15)*32 + lhi*8];
#pragma unroll
        for (int n = 0; n < 4; ++n) bf[n] = *(const short8*)&Bt[(wc*64 + n*16 + l15)*32 + lhi*8];
#pragma unroll
        for (int m = 0; m < 4; ++m)
#pragma unroll
            for (int n = 0; n < 4; ++n)
                acc[m][n] = __builtin_amdgcn_mfma_f32_16x16x32_bf16(af[m], bf[n], acc[m][n], 0, 0, 0);
        __syncthreads();
    }

#pragma unroll
    for (int m = 0; m < 4; ++m) {
#pragma unroll
        for (int j = 0; j < 4; ++j) {
            int row = bm + wr*64 + m*16 + lhi*4 + j;
#pragma unroll
            for (int n = 0; n < 4; ++n) {
                int col = bn + wc*64 + n*16 + l15;
                float val = acc[m][n][j];
                if (MODE == 2 || MODE == 3) val += bias[col];
                if (MODE == 2) val = 0.5f * val * (1.0f + erff(val * 0.70710678118654752f));
                if (MODE == 1 || MODE == 3) val += res[(size_t)row * N + col];
                if (MODE == 2) Cb[(size_t)row * N + col] = __float2bfloat16(val);
                else           Cf[(size_t)row * N + col] = val;
            }
        }
    }
}

// ---------------- QKV GEMM with fused RoPE epilogue ----------------
// qkv = hb @ Wqkvb^T (M=R_, N=1536, K=1024). Epilogue routes:
//   cols [0,1024): q -> rope, scale 1/8 -> qb [B*QH][T][HD]
//   cols [1024,1536) wc==0: k -> rope -> kbb [B*KVH][T][HD]
//   cols [1024,1536) wc==1: v -> vbt [B*KVH][HD][T] (packed short4 over 4 rows)
// RoPE pairs are adjacent cols = adjacent l15 lanes: partner via __shfl_xor(val,1).
__global__ __launch_bounds__(256) void gemm_qkv_rope(const __hip_bfloat16* __restrict__ A,
                                                     const __hip_bfloat16* __restrict__ W,
                                                     const float* __restrict__ cosb,
                                                     const float* __restrict__ sinb,
                                                     __hip_bfloat16* __restrict__ qb,
                                                     __hip_bfloat16* __restrict__ kbb,
                                                     __hip_bfloat16* __restrict__ vbt) {
    const int N = QKVW, K = D_;
    __shared__ __hip_bfloat16 At[128*32];
    __shared__ __hip_bfloat16 Bt[128*32];
    int tid = threadIdx.x;
    int w = tid >> 6, lane = tid & 63;
    int l15 = lane & 15, lhi = lane >> 4;
    int bm = blockIdx.y * 128, bn = blockIdx.x * 128;
    int wr = w >> 1, wc = w & 1;
    f32x4 acc[4][4] = {};

    for (int k0 = 0; k0 < K; k0 += 32) {
#pragma unroll
        for (int iss = 0; iss < 2; ++iss) {
            int off = (iss*256 + tid) * 8;
            int row = off >> 5, col = off & 31;
            gload_lds16(A + (size_t)(bm + row) * K + k0 + col, &At[off]);
            gload_lds16(W + (size_t)(bn + row) * K + k0 + col, &Bt[off]);
        }
        __syncthreads();
        short8 af[4], bf[4];
#pragma unroll
        for (int m = 0; m < 4; ++m) af[m] = *(const short8*)&At[(wr*64 + m*16 + l15)*32 + lhi*8];
#pragma unroll
        for (int n = 0; n < 4; ++n) bf[n] = *(const short8*)&Bt[(wc*64 + n*16 + l15)*32 + lhi*8];
#pragma unroll
        for (int m = 0; m < 4; ++m)
#pragma unroll
            for (int n = 0; n < 4; ++n)
                acc[m][n] = __builtin_amdgcn_mfma_f32_16x16x32_bf16(af[m], bf[n], acc[m][n], 0, 0, 0);
        __syncthreads();
    }

    bool is_q = (bn < 1024);
    bool is_v = (!is_q) && (wc == 1);   // wave-uniform
    if (!is_v) {
        // q or k: rope
#pragma unroll
        for (int m = 0; m < 4; ++m) {
#pragma unroll
            for (int j = 0; j < 4; ++j) {
                int row = bm + wr*64 + m*16 + lhi*4 + j;
                int b = row >> 11, t = row & (T_ - 1);
                const float* crow = cosb + t*HD_;
                const float* srow = sinb + t*HD_;
#pragma unroll
                for (int n = 0; n < 4; ++n) {
                    int col = bn + wc*64 + n*16 + l15;
                    int hd = n*16 + l15;
                    float val = acc[m][n][j];
                    float part = __shfl_xor(val, 1);
                    float rot = (l15 & 1) ? part : -part;
                    float o = val * crow[hd] + rot * srow[hd];
                    if (is_q) {
                        int h = col >> 6;
                        qb[(((size_t)(b*QH + h))*T_ + t)*HD_ + hd] = __float2bfloat16(o * 0.125f);
                    } else {
                        int kvh = (col - 1024) >> 7;
                        kbb[(((size_t)(b*KVH + kvh))*T_ + t)*HD_ + hd] = __float2bfloat16(o);
                    }
                }
            }
        }
    } else {
        // v: transpose-pack 4 consecutive rows (j) per (m,n)
#pragma unroll
        for (int m = 0; m < 4; ++m) {
            int row0 = bm + wr*64 + m*16 + lhi*4;
            int b = row0 >> 11, t0 = row0 & (T_ - 1);
#pragma unroll
            for (int n = 0; n < 4; ++n) {
                int col = bn + 64 + n*16 + l15;
                int kvh = (col - 1024) >> 7;
                int hd = n*16 + l15;
                short4v pk = { (short)f2bu(acc[m][n][0]), (short)f2bu(acc[m][n][1]),
                               (short)f2bu(acc[m][n][2]), (short)f2bu(acc[m][n][3]) };
                *(short4v*)&vbt[(((size_t)(b*KVH + kvh))*HD_ + hd)*T_ + t0] = pk;
            }
        }
    }
}

// ---------------- Flash attention: R15 structure + T14 async-STAGE split (dbuf) ----------------
// QBLK=64 (4 waves x 16 q-rows), KVBLK=64, swapped MFMA operands, swizzled LDS, defer-max.
// Staging: tile t+1's 4 global b128 loads issued at top of tile t (regs); ds_write into the
// OTHER buffer after PV (that buffer was last read at t-1, behind a barrier). 1 barrier/tile.
__global__ __launch_bounds__(256) void attn_mfma(const __hip_bfloat16* __restrict__ qb,
                                                 const __hip_bfloat16* __restrict__ kb,
                                                 const __hip_bfloat16* __restrict__ vbt,
                                                 __hip_bfloat16* __restrict__ ob) {
    __shared__ __hip_bfloat16 Ks[2][64*64];   // [key][d]   swizzled
    __shared__ __hip_bfloat16 Vs[2][64*64];   // [d][key]   swizzled
    __shared__ __hip_bfloat16 Ps[64*64];      // [qrow][key] swizzled, per-wave rows
    char* PsB = (char*)Ps;
    int tid = threadIdx.x;
    int w = tid >> 6, lane = tid & 63;
    int l15 = lane & 15, lhi = lane >> 4;
    int bh = blockIdx.y;
    int b = bh >> 4, h = bh & 15;
    int bk = b * KVH + (h >> 2);
    int qt0 = blockIdx.x * 64;

    const __hip_bfloat16* qrow = qb + ((size_t)bh * T_ + qt0 + w*16 + l15) * HD_;
    short8 qf0 = *(const short8*)(qrow + lhi*8);
    short8 qf1 = *(const short8*)(qrow + 32 + lhi*8);

    f32x4 oacc[4] = {};          // O^T[d=cb*16+lhi*4+r][qrow=l15]
    float m_run = -INFINITY, l_run = 0.0f;

    int sr = tid >> 2;                 // staging row 0..63
    int scB = (tid & 3) * 32;          // staging col byte {0,32,64,96}
    const __hip_bfloat16* kbase = kb  + (size_t)bk * T_ * HD_;
    const __hip_bfloat16* vbase = vbt + (size_t)bk * HD_ * T_;
    int sce = (tid & 3) * 16;          // element offset for global side

    // prologue: stage tile 0 into buf0
    {
        short8 ra = *(const short8*)(kbase + (size_t)sr*HD_ + sce);
        short8 rb = *(const short8*)(kbase + (size_t)sr*HD_ + sce + 8);
        short8 rc = *(const short8*)(vbase + (size_t)sr*T_ + sce);
        short8 rd = *(const short8*)(vbase + (size_t)sr*T_ + sce + 8);
        *(short8*)((char*)Ks[0] + KSWZ(sr, scB))      = ra;
        *(short8*)((char*)Ks[0] + KSWZ(sr, scB + 16)) = rb;
        *(short8*)((char*)Vs[0] + KSWZ(sr, scB))      = rc;
        *(short8*)((char*)Vs[0] + KSWZ(sr, scB + 16)) = rd;
    }
    __syncthreads();
    int cur = 0;
    const int NT = T_ / 64;

    for (int it = 0; it < NT; ++it) {
        // issue next tile's global loads early (latency hides under this tile's compute)
        short8 ra, rb, rc, rd;
        bool pfv = (it + 1 < NT);
        if (pfv) {
            int s0n = (it + 1) * 64;
            ra = *(const short8*)(kbase + (size_t)(s0n + sr)*HD_ + sce);
            rb = *(const short8*)(kbase + (size_t)(s0n + sr)*HD_ + sce + 8);
            rc = *(const short8*)(vbase + (size_t)sr*T_ + s0n + sce);
            rd = *(const short8*)(vbase + (size_t)sr*T_ + s0n + sce + 8);
        }
        char* KsB = (char*)Ks[cur];
        char* VsB = (char*)Vs[cur];

        // S^T = K Q^T
        f32x4 accs[4];
#pragma unroll
        for (int cb = 0; cb < 4; ++cb) {
            f32x4 z = {0.f, 0.f, 0.f, 0.f};
            short8 k0 = *(const short8*)(KsB + KSWZ(cb*16 + l15, lhi*16));
            short8 k1 = *(const short8*)(KsB + KSWZ(cb*16 + l15, 64 + lhi*16));
            z = __builtin_amdgcn_mfma_f32_16x16x32_bf16(k0, qf0, z, 0, 0, 0);
            z = __builtin_amdgcn_mfma_f32_16x16x32_bf16(k1, qf1, z, 0, 0, 0);
            accs[cb] = z;
        }

        // tile max for q-row l15
        float mx = -INFINITY;
#pragma unroll
        for (int cb = 0; cb < 4; ++cb)
#pragma unroll
            for (int r = 0; r < 4; ++r) mx = fmaxf(mx, accs[cb][r]);
        mx = fmaxf(mx, __shfl_xor(mx, 16));
        mx = fmaxf(mx, __shfl_xor(mx, 32));

        // defer-max (THR=8): rescale only when tile max exceeds m_run + 8
        if (!__all(mx <= m_run + 8.0f)) {
            float mn = fmaxf(m_run, mx);
            float cr = __expf(m_run - mn);
            m_run = mn;
            l_run *= cr;
#pragma unroll
            for (int cb = 0; cb < 4; ++cb)
#pragma unroll
                for (int r = 0; r < 4; ++r) oacc[cb][r] *= cr;
        }

        float rs = 0.0f;
        int pr = w*16 + l15;               // per-wave P row
#pragma unroll
        for (int cb = 0; cb < 4; ++cb) {
            f32x4 p;
#pragma unroll
            for (int r = 0; r < 4; ++r) { p[r] = __expf(accs[cb][r] - m_run); rs += p[r]; }
            short4v pk = { (short)f2bu(p[0]), (short)f2bu(p[1]),
                           (short)f2bu(p[2]), (short)f2bu(p[3]) };
            *(short4v*)(PsB + KSWZ(pr, cb*32 + lhi*8)) = pk;
        }
        rs += __shfl_xor(rs, 16);
        rs += __shfl_xor(rs, 32);
        l_run += rs;

        // O^T += V^T P^T
#pragma unroll
        for (int kk = 0; kk < 2; ++kk) {
            short8 pf = *(const short8*)(PsB + KSWZ(w*16 + l15, kk*64 + lhi*16));
#pragma unroll
            for (int cb = 0; cb < 4; ++cb) {
                short8 vf = *(const short8*)(VsB + KSWZ(cb*16 + l15, kk*64 + lhi*16));
                oacc[cb] = __builtin_amdgcn_mfma_f32_16x16x32_bf16(vf, pf, oacc[cb], 0, 0, 0);
            }
        }

        // write next tile into the other buffer (last read at t-1, behind barrier -> safe)
        if (pfv) {
            char* KnB = (char*)Ks[cur ^ 1];
            char* VnB = (char*)Vs[cur ^ 1];
            *(short8*)(KnB + KSWZ(sr, scB))      = ra;
            *(short8*)(KnB + KSWZ(sr, scB + 16)) = rb;
            *(short8*)(VnB + KSWZ(sr, scB))      = rc;
            *(short8*)(VnB + KSWZ(sr, scB + 16)) = rd;
        }
        __syncthreads();   // writes visible + all waves done reading cur
        cur ^= 1;
    }

    float inv = 1.0f / l_run;
    int t = qt0 + w*16 + l15;
    __hip_bfloat16* orow = ob + (size_t)(b*T_ + t) * D_ + h*HD_;
#pragma unroll
    for (int cb = 0; cb < 4; ++cb) {
        short4v okv = { (short)f2bu(oacc[cb][0] * inv), (short)f2bu(oacc[cb][1] * inv),
                        (short)f2bu(oacc[cb][2] * inv), (short)f2bu(oacc[cb][3] * inv) };
        *(short4v*)&orow[cb*16 + lhi*4] = okv;
    }
}

extern "C" void kernel_launch(void* const* d_in, const int* in_sizes, int n_in,
                              void* d_out, int out_size, void* d_ws, size_t ws_size,
                              hipStream_t stream) {
    const float* x    = (const float*)d_in[0];
    const float* cosb = (const float*)d_in[1];
    const float* sinb = (const float*)d_in[2];
    const float* Wq   = (const float*)d_in[3];
    const float* Wkv  = (const float*)d_in[4];
    const float* Wo   = (const float*)d_in[5];
    const float* ln1g = (const float*)d_in[6];
    const float* ln1b = (const float*)d_in[7];
    const float* ln2g = (const float*)d_in[8];
    const float* ln2b = (const float*)d_in[9];
    const float* W1   = (const float*)d_in[10];
    const float* b1   = (const float*)d_in[11];
    const float* W2   = (const float*)d_in[12];
    const float* b2   = (const float*)d_in[13];
    float* out = (float*)d_out;

    float* ws = (float*)d_ws;
    const size_t M = 1024 * 1024;
    __hip_bfloat16* hb   = (__hip_bfloat16*)(ws);
    float*          x2   = ws + 4*M;
    __hip_bfloat16* gbuf = (__hip_bfloat16*)(ws + 12*M);
    __hip_bfloat16* ob   = (__hip_bfloat16*)(ws + 20*M);
    __hip_bfloat16* qb   = (__hip_bfloat16*)(ws + 24*M);
    __hip_bfloat16* kbb  = (__hip_bfloat16*)(ws + 28*M);
    __hip_bfloat16* vbt  = (__hip_bfloat16*)(ws + 29*M);
    __hip_bfloat16* Wqkvb= (__hip_bfloat16*)(ws + 30*M);
    __hip_bfloat16* Wob  = (__hip_bfloat16*)(ws + 30*M + 3*M/4);
    __hip_bfloat16* W1b  = (__hip_bfloat16*)(ws + 31*M + M/4);
    __hip_bfloat16* W2b  = (__hip_bfloat16*)(ws + 32*M + M/4);

    // 0. weight casts (bf16)
    castw<<<(1024*1024/4 + 255)/256, 256, 0, stream>>>(Wq,  Wqkvb,              1024*1024/4);
    castw<<<( 512*1024/4 + 255)/256, 256, 0, stream>>>(Wkv, Wqkvb + 1024*1024,   512*1024/4);
    castw<<<(1024*1024/4 + 255)/256, 256, 0, stream>>>(Wo,  Wob,               1024*1024/4);
    castw<<<(2048*1024/4 + 255)/256, 256, 0, stream>>>(W1,  W1b,               2048*1024/4);
    castw<<<(2048*1024/4 + 255)/256, 256, 0, stream>>>(W2,  W2b,               2048*1024/4);

    // 1. LN1 -> hb (bf16)
    ln_bf16<<<R_, 256, 0, stream>>>(x, ln1g, ln1b, hb);
    // 2+3. qkv GEMM with fused RoPE -> qb/kbb/vbt (bf16)
    gemm_qkv_rope<<<dim3(QKVW/128, R_/128), 256, 0, stream>>>(hb, Wqkvb, cosb, sinb, qb, kbb, vbt);
    // 4. attention -> ob (bf16)
    attn_mfma<<<dim3(T_/64, B_*QH), 256, 0, stream>>>(qb, kbb, vbt, ob);
    // 5. x2 = x + ob @ Wob^T
    gemm_mfma<1><<<dim3(D_/128, R_/128), 256, 0, stream>>>(ob, Wob, nullptr, x, x2, nullptr, R_, D_, D_);
    // 6. LN2 -> hb (bf16)
    ln_bf16<<<R_, 256, 0, stream>>>(x2, ln2g, ln2b, hb);
    // 7. gbuf = gelu(hb @ W1b^T + b1) (bf16 out)
    gemm_mfma<2><<<dim3(DFF/128, R_/128), 256, 0, stream>>>(hb, W1b, b1, nullptr, nullptr, gbuf, R_, DFF, D_);
    // 8. out = x2 + gbuf @ W2b^T + b2
    gemm_mfma<3><<<dim3(D_/128, R_/128), 256, 0, stream>>>(gbuf, W2b, b2, x2, out, nullptr, R_, D_, DFF);
}

// Round 17
// 373.608 us; speedup vs baseline: 1.1019x; 1.0163x over previous
//
#include <hip/hip_runtime.h>
#include <hip/hip_bf16.h>
#include <math.h>
#include <stdint.h>

#define B_   4
#define T_   2048
#define D_   1024
#define QH   16
#define KVH  4
#define HD_  64
#define R_   (B_*T_)      // 8192 rows
#define DFF  2048
#define QKVW 1536         // fused q(1024) + kv(512) output width

typedef short short8 __attribute__((ext_vector_type(8)));
typedef short short4v __attribute__((ext_vector_type(4)));
typedef float f32x4 __attribute__((ext_vector_type(4)));

static __device__ __forceinline__ unsigned short f2bu(float x) {
    __hip_bfloat16 h = __float2bfloat16(x);
    return *reinterpret_cast<unsigned short*>(&h);
}

// swizzled byte offset within a [64][64]-bf16 (128B/row) LDS tile
#define KSWZ(row, cbyte) (((row) << 7) + ((cbyte) ^ (((row) & 7) << 4)))

__device__ __forceinline__ void gload_lds16(const void* g, void* l) {
    typedef __attribute__((address_space(1))) void gv_t;
    typedef __attribute__((address_space(3))) void lv_t;
    __builtin_amdgcn_global_load_lds((gv_t*)g, (lv_t*)l, 16, 0, 0);
}

// ---------------- all weights f32 -> bf16, one kernel ----------------
// quad prefix ranges: Wq 262144 | Wkv 131072 | Wo 262144 | W1 524288 | W2 524288
__global__ __launch_bounds__(256) void castw_all(const float* __restrict__ Wq,
                                                 const float* __restrict__ Wkv,
                                                 const float* __restrict__ Wo,
                                                 const float* __restrict__ W1,
                                                 const float* __restrict__ W2,
                                                 __hip_bfloat16* __restrict__ dqkv,
                                                 __hip_bfloat16* __restrict__ dWo,
                                                 __hip_bfloat16* __restrict__ dW1,
                                                 __hip_bfloat16* __restrict__ dW2) {
    int i = blockIdx.x * 256 + threadIdx.x;   // quad index, total 1703936
    const float* src; __hip_bfloat16* dst; int off;
    if (i < 262144)       { src = Wq;  dst = dqkv;            off = i; }
    else if (i < 393216)  { src = Wkv; dst = dqkv + 1048576;  off = i - 262144; }
    else if (i < 655360)  { src = Wo;  dst = dWo;             off = i - 393216; }
    else if (i < 1179648) { src = W1;  dst = dW1;             off = i - 655360; }
    else                  { src = W2;  dst = dW2;             off = i - 1179648; }
    float4 v = *(const float4*)&src[(size_t)off*4];
    ushort4 o = { f2bu(v.x), f2bu(v.y), f2bu(v.z), f2bu(v.w) };
    *(ushort4*)&dst[(size_t)off*4] = o;
}

// ---------------- LayerNorm -> bf16 out: one block per row ----------------
__global__ __launch_bounds__(256) void ln_bf16(const float* __restrict__ x,
                                               const float* __restrict__ g,
                                               const float* __restrict__ bta,
                                               __hip_bfloat16* __restrict__ out) {
    int row = blockIdx.x;
    int tid = threadIdx.x;
    const float* xr = x + (size_t)row * D_;
    int c = tid * 4;
    float4 v = *(const float4*)&xr[c];
    float s = v.x + v.y + v.z + v.w;
#pragma unroll
    for (int off = 32; off >= 1; off >>= 1) s += __shfl_xor(s, off);
    __shared__ float sm[4], sv[4];
    int wid = tid >> 6, lane = tid & 63;
    if (lane == 0) sm[wid] = s;
    __syncthreads();
    float mean = (sm[0] + sm[1] + sm[2] + sm[3]) * (1.0f / D_);
    float d0 = v.x - mean, d1 = v.y - mean, d2 = v.z - mean, d3 = v.w - mean;
    float qq = d0*d0 + d1*d1 + d2*d2 + d3*d3;
#pragma unroll
    for (int off = 32; off >= 1; off >>= 1) qq += __shfl_xor(qq, off);
    if (lane == 0) sv[wid] = qq;
    __syncthreads();
    float var = (sv[0] + sv[1] + sv[2] + sv[3]) * (1.0f / D_);
    float rstd = rsqrtf(var + 1e-5f);
    float4 gg = *(const float4*)&g[c];
    float4 bb = *(const float4*)&bta[c];
    ushort4 o = { f2bu(d0 * rstd * gg.x + bb.x),
                  f2bu(d1 * rstd * gg.y + bb.y),
                  f2bu(d2 * rstd * gg.z + bb.z),
                  f2bu(d3 * rstd * gg.w + bb.w) };
    *(ushort4*)&(out + (size_t)row * D_)[c] = o;
}

// ---------------- bf16 MFMA GEMM: C = res + act(A(MxK) * W(NxK)^T + bias) ----------------
// MODE: 1 +res f32; 2 +bias,gelu -> bf16; 3 +bias,+res f32
template<int MODE>
__global__ __launch_bounds__(256) void gemm_mfma(const __hip_bfloat16* __restrict__ A,
                                                 const __hip_bfloat16* __restrict__ W,
                                                 const float* __restrict__ bias,
                                                 const float* __restrict__ res,
                                                 float* __restrict__ Cf,
                                                 __hip_bfloat16* __restrict__ Cb,
                                                 int M, int N, int K) {
    __shared__ __hip_bfloat16 At[128*32];
    __shared__ __hip_bfloat16 Bt[128*32];
    int tid = threadIdx.x;
    int w = tid >> 6, lane = tid & 63;
    int l15 = lane & 15, lhi = lane >> 4;
    int bm = blockIdx.y * 128, bn = blockIdx.x * 128;
    int wr = w >> 1, wc = w & 1;
    f32x4 acc[4][4] = {};

    for (int k0 = 0; k0 < K; k0 += 32) {
#pragma unroll
        for (int iss = 0; iss < 2; ++iss) {
            int off = (iss*256 + tid) * 8;     // element offset in 128x32 tile
            int row = off >> 5, col = off & 31;
            gload_lds16(A + (size_t)(bm + row) * K + k0 + col, &At[off]);
            gload_lds16(W + (size_t)(bn + row) * K + k0 + col, &Bt[off]);
        }
        __syncthreads();
        short8 af[4], bf[4];
#pragma unroll
        for (int m = 0; m < 4; ++m) af[m] = *(const short8*)&At[(wr*64 + m*16 + l15)*32 + lhi*8];
#pragma unroll
        for (int n = 0; n < 4; ++n) bf[n] = *(const short8*)&Bt[(wc*64 + n*16 + l15)*32 + lhi*8];
#pragma unroll
        for (int m = 0; m < 4; ++m)
#pragma unroll
            for (int n = 0; n < 4; ++n)
                acc[m][n] = __builtin_amdgcn_mfma_f32_16x16x32_bf16(af[m], bf[n], acc[m][n], 0, 0, 0);
        __syncthreads();
    }

#pragma unroll
    for (int m = 0; m < 4; ++m) {
#pragma unroll
        for (int j = 0; j < 4; ++j) {
            int row = bm + wr*64 + m*16 + lhi*4 + j;
#pragma unroll
            for (int n = 0; n < 4; ++n) {
                int col = bn + wc*64 + n*16 + l15;
                float val = acc[m][n][j];
                if (MODE == 2 || MODE == 3) val += bias[col];
                if (MODE == 2) val = 0.5f * val * (1.0f + erff(val * 0.70710678118654752f));
                if (MODE == 1 || MODE == 3) val += res[(size_t)row * N + col];
                if (MODE == 2) Cb[(size_t)row * N + col] = __float2bfloat16(val);
                else           Cf[(size_t)row * N + col] = val;
            }
        }
    }
}

// ---------------- QKV GEMM with fused RoPE epilogue ----------------
__global__ __launch_bounds__(256) void gemm_qkv_rope(const __hip_bfloat16* __restrict__ A,
                                                     const __hip_bfloat16* __restrict__ W,
                                                     const float* __restrict__ cosb,
                                                     const float* __restrict__ sinb,
                                                     __hip_bfloat16* __restrict__ qb,
                                                     __hip_bfloat16* __restrict__ kbb,
                                                     __hip_bfloat16* __restrict__ vbt) {
    const int N = QKVW, K = D_;
    (void)N;
    __shared__ __hip_bfloat16 At[128*32];
    __shared__ __hip_bfloat16 Bt[128*32];
    int tid = threadIdx.x;
    int w = tid >> 6, lane = tid & 63;
    int l15 = lane & 15, lhi = lane >> 4;
    int bm = blockIdx.y * 128, bn = blockIdx.x * 128;
    int wr = w >> 1, wc = w & 1;
    f32x4 acc[4][4] = {};

    for (int k0 = 0; k0 < K; k0 += 32) {
#pragma unroll
        for (int iss = 0; iss < 2; ++iss) {
            int off = (iss*256 + tid) * 8;
            int row = off >> 5, col = off & 31;
            gload_lds16(A + (size_t)(bm + row) * K + k0 + col, &At[off]);
            gload_lds16(W + (size_t)(bn + row) * K + k0 + col, &Bt[off]);
        }
        __syncthreads();
        short8 af[4], bf[4];
#pragma unroll
        for (int m = 0; m < 4; ++m) af[m] = *(const short8*)&At[(wr*64 + m*16 + l15)*32 + lhi*8];
#pragma unroll
        for (int n = 0; n < 4; ++n) bf[n] = *(const short8*)&Bt[(wc*64 + n*16 + l15)*32 + lhi*8];
#pragma unroll
        for (int m = 0; m < 4; ++m)
#pragma unroll
            for (int n = 0; n < 4; ++n)
                acc[m][n] = __builtin_amdgcn_mfma_f32_16x16x32_bf16(af[m], bf[n], acc[m][n], 0, 0, 0);
        __syncthreads();
    }

    bool is_q = (bn < 1024);
    bool is_v = (!is_q) && (wc == 1);   // wave-uniform
    if (!is_v) {
#pragma unroll
        for (int m = 0; m < 4; ++m) {
#pragma unroll
            for (int j = 0; j < 4; ++j) {
                int row = bm + wr*64 + m*16 + lhi*4 + j;
                int b = row >> 11, t = row & (T_ - 1);
                const float* crow = cosb + t*HD_;
                const float* srow = sinb + t*HD_;
#pragma unroll
                for (int n = 0; n < 4; ++n) {
                    int col = bn + wc*64 + n*16 + l15;
                    int hd = n*16 + l15;
                    float val = acc[m][n][j];
                    float part = __shfl_xor(val, 1);
                    float rot = (l15 & 1) ? part : -part;
                    float o = val * crow[hd] + rot * srow[hd];
                    if (is_q) {
                        int h = col >> 6;
                        qb[(((size_t)(b*QH + h))*T_ + t)*HD_ + hd] = __float2bfloat16(o * 0.125f);
                    } else {
                        int kvh = (col - 1024) >> 7;
                        kbb[(((size_t)(b*KVH + kvh))*T_ + t)*HD_ + hd] = __float2bfloat16(o);
                    }
                }
            }
        }
    } else {
#pragma unroll
        for (int m = 0; m < 4; ++m) {
            int row0 = bm + wr*64 + m*16 + lhi*4;
            int b = row0 >> 11, t0 = row0 & (T_ - 1);
#pragma unroll
            for (int n = 0; n < 4; ++n) {
                int col = bn + 64 + n*16 + l15;
                int kvh = (col - 1024) >> 7;
                int hd = n*16 + l15;
                short4v pk = { (short)f2bu(acc[m][n][0]), (short)f2bu(acc[m][n][1]),
                               (short)f2bu(acc[m][n][2]), (short)f2bu(acc[m][n][3]) };
                *(short4v*)&vbt[(((size_t)(b*KVH + kvh))*HD_ + hd)*T_ + t0] = pk;
            }
        }
    }
}

// ---------------- Flash attention: dbuf gload_lds staging (pre-swizzled source) ----------------
// QBLK=64 (4 waves x 16 q-rows), KVBLK=64, swapped MFMA operands, swizzled LDS, defer-max.
// Staging: tile t+1 issued via 4 global_load_lds into the OTHER buffer right after the
// barrier (all reads of it finished at t-1); end-of-tile __syncthreads drains vmcnt.
// LDS dest is linear (chunk + lane*16); global SOURCE col is pre-swizzled so reads use KSWZ.
__global__ __launch_bounds__(256) void attn_mfma(const __hip_bfloat16* __restrict__ qb,
                                                 const __hip_bfloat16* __restrict__ kb,
                                                 const __hip_bfloat16* __restrict__ vbt,
                                                 __hip_bfloat16* __restrict__ ob) {
    __shared__ __hip_bfloat16 Ks[2][64*64];   // [key][d]   swizzled
    __shared__ __hip_bfloat16 Vs[2][64*64];   // [d][key]   swizzled
    __shared__ __hip_bfloat16 Ps[64*64];      // [qrow][key] swizzled, per-wave rows
    char* PsB = (char*)Ps;
    int tid = threadIdx.x;
    int w = tid >> 6, lane = tid & 63;
    int l15 = lane & 15, lhi = lane >> 4;
    int bh = blockIdx.y;
    int b = bh >> 4, h = bh & 15;
    int bk = b * KVH + (h >> 2);
    int qt0 = blockIdx.x * 64;

    const __hip_bfloat16* qrow = qb + ((size_t)bh * T_ + qt0 + w*16 + l15) * HD_;
    short8 qf0 = *(const short8*)(qrow + lhi*8);
    short8 qf1 = *(const short8*)(qrow + 32 + lhi*8);

    f32x4 oacc[4] = {};          // O^T[d=cb*16+lhi*4+r][qrow=l15]
    float m_run = -INFINITY, l_run = 0.0f;

    const __hip_bfloat16* kbase = kb  + (size_t)bk * T_ * HD_;
    const __hip_bfloat16* vbase = vbt + (size_t)bk * HD_ * T_;
    // pre-swizzled source addressing (linear LDS dest = chunk + lane*16)
    int lrow = lane >> 3;                                // row within 8-row chunk
    int sce  = (((lane & 7) * 16) ^ (lrow << 4)) >> 1;   // swizzled source col (elements)

#define STAGE(buf, s0) do { \
    _Pragma("unroll") \
    for (int c = 0; c < 2; ++c) { \
        int rw = (w + 4*c)*8 + lrow; \
        int ldsoff = (w + 4*c)*1024 + lane*16; \
        gload_lds16(kbase + (size_t)((s0) + rw)*HD_ + sce, (char*)Ks[buf] + ldsoff); \
        gload_lds16(vbase + (size_t)rw*T_ + (s0) + sce,    (char*)Vs[buf] + ldsoff); \
    } } while(0)

    STAGE(0, 0);
    __syncthreads();    // drains vmcnt before first compute
    int cur = 0;
    const int NT = T_ / 64;

    for (int it = 0; it < NT; ++it) {
        if (it + 1 < NT) STAGE(cur^1, (it+1)*64);   // async prefetch into other buffer
        char* KsB = (char*)Ks[cur];
        char* VsB = (char*)Vs[cur];

        // S^T = K Q^T
        f32x4 accs[4];
#pragma unroll
        for (int cb = 0; cb < 4; ++cb) {
            f32x4 z = {0.f, 0.f, 0.f, 0.f};
            short8 k0 = *(const short8*)(KsB + KSWZ(cb*16 + l15, lhi*16));
            short8 k1 = *(const short8*)(KsB + KSWZ(cb*16 + l15, 64 + lhi*16));
            z = __builtin_amdgcn_mfma_f32_16x16x32_bf16(k0, qf0, z, 0, 0, 0);
            z = __builtin_amdgcn_mfma_f32_16x16x32_bf16(k1, qf1, z, 0, 0, 0);
            accs[cb] = z;
        }

        // tile max for q-row l15
        float mx = -INFINITY;
#pragma unroll
        for (int cb = 0; cb < 4; ++cb)
#pragma unroll
            for (int r = 0; r < 4; ++r) mx = fmaxf(mx, accs[cb][r]);
        mx = fmaxf(mx, __shfl_xor(mx, 16));
        mx = fmaxf(mx, __shfl_xor(mx, 32));

        // defer-max (THR=8)
        if (!__all(mx <= m_run + 8.0f)) {
            float mn = fmaxf(m_run, mx);
            float cr = __expf(m_run - mn);
            m_run = mn;
            l_run *= cr;
#pragma unroll
            for (int cb = 0; cb < 4; ++cb)
#pragma unroll
                for (int r = 0; r < 4; ++r) oacc[cb][r] *= cr;
        }

        float rs = 0.0f;
        int pr = w*16 + l15;               // per-wave P row
#pragma unroll
        for (int cb = 0; cb < 4; ++cb) {
            f32x4 p;
#pragma unroll
            for (int r = 0; r < 4; ++r) { p[r] = __expf(accs[cb][r] - m_run); rs += p[r]; }
            short4v pk = { (short)f2bu(p[0]), (short)f2bu(p[1]),
                           (short)f2bu(p[2]), (short)f2bu(p[3]) };
            *(short4v*)(PsB + KSWZ(pr, cb*32 + lhi*8)) = pk;
        }
        rs += __shfl_xor(rs, 16);
        rs += __shfl_xor(rs, 32);
        l_run += rs;
        // no barrier: P write->read is same-wave (lgkmcnt-ordered)

        // O^T += V^T P^T
#pragma unroll
        for (int kk = 0; kk < 2; ++kk) {
            short8 pf = *(const short8*)(PsB + KSWZ(w*16 + l15, kk*64 + lhi*16));
#pragma unroll
            for (int cb = 0; cb < 4; ++cb) {
                short8 vf = *(const short8*)(VsB + KSWZ(cb*16 + l15, kk*64 + lhi*16));
                oacc[cb] = __builtin_amdgcn_mfma_f32_16x16x32_bf16(vf, pf, oacc[cb], 0, 0, 0);
            }
        }
        __syncthreads();   // drains prefetch vmcnt + all waves done with cur
        cur ^= 1;
    }
#undef STAGE

    float inv = 1.0f / l_run;
    int t = qt0 + w*16 + l15;
    __hip_bfloat16* orow = ob + (size_t)(b*T_ + t) * D_ + h*HD_;
#pragma unroll
    for (int cb = 0; cb < 4; ++cb) {
        short4v okv = { (short)f2bu(oacc[cb][0] * inv), (short)f2bu(oacc[cb][1] * inv),
                        (short)f2bu(oacc[cb][2] * inv), (short)f2bu(oacc[cb][3] * inv) };
        *(short4v*)&orow[cb*16 + lhi*4] = okv;
    }
}

extern "C" void kernel_launch(void* const* d_in, const int* in_sizes, int n_in,
                              void* d_out, int out_size, void* d_ws, size_t ws_size,
                              hipStream_t stream) {
    const float* x    = (const float*)d_in[0];
    const float* cosb = (const float*)d_in[1];
    const float* sinb = (const float*)d_in[2];
    const float* Wq   = (const float*)d_in[3];
    const float* Wkv  = (const float*)d_in[4];
    const float* Wo   = (const float*)d_in[5];
    const float* ln1g = (const float*)d_in[6];
    const float* ln1b = (const float*)d_in[7];
    const float* ln2g = (const float*)d_in[8];
    const float* ln2b = (const float*)d_in[9];
    const float* W1   = (const float*)d_in[10];
    const float* b1   = (const float*)d_in[11];
    const float* W2   = (const float*)d_in[12];
    const float* b2   = (const float*)d_in[13];
    float* out = (float*)d_out;

    float* ws = (float*)d_ws;
    const size_t M = 1024 * 1024;
    __hip_bfloat16* hb   = (__hip_bfloat16*)(ws);
    float*          x2   = ws + 4*M;
    __hip_bfloat16* gbuf = (__hip_bfloat16*)(ws + 12*M);
    __hip_bfloat16* ob   = (__hip_bfloat16*)(ws + 20*M);
    __hip_bfloat16* qb   = (__hip_bfloat16*)(ws + 24*M);
    __hip_bfloat16* kbb  = (__hip_bfloat16*)(ws + 28*M);
    __hip_bfloat16* vbt  = (__hip_bfloat16*)(ws + 29*M);
    __hip_bfloat16* Wqkvb= (__hip_bfloat16*)(ws + 30*M);
    __hip_bfloat16* Wob  = (__hip_bfloat16*)(ws + 30*M + 3*M/4);
    __hip_bfloat16* W1b  = (__hip_bfloat16*)(ws + 31*M + M/4);
    __hip_bfloat16* W2b  = (__hip_bfloat16*)(ws + 32*M + M/4);

    // 0. all weight casts in one kernel (1703936 quads)
    castw_all<<<(1703936 + 255)/256, 256, 0, stream>>>(Wq, Wkv, Wo, W1, W2,
                                                       Wqkvb, Wob, W1b, W2b);

    // 1. LN1 -> hb (bf16)
    ln_bf16<<<R_, 256, 0, stream>>>(x, ln1g, ln1b, hb);
    // 2+3. qkv GEMM with fused RoPE -> qb/kbb/vbt (bf16)
    gemm_qkv_rope<<<dim3(QKVW/128, R_/128), 256, 0, stream>>>(hb, Wqkvb, cosb, sinb, qb, kbb, vbt);
    // 4. attention -> ob (bf16)
    attn_mfma<<<dim3(T_/64, B_*QH), 256, 0, stream>>>(qb, kbb, vbt, ob);
    // 5. x2 = x + ob @ Wob^T
    gemm_mfma<1><<<dim3(D_/128, R_/128), 256, 0, stream>>>(ob, Wob, nullptr, x, x2, nullptr, R_, D_, D_);
    // 6. LN2 -> hb (bf16)
    ln_bf16<<<R_, 256, 0, stream>>>(x2, ln2g, ln2b, hb);
    // 7. gbuf = gelu(hb @ W1b^T + b1) (bf16 out)
    gemm_mfma<2><<<dim3(DFF/128, R_/128), 256, 0, stream>>>(hb, W1b, b1, nullptr, nullptr, gbuf, R_, DFF, D_);
    // 8. out = x2 + gbuf @ W2b^T + b2
    gemm_mfma<3><<<dim3(D_/128, R_/128), 256, 0, stream>>>(gbuf, W2b, b2, x2, out, nullptr, R_, D_, DFF);
}

// Round 18
// 359.047 us; speedup vs baseline: 1.1466x; 1.0406x over previous
//
#include <hip/hip_runtime.h>
#include <hip/hip_bf16.h>
#include <math.h>
#include <stdint.h>

#define B_   4
#define T_   2048
#define D_   1024
#define QH   16
#define KVH  4
#define HD_  64
#define R_   (B_*T_)      // 8192 rows
#define DFF  2048
#define QKVW 1536         // fused q(1024) + kv(512) output width

typedef short short8 __attribute__((ext_vector_type(8)));
typedef short short4v __attribute__((ext_vector_type(4)));
typedef float f32x4 __attribute__((ext_vector_type(4)));

static __device__ __forceinline__ unsigned short f2bu(float x) {
    __hip_bfloat16 h = __float2bfloat16(x);
    return *reinterpret_cast<unsigned short*>(&h);
}

// swizzled byte offset within a [64][64]-bf16 (128B/row) LDS tile
#define KSWZ(row, cbyte) (((row) << 7) + ((cbyte) ^ (((row) & 7) << 4)))

__device__ __forceinline__ void gload_lds16(const void* g, void* l) {
    typedef __attribute__((address_space(1))) void gv_t;
    typedef __attribute__((address_space(3))) void lv_t;
    __builtin_amdgcn_global_load_lds((gv_t*)g, (lv_t*)l, 16, 0, 0);
}

// XCD-aware linear block swizzle (requires nwg % 8 == 0): consecutive swz ids
// stay on one XCD -> neighbor tiles sharing an A-panel hit the same L2.
__device__ __forceinline__ int xcd_swz(int bid, int nwg) {
    int cpx = nwg >> 3;
    return (bid & 7) * cpx + (bid >> 3);
}

// ---------------- all weights f32 -> bf16, one kernel ----------------
// quad prefix ranges: Wq 262144 | Wkv 131072 | Wo 262144 | W1 524288 | W2 524288
__global__ __launch_bounds__(256) void castw_all(const float* __restrict__ Wq,
                                                 const float* __restrict__ Wkv,
                                                 const float* __restrict__ Wo,
                                                 const float* __restrict__ W1,
                                                 const float* __restrict__ W2,
                                                 __hip_bfloat16* __restrict__ dqkv,
                                                 __hip_bfloat16* __restrict__ dWo,
                                                 __hip_bfloat16* __restrict__ dW1,
                                                 __hip_bfloat16* __restrict__ dW2) {
    int i = blockIdx.x * 256 + threadIdx.x;   // quad index, total 1703936
    const float* src; __hip_bfloat16* dst; int off;
    if (i < 262144)       { src = Wq;  dst = dqkv;            off = i; }
    else if (i < 393216)  { src = Wkv; dst = dqkv + 1048576;  off = i - 262144; }
    else if (i < 655360)  { src = Wo;  dst = dWo;             off = i - 393216; }
    else if (i < 1179648) { src = W1;  dst = dW1;             off = i - 655360; }
    else                  { src = W2;  dst = dW2;             off = i - 1179648; }
    float4 v = *(const float4*)&src[(size_t)off*4];
    ushort4 o = { f2bu(v.x), f2bu(v.y), f2bu(v.z), f2bu(v.w) };
    *(ushort4*)&dst[(size_t)off*4] = o;
}

// ---------------- LayerNorm -> bf16 out: one block per row ----------------
__global__ __launch_bounds__(256) void ln_bf16(const float* __restrict__ x,
                                               const float* __restrict__ g,
                                               const float* __restrict__ bta,
                                               __hip_bfloat16* __restrict__ out) {
    int row = blockIdx.x;
    int tid = threadIdx.x;
    const float* xr = x + (size_t)row * D_;
    int c = tid * 4;
    float4 v = *(const float4*)&xr[c];
    float s = v.x + v.y + v.z + v.w;
#pragma unroll
    for (int off = 32; off >= 1; off >>= 1) s += __shfl_xor(s, off);
    __shared__ float sm[4], sv[4];
    int wid = tid >> 6, lane = tid & 63;
    if (lane == 0) sm[wid] = s;
    __syncthreads();
    float mean = (sm[0] + sm[1] + sm[2] + sm[3]) * (1.0f / D_);
    float d0 = v.x - mean, d1 = v.y - mean, d2 = v.z - mean, d3 = v.w - mean;
    float qq = d0*d0 + d1*d1 + d2*d2 + d3*d3;
#pragma unroll
    for (int off = 32; off >= 1; off >>= 1) qq += __shfl_xor(qq, off);
    if (lane == 0) sv[wid] = qq;
    __syncthreads();
    float var = (sv[0] + sv[1] + sv[2] + sv[3]) * (1.0f / D_);
    float rstd = rsqrtf(var + 1e-5f);
    float4 gg = *(const float4*)&g[c];
    float4 bb = *(const float4*)&bta[c];
    ushort4 o = { f2bu(d0 * rstd * gg.x + bb.x),
                  f2bu(d1 * rstd * gg.y + bb.y),
                  f2bu(d2 * rstd * gg.z + bb.z),
                  f2bu(d3 * rstd * gg.w + bb.w) };
    *(ushort4*)&(out + (size_t)row * D_)[c] = o;
}

// ---------------- bf16 MFMA GEMM: C = res + act(A(MxK) * W(NxK)^T + bias) ----------------
// 1D grid with XCD swizzle. MODE: 1 +res f32; 2 +bias,gelu -> bf16; 3 +bias,+res f32
template<int MODE>
__global__ __launch_bounds__(256) void gemm_mfma(const __hip_bfloat16* __restrict__ A,
                                                 const __hip_bfloat16* __restrict__ W,
                                                 const float* __restrict__ bias,
                                                 const float* __restrict__ res,
                                                 float* __restrict__ Cf,
                                                 __hip_bfloat16* __restrict__ Cb,
                                                 int M, int N, int K) {
    __shared__ __hip_bfloat16 At[128*32];
    __shared__ __hip_bfloat16 Bt[128*32];
    int tid = threadIdx.x;
    int w = tid >> 6, lane = tid & 63;
    int l15 = lane & 15, lhi = lane >> 4;
    int swz = xcd_swz(blockIdx.x, gridDim.x);
    int gx = N >> 7;
    int bn = (swz % gx) * 128, bm = (swz / gx) * 128;
    int wr = w >> 1, wc = w & 1;
    f32x4 acc[4][4] = {};

    for (int k0 = 0; k0 < K; k0 += 32) {
#pragma unroll
        for (int iss = 0; iss < 2; ++iss) {
            int off = (iss*256 + tid) * 8;     // element offset in 128x32 tile
            int row = off >> 5, col = off & 31;
            gload_lds16(A + (size_t)(bm + row) * K + k0 + col, &At[off]);
            gload_lds16(W + (size_t)(bn + row) * K + k0 + col, &Bt[off]);
        }
        __syncthreads();
        short8 af[4], bf[4];
#pragma unroll
        for (int m = 0; m < 4; ++m) af[m] = *(const short8*)&At[(wr*64 + m*16 + l15)*32 + lhi*8];
#pragma unroll
        for (int n = 0; n < 4; ++n) bf[n] = *(const short8*)&Bt[(wc*64 + n*16 + l15)*32 + lhi*8];
#pragma unroll
        for (int m = 0; m < 4; ++m)
#pragma unroll
            for (int n = 0; n < 4; ++n)
                acc[m][n] = __builtin_amdgcn_mfma_f32_16x16x32_bf16(af[m], bf[n], acc[m][n], 0, 0, 0);
        __syncthreads();
    }

#pragma unroll
    for (int m = 0; m < 4; ++m) {
#pragma unroll
        for (int j = 0; j < 4; ++j) {
            int row = bm + wr*64 + m*16 + lhi*4 + j;
#pragma unroll
            for (int n = 0; n < 4; ++n) {
                int col = bn + wc*64 + n*16 + l15;
                float val = acc[m][n][j];
                if (MODE == 2 || MODE == 3) val += bias[col];
                if (MODE == 2) val = 0.5f * val * (1.0f + erff(val * 0.70710678118654752f));
                if (MODE == 1 || MODE == 3) val += res[(size_t)row * N + col];
                if (MODE == 2) Cb[(size_t)row * N + col] = __float2bfloat16(val);
                else           Cf[(size_t)row * N + col] = val;
            }
        }
    }
}

// ---------------- QKV GEMM with fused RoPE epilogue (1D grid, XCD swizzle) ----------------
__global__ __launch_bounds__(256) void gemm_qkv_rope(const __hip_bfloat16* __restrict__ A,
                                                     const __hip_bfloat16* __restrict__ W,
                                                     const float* __restrict__ cosb,
                                                     const float* __restrict__ sinb,
                                                     __hip_bfloat16* __restrict__ qb,
                                                     __hip_bfloat16* __restrict__ kbb,
                                                     __hip_bfloat16* __restrict__ vbt) {
    const int K = D_;
    __shared__ __hip_bfloat16 At[128*32];
    __shared__ __hip_bfloat16 Bt[128*32];
    int tid = threadIdx.x;
    int w = tid >> 6, lane = tid & 63;
    int l15 = lane & 15, lhi = lane >> 4;
    int swz = xcd_swz(blockIdx.x, gridDim.x);
    const int gx = QKVW >> 7;   // 12
    int bn = (swz % gx) * 128, bm = (swz / gx) * 128;
    int wr = w >> 1, wc = w & 1;
    f32x4 acc[4][4] = {};

    for (int k0 = 0; k0 < K; k0 += 32) {
#pragma unroll
        for (int iss = 0; iss < 2; ++iss) {
            int off = (iss*256 + tid) * 8;
            int row = off >> 5, col = off & 31;
            gload_lds16(A + (size_t)(bm + row) * K + k0 + col, &At[off]);
            gload_lds16(W + (size_t)(bn + row) * K + k0 + col, &Bt[off]);
        }
        __syncthreads();
        short8 af[4], bf[4];
#pragma unroll
        for (int m = 0; m < 4; ++m) af[m] = *(const short8*)&At[(wr*64 + m*16 + l15)*32 + lhi*8];
#pragma unroll
        for (int n = 0; n < 4; ++n) bf[n] = *(const short8*)&Bt[(wc*64 + n*16 + l15)*32 + lhi*8];
#pragma unroll
        for (int m = 0; m < 4; ++m)
#pragma unroll
            for (int n = 0; n < 4; ++n)
                acc[m][n] = __builtin_amdgcn_mfma_f32_16x16x32_bf16(af[m], bf[n], acc[m][n], 0, 0, 0);
        __syncthreads();
    }

    bool is_q = (bn < 1024);
    bool is_v = (!is_q) && (wc == 1);   // wave-uniform
    if (!is_v) {
#pragma unroll
        for (int m = 0; m < 4; ++m) {
#pragma unroll
            for (int j = 0; j < 4; ++j) {
                int row = bm + wr*64 + m*16 + lhi*4 + j;
                int b = row >> 11, t = row & (T_ - 1);
                const float* crow = cosb + t*HD_;
                const float* srow = sinb + t*HD_;
#pragma unroll
                for (int n = 0; n < 4; ++n) {
                    int col = bn + wc*64 + n*16 + l15;
                    int hd = n*16 + l15;
                    float val = acc[m][n][j];
                    float part = __shfl_xor(val, 1);
                    float rot = (l15 & 1) ? part : -part;
                    float o = val * crow[hd] + rot * srow[hd];
                    if (is_q) {
                        int h = col >> 6;
                        qb[(((size_t)(b*QH + h))*T_ + t)*HD_ + hd] = __float2bfloat16(o * 0.125f);
                    } else {
                        int kvh = (col - 1024) >> 7;
                        kbb[(((size_t)(b*KVH + kvh))*T_ + t)*HD_ + hd] = __float2bfloat16(o);
                    }
                }
            }
        }
    } else {
#pragma unroll
        for (int m = 0; m < 4; ++m) {
            int row0 = bm + wr*64 + m*16 + lhi*4;
            int b = row0 >> 11, t0 = row0 & (T_ - 1);
#pragma unroll
            for (int n = 0; n < 4; ++n) {
                int col = bn + 64 + n*16 + l15;
                int kvh = (col - 1024) >> 7;
                int hd = n*16 + l15;
                short4v pk = { (short)f2bu(acc[m][n][0]), (short)f2bu(acc[m][n][1]),
                               (short)f2bu(acc[m][n][2]), (short)f2bu(acc[m][n][3]) };
                *(short4v*)&vbt[(((size_t)(b*KVH + kvh))*HD_ + hd)*T_ + t0] = pk;
            }
        }
    }
}

// ---------------- Flash attention: R16 structure (reg-staged async split) + s_setprio ----------------
// QBLK=64 (4 waves x 16 q-rows), KVBLK=64, swapped MFMA operands, swizzled LDS, defer-max.
// Staging: tile t+1's 4 global b128 loads issued at top of tile t (regs); ds_write into the
// OTHER buffer after PV (that buffer was last read at t-1, behind a barrier). 1 barrier/tile.
__global__ __launch_bounds__(256) void attn_mfma(const __hip_bfloat16* __restrict__ qb,
                                                 const __hip_bfloat16* __restrict__ kb,
                                                 const __hip_bfloat16* __restrict__ vbt,
                                                 __hip_bfloat16* __restrict__ ob) {
    __shared__ __hip_bfloat16 Ks[2][64*64];   // [key][d]   swizzled
    __shared__ __hip_bfloat16 Vs[2][64*64];   // [d][key]   swizzled
    __shared__ __hip_bfloat16 Ps[64*64];      // [qrow][key] swizzled, per-wave rows
    char* PsB = (char*)Ps;
    int tid = threadIdx.x;
    int w = tid >> 6, lane = tid & 63;
    int l15 = lane & 15, lhi = lane >> 4;
    int bh = blockIdx.y;
    int b = bh >> 4, h = bh & 15;
    int bk = b * KVH + (h >> 2);
    int qt0 = blockIdx.x * 64;

    const __hip_bfloat16* qrow = qb + ((size_t)bh * T_ + qt0 + w*16 + l15) * HD_;
    short8 qf0 = *(const short8*)(qrow + lhi*8);
    short8 qf1 = *(const short8*)(qrow + 32 + lhi*8);

    f32x4 oacc[4] = {};          // O^T[d=cb*16+lhi*4+r][qrow=l15]
    float m_run = -INFINITY, l_run = 0.0f;

    int sr = tid >> 2;                 // staging row 0..63
    int scB = (tid & 3) * 32;          // staging col byte {0,32,64,96}
    const __hip_bfloat16* kbase = kb  + (size_t)bk * T_ * HD_;
    const __hip_bfloat16* vbase = vbt + (size_t)bk * HD_ * T_;
    int sce = (tid & 3) * 16;          // element offset for global side

    // prologue: stage tile 0 into buf0
    {
        short8 ra = *(const short8*)(kbase + (size_t)sr*HD_ + sce);
        short8 rb = *(const short8*)(kbase + (size_t)sr*HD_ + sce + 8);
        short8 rc = *(const short8*)(vbase + (size_t)sr*T_ + sce);
        short8 rd = *(const short8*)(vbase + (size_t)sr*T_ + sce + 8);
        *(short8*)((char*)Ks[0] + KSWZ(sr, scB))      = ra;
        *(short8*)((char*)Ks[0] + KSWZ(sr, scB + 16)) = rb;
        *(short8*)((char*)Vs[0] + KSWZ(sr, scB))      = rc;
        *(short8*)((char*)Vs[0] + KSWZ(sr, scB + 16)) = rd;
    }
    __syncthreads();
    int cur = 0;
    const int NT = T_ / 64;

    for (int it = 0; it < NT; ++it) {
        // issue next tile's global loads early (latency hides under this tile's compute)
        short8 ra, rb, rc, rd;
        bool pfv = (it + 1 < NT);
        if (pfv) {
            int s0n = (it + 1) * 64;
            ra = *(const short8*)(kbase + (size_t)(s0n + sr)*HD_ + sce);
            rb = *(const short8*)(kbase + (size_t)(s0n + sr)*HD_ + sce + 8);
            rc = *(const short8*)(vbase + (size_t)sr*T_ + s0n + sce);
            rd = *(const short8*)(vbase + (size_t)sr*T_ + s0n + sce + 8);
        }
        char* KsB = (char*)Ks[cur];
        char* VsB = (char*)Vs[cur];

        // S^T = K Q^T
        f32x4 accs[4];
#pragma unroll
        for (int cb = 0; cb < 4; ++cb) {
            f32x4 z = {0.f, 0.f, 0.f, 0.f};
            short8 k0 = *(const short8*)(KsB + KSWZ(cb*16 + l15, lhi*16));
            short8 k1 = *(const short8*)(KsB + KSWZ(cb*16 + l15, 64 + lhi*16));
            __builtin_amdgcn_s_setprio(1);
            z = __builtin_amdgcn_mfma_f32_16x16x32_bf16(k0, qf0, z, 0, 0, 0);
            z = __builtin_amdgcn_mfma_f32_16x16x32_bf16(k1, qf1, z, 0, 0, 0);
            __builtin_amdgcn_s_setprio(0);
            accs[cb] = z;
        }

        // tile max for q-row l15
        float mx = -INFINITY;
#pragma unroll
        for (int cb = 0; cb < 4; ++cb)
#pragma unroll
            for (int r = 0; r < 4; ++r) mx = fmaxf(mx, accs[cb][r]);
        mx = fmaxf(mx, __shfl_xor(mx, 16));
        mx = fmaxf(mx, __shfl_xor(mx, 32));

        // defer-max (THR=8): rescale only when tile max exceeds m_run + 8
        if (!__all(mx <= m_run + 8.0f)) {
            float mn = fmaxf(m_run, mx);
            float cr = __expf(m_run - mn);
            m_run = mn;
            l_run *= cr;
#pragma unroll
            for (int cb = 0; cb < 4; ++cb)
#pragma unroll
                for (int r = 0; r < 4; ++r) oacc[cb][r] *= cr;
        }

        float rs = 0.0f;
        int pr = w*16 + l15;               // per-wave P row
#pragma unroll
        for (int cb = 0; cb < 4; ++cb) {
            f32x4 p;
#pragma unroll
            for (int r = 0; r < 4; ++r) { p[r] = __expf(accs[cb][r] - m_run); rs += p[r]; }
            short4v pk = { (short)f2bu(p[0]), (short)f2bu(p[1]),
                           (short)f2bu(p[2]), (short)f2bu(p[3]) };
            *(short4v*)(PsB + KSWZ(pr, cb*32 + lhi*8)) = pk;
        }
        rs += __shfl_xor(rs, 16);
        rs += __shfl_xor(rs, 32);
        l_run += rs;

        // O^T += V^T P^T
#pragma unroll
        for (int kk = 0; kk < 2; ++kk) {
            short8 pf = *(const short8*)(PsB + KSWZ(w*16 + l15, kk*64 + lhi*16));
            __builtin_amdgcn_s_setprio(1);
#pragma unroll
            for (int cb = 0; cb < 4; ++cb) {
                short8 vf = *(const short8*)(VsB + KSWZ(cb*16 + l15, kk*64 + lhi*16));
                oacc[cb] = __builtin_amdgcn_mfma_f32_16x16x32_bf16(vf, pf, oacc[cb], 0, 0, 0);
            }
            __builtin_amdgcn_s_setprio(0);
        }

        // write next tile into the other buffer (last read at t-1, behind barrier -> safe)
        if (pfv) {
            char* KnB = (char*)Ks[cur ^ 1];
            char* VnB = (char*)Vs[cur ^ 1];
            *(short8*)(KnB + KSWZ(sr, scB))      = ra;
            *(short8*)(KnB + KSWZ(sr, scB + 16)) = rb;
            *(short8*)(VnB + KSWZ(sr, scB))      = rc;
            *(short8*)(VnB + KSWZ(sr, scB + 16)) = rd;
        }
        __syncthreads();   // writes visible + all waves done reading cur
        cur ^= 1;
    }

    float inv = 1.0f / l_run;
    int t = qt0 + w*16 + l15;
    __hip_bfloat16* orow = ob + (size_t)(b*T_ + t) * D_ + h*HD_;
#pragma unroll
    for (int cb = 0; cb < 4; ++cb) {
        short4v okv = { (short)f2bu(oacc[cb][0] * inv), (short)f2bu(oacc[cb][1] * inv),
                        (short)f2bu(oacc[cb][2] * inv), (short)f2bu(oacc[cb][3] * inv) };
        *(short4v*)&orow[cb*16 + lhi*4] = okv;
    }
}

extern "C" void kernel_launch(void* const* d_in, const int* in_sizes, int n_in,
                              void* d_out, int out_size, void* d_ws, size_t ws_size,
                              hipStream_t stream) {
    const float* x    = (const float*)d_in[0];
    const float* cosb = (const float*)d_in[1];
    const float* sinb = (const float*)d_in[2];
    const float* Wq   = (const float*)d_in[3];
    const float* Wkv  = (const float*)d_in[4];
    const float* Wo   = (const float*)d_in[5];
    const float* ln1g = (const float*)d_in[6];
    const float* ln1b = (const float*)d_in[7];
    const float* ln2g = (const float*)d_in[8];
    const float* ln2b = (const float*)d_in[9];
    const float* W1   = (const float*)d_in[10];
    const float* b1   = (const float*)d_in[11];
    const float* W2   = (const float*)d_in[12];
    const float* b2   = (const float*)d_in[13];
    float* out = (float*)d_out;

    float* ws = (float*)d_ws;
    const size_t M = 1024 * 1024;
    __hip_bfloat16* hb   = (__hip_bfloat16*)(ws);
    float*          x2   = ws + 4*M;
    __hip_bfloat16* gbuf = (__hip_bfloat16*)(ws + 12*M);
    __hip_bfloat16* ob   = (__hip_bfloat16*)(ws + 20*M);
    __hip_bfloat16* qb   = (__hip_bfloat16*)(ws + 24*M);
    __hip_bfloat16* kbb  = (__hip_bfloat16*)(ws + 28*M);
    __hip_bfloat16* vbt  = (__hip_bfloat16*)(ws + 29*M);
    __hip_bfloat16* Wqkvb= (__hip_bfloat16*)(ws + 30*M);
    __hip_bfloat16* Wob  = (__hip_bfloat16*)(ws + 30*M + 3*M/4);
    __hip_bfloat16* W1b  = (__hip_bfloat16*)(ws + 31*M + M/4);
    __hip_bfloat16* W2b  = (__hip_bfloat16*)(ws + 32*M + M/4);

    // 0. all weight casts in one kernel (1703936 quads)
    castw_all<<<(1703936 + 255)/256, 256, 0, stream>>>(Wq, Wkv, Wo, W1, W2,
                                                       Wqkvb, Wob, W1b, W2b);

    // 1. LN1 -> hb (bf16)
    ln_bf16<<<R_, 256, 0, stream>>>(x, ln1g, ln1b, hb);
    // 2+3. qkv GEMM with fused RoPE -> qb/kbb/vbt (bf16), XCD-swizzled 1D grid (768 blocks)
    gemm_qkv_rope<<<(QKVW/128)*(R_/128), 256, 0, stream>>>(hb, Wqkvb, cosb, sinb, qb, kbb, vbt);
    // 4. attention -> ob (bf16)
    attn_mfma<<<dim3(T_/64, B_*QH), 256, 0, stream>>>(qb, kbb, vbt, ob);
    // 5. x2 = x + ob @ Wob^T (512 blocks)
    gemm_mfma<1><<<(D_/128)*(R_/128), 256, 0, stream>>>(ob, Wob, nullptr, x, x2, nullptr, R_, D_, D_);
    // 6. LN2 -> hb (bf16)
    ln_bf16<<<R_, 256, 0, stream>>>(x2, ln2g, ln2b, hb);
    // 7. gbuf = gelu(hb @ W1b^T + b1) (bf16 out, 1024 blocks)
    gemm_mfma<2><<<(DFF/128)*(R_/128), 256, 0, stream>>>(hb, W1b, b1, nullptr, nullptr, gbuf, R_, DFF, D_);
    // 8. out = x2 + gbuf @ W2b^T + b2 (512 blocks)
    gemm_mfma<3><<<(D_/128)*(R_/128), 256, 0, stream>>>(gbuf, W2b, b2, x2, out, nullptr, R_, D_, DFF);
}

// Round 19
// 352.325 us; speedup vs baseline: 1.1685x; 1.0191x over previous
//
#include <hip/hip_runtime.h>
#include <hip/hip_bf16.h>
#include <math.h>
#include <stdint.h>

#define B_   4
#define T_   2048
#define D_   1024
#define QH   16
#define KVH  4
#define HD_  64
#define R_   (B_*T_)      // 8192 rows
#define DFF  2048
#define QKVW 1536         // fused q(1024) + kv(512) output width

typedef short short8 __attribute__((ext_vector_type(8)));
typedef short short4v __attribute__((ext_vector_type(4)));
typedef float f32x4 __attribute__((ext_vector_type(4)));

static __device__ __forceinline__ unsigned short f2bu(float x) {
    __hip_bfloat16 h = __float2bfloat16(x);
    return *reinterpret_cast<unsigned short*>(&h);
}

// swizzled byte offset within a [64][64]-bf16 (128B/row) LDS tile
#define KSWZ(row, cbyte) (((row) << 7) + ((cbyte) ^ (((row) & 7) << 4)))

__device__ __forceinline__ void gload_lds16(const void* g, void* l) {
    typedef __attribute__((address_space(1))) void gv_t;
    typedef __attribute__((address_space(3))) void lv_t;
    __builtin_amdgcn_global_load_lds((gv_t*)g, (lv_t*)l, 16, 0, 0);
}

// XCD-aware linear block swizzle (requires nwg % 8 == 0)
__device__ __forceinline__ int xcd_swz(int bid, int nwg) {
    int cpx = nwg >> 3;
    return (bid & 7) * cpx + (bid >> 3);
}

// ---------------- all weights f32 -> bf16, one kernel ----------------
__global__ __launch_bounds__(256) void castw_all(const float* __restrict__ Wq,
                                                 const float* __restrict__ Wkv,
                                                 const float* __restrict__ Wo,
                                                 const float* __restrict__ W1,
                                                 const float* __restrict__ W2,
                                                 __hip_bfloat16* __restrict__ dqkv,
                                                 __hip_bfloat16* __restrict__ dWo,
                                                 __hip_bfloat16* __restrict__ dW1,
                                                 __hip_bfloat16* __restrict__ dW2) {
    int i = blockIdx.x * 256 + threadIdx.x;   // quad index, total 1703936
    const float* src; __hip_bfloat16* dst; int off;
    if (i < 262144)       { src = Wq;  dst = dqkv;            off = i; }
    else if (i < 393216)  { src = Wkv; dst = dqkv + 1048576;  off = i - 262144; }
    else if (i < 655360)  { src = Wo;  dst = dWo;             off = i - 393216; }
    else if (i < 1179648) { src = W1;  dst = dW1;             off = i - 655360; }
    else                  { src = W2;  dst = dW2;             off = i - 1179648; }
    float4 v = *(const float4*)&src[(size_t)off*4];
    ushort4 o = { f2bu(v.x), f2bu(v.y), f2bu(v.z), f2bu(v.w) };
    *(ushort4*)&dst[(size_t)off*4] = o;
}

// ---------------- LayerNorm -> bf16 out: one block per row ----------------
__global__ __launch_bounds__(256) void ln_bf16(const float* __restrict__ x,
                                               const float* __restrict__ g,
                                               const float* __restrict__ bta,
                                               __hip_bfloat16* __restrict__ out) {
    int row = blockIdx.x;
    int tid = threadIdx.x;
    const float* xr = x + (size_t)row * D_;
    int c = tid * 4;
    float4 v = *(const float4*)&xr[c];
    float s = v.x + v.y + v.z + v.w;
#pragma unroll
    for (int off = 32; off >= 1; off >>= 1) s += __shfl_xor(s, off);
    __shared__ float sm[4], sv[4];
    int wid = tid >> 6, lane = tid & 63;
    if (lane == 0) sm[wid] = s;
    __syncthreads();
    float mean = (sm[0] + sm[1] + sm[2] + sm[3]) * (1.0f / D_);
    float d0 = v.x - mean, d1 = v.y - mean, d2 = v.z - mean, d3 = v.w - mean;
    float qq = d0*d0 + d1*d1 + d2*d2 + d3*d3;
#pragma unroll
    for (int off = 32; off >= 1; off >>= 1) qq += __shfl_xor(qq, off);
    if (lane == 0) sv[wid] = qq;
    __syncthreads();
    float var = (sv[0] + sv[1] + sv[2] + sv[3]) * (1.0f / D_);
    float rstd = rsqrtf(var + 1e-5f);
    float4 gg = *(const float4*)&g[c];
    float4 bb = *(const float4*)&bta[c];
    ushort4 o = { f2bu(d0 * rstd * gg.x + bb.x),
                  f2bu(d1 * rstd * gg.y + bb.y),
                  f2bu(d2 * rstd * gg.z + bb.z),
                  f2bu(d3 * rstd * gg.w + bb.w) };
    *(ushort4*)&(out + (size_t)row * D_)[c] = o;
}

// ---------------- bf16 MFMA GEMM: C = res + act(A(MxK) * W(NxK)^T + bias) ----------------
// 1D grid with XCD swizzle. MODE: 1 +res f32; 2 +bias,gelu -> bf16; 3 +bias,+res f32
template<int MODE>
__global__ __launch_bounds__(256) void gemm_mfma(const __hip_bfloat16* __restrict__ A,
                                                 const __hip_bfloat16* __restrict__ W,
                                                 const float* __restrict__ bias,
                                                 const float* __restrict__ res,
                                                 float* __restrict__ Cf,
                                                 __hip_bfloat16* __restrict__ Cb,
                                                 int M, int N, int K) {
    __shared__ __hip_bfloat16 At[128*32];
    __shared__ __hip_bfloat16 Bt[128*32];
    int tid = threadIdx.x;
    int w = tid >> 6, lane = tid & 63;
    int l15 = lane & 15, lhi = lane >> 4;
    int swz = xcd_swz(blockIdx.x, gridDim.x);
    int gx = N >> 7;
    int bn = (swz % gx) * 128, bm = (swz / gx) * 128;
    int wr = w >> 1, wc = w & 1;
    f32x4 acc[4][4] = {};

    for (int k0 = 0; k0 < K; k0 += 32) {
#pragma unroll
        for (int iss = 0; iss < 2; ++iss) {
            int off = (iss*256 + tid) * 8;     // element offset in 128x32 tile
            int row = off >> 5, col = off & 31;
            gload_lds16(A + (size_t)(bm + row) * K + k0 + col, &At[off]);
            gload_lds16(W + (size_t)(bn + row) * K + k0 + col, &Bt[off]);
        }
        __syncthreads();
        short8 af[4], bf[4];
#pragma unroll
        for (int m = 0; m < 4; ++m) af[m] = *(const short8*)&At[(wr*64 + m*16 + l15)*32 + lhi*8];
#pragma unroll
        for (int n = 0; n < 4; ++n) bf[n] = *(const short8*)&Bt[(wc*64 + n*16 + l15)*32 + lhi*8];
#pragma unroll
        for (int m = 0; m < 4; ++m)
#pragma unroll
            for (int n = 0; n < 4; ++n)
                acc[m][n] = __builtin_amdgcn_mfma_f32_16x16x32_bf16(af[m], bf[n], acc[m][n], 0, 0, 0);
        __syncthreads();
    }

#pragma unroll
    for (int m = 0; m < 4; ++m) {
#pragma unroll
        for (int j = 0; j < 4; ++j) {
            int row = bm + wr*64 + m*16 + lhi*4 + j;
#pragma unroll
            for (int n = 0; n < 4; ++n) {
                int col = bn + wc*64 + n*16 + l15;
                float val = acc[m][n][j];
                if (MODE == 2 || MODE == 3) val += bias[col];
                if (MODE == 2) val = 0.5f * val * (1.0f + erff(val * 0.70710678118654752f));
                if (MODE == 1 || MODE == 3) val += res[(size_t)row * N + col];
                if (MODE == 2) Cb[(size_t)row * N + col] = __float2bfloat16(val);
                else           Cf[(size_t)row * N + col] = val;
            }
        }
    }
}

// ---------------- QKV GEMM with fused RoPE epilogue (1D grid, XCD swizzle) ----------------
__global__ __launch_bounds__(256) void gemm_qkv_rope(const __hip_bfloat16* __restrict__ A,
                                                     const __hip_bfloat16* __restrict__ W,
                                                     const float* __restrict__ cosb,
                                                     const float* __restrict__ sinb,
                                                     __hip_bfloat16* __restrict__ qb,
                                                     __hip_bfloat16* __restrict__ kbb,
                                                     __hip_bfloat16* __restrict__ vbt) {
    const int K = D_;
    __shared__ __hip_bfloat16 At[128*32];
    __shared__ __hip_bfloat16 Bt[128*32];
    int tid = threadIdx.x;
    int w = tid >> 6, lane = tid & 63;
    int l15 = lane & 15, lhi = lane >> 4;
    int swz = xcd_swz(blockIdx.x, gridDim.x);
    const int gx = QKVW >> 7;   // 12
    int bn = (swz % gx) * 128, bm = (swz / gx) * 128;
    int wr = w >> 1, wc = w & 1;
    f32x4 acc[4][4] = {};

    for (int k0 = 0; k0 < K; k0 += 32) {
#pragma unroll
        for (int iss = 0; iss < 2; ++iss) {
            int off = (iss*256 + tid) * 8;
            int row = off >> 5, col = off & 31;
            gload_lds16(A + (size_t)(bm + row) * K + k0 + col, &At[off]);
            gload_lds16(W + (size_t)(bn + row) * K + k0 + col, &Bt[off]);
        }
        __syncthreads();
        short8 af[4], bf[4];
#pragma unroll
        for (int m = 0; m < 4; ++m) af[m] = *(const short8*)&At[(wr*64 + m*16 + l15)*32 + lhi*8];
#pragma unroll
        for (int n = 0; n < 4; ++n) bf[n] = *(const short8*)&Bt[(wc*64 + n*16 + l15)*32 + lhi*8];
#pragma unroll
        for (int m = 0; m < 4; ++m)
#pragma unroll
            for (int n = 0; n < 4; ++n)
                acc[m][n] = __builtin_amdgcn_mfma_f32_16x16x32_bf16(af[m], bf[n], acc[m][n], 0, 0, 0);
        __syncthreads();
    }

    bool is_q = (bn < 1024);
    bool is_v = (!is_q) && (wc == 1);   // wave-uniform
    if (!is_v) {
#pragma unroll
        for (int m = 0; m < 4; ++m) {
#pragma unroll
            for (int j = 0; j < 4; ++j) {
                int row = bm + wr*64 + m*16 + lhi*4 + j;
                int b = row >> 11, t = row & (T_ - 1);
                const float* crow = cosb + t*HD_;
                const float* srow = sinb + t*HD_;
#pragma unroll
                for (int n = 0; n < 4; ++n) {
                    int col = bn + wc*64 + n*16 + l15;
                    int hd = n*16 + l15;
                    float val = acc[m][n][j];
                    float part = __shfl_xor(val, 1);
                    float rot = (l15 & 1) ? part : -part;
                    float o = val * crow[hd] + rot * srow[hd];
                    if (is_q) {
                        int h = col >> 6;
                        qb[(((size_t)(b*QH + h))*T_ + t)*HD_ + hd] = __float2bfloat16(o * 0.125f);
                    } else {
                        int kvh = (col - 1024) >> 7;
                        kbb[(((size_t)(b*KVH + kvh))*T_ + t)*HD_ + hd] = __float2bfloat16(o);
                    }
                }
            }
        }
    } else {
#pragma unroll
        for (int m = 0; m < 4; ++m) {
            int row0 = bm + wr*64 + m*16 + lhi*4;
            int b = row0 >> 11, t0 = row0 & (T_ - 1);
#pragma unroll
            for (int n = 0; n < 4; ++n) {
                int col = bn + 64 + n*16 + l15;
                int kvh = (col - 1024) >> 7;
                int hd = n*16 + l15;
                short4v pk = { (short)f2bu(acc[m][n][0]), (short)f2bu(acc[m][n][1]),
                               (short)f2bu(acc[m][n][2]), (short)f2bu(acc[m][n][3]) };
                *(short4v*)&vbt[(((size_t)(b*KVH + kvh))*HD_ + hd)*T_ + t0] = pk;
            }
        }
    }
}

// ---------------- Flash attention: R18 structure + predicate-only defer-max + deferred l ----------
// QBLK=64 (4 waves x 16 q-rows), KVBLK=64, swapped MFMA operands, swizzled LDS, setprio.
// Reg-staged async split: tile t+1's loads issued at top of tile t; ds_write after PV.
// Common path has ZERO cross-lane shuffles: defer-max predicate uses per-lane local max
// (group-max <= thr iff all local max <= thr); l is accumulated per-lane (l_part) and
// group-reduced once after the loop. Rescale path (rare) does the exact group-max reduce.
__global__ __launch_bounds__(256) void attn_mfma(const __hip_bfloat16* __restrict__ qb,
                                                 const __hip_bfloat16* __restrict__ kb,
                                                 const __hip_bfloat16* __restrict__ vbt,
                                                 __hip_bfloat16* __restrict__ ob) {
    __shared__ __hip_bfloat16 Ks[2][64*64];   // [key][d]   swizzled
    __shared__ __hip_bfloat16 Vs[2][64*64];   // [d][key]   swizzled
    __shared__ __hip_bfloat16 Ps[64*64];      // [qrow][key] swizzled, per-wave rows
    char* PsB = (char*)Ps;
    int tid = threadIdx.x;
    int w = tid >> 6, lane = tid & 63;
    int l15 = lane & 15, lhi = lane >> 4;
    int bh = blockIdx.y;
    int b = bh >> 4, h = bh & 15;
    int bk = b * KVH + (h >> 2);
    int qt0 = blockIdx.x * 64;

    const __hip_bfloat16* qrow = qb + ((size_t)bh * T_ + qt0 + w*16 + l15) * HD_;
    short8 qf0 = *(const short8*)(qrow + lhi*8);
    short8 qf1 = *(const short8*)(qrow + 32 + lhi*8);

    f32x4 oacc[4] = {};          // O^T[d=cb*16+lhi*4+r][qrow=l15]
    float m_run = -INFINITY, l_part = 0.0f;

    int sr = tid >> 2;                 // staging row 0..63
    int scB = (tid & 3) * 32;          // staging col byte {0,32,64,96}
    const __hip_bfloat16* kbase = kb  + (size_t)bk * T_ * HD_;
    const __hip_bfloat16* vbase = vbt + (size_t)bk * HD_ * T_;
    int sce = (tid & 3) * 16;          // element offset for global side

    // prologue: stage tile 0 into buf0
    {
        short8 ra = *(const short8*)(kbase + (size_t)sr*HD_ + sce);
        short8 rb = *(const short8*)(kbase + (size_t)sr*HD_ + sce + 8);
        short8 rc = *(const short8*)(vbase + (size_t)sr*T_ + sce);
        short8 rd = *(const short8*)(vbase + (size_t)sr*T_ + sce + 8);
        *(short8*)((char*)Ks[0] + KSWZ(sr, scB))      = ra;
        *(short8*)((char*)Ks[0] + KSWZ(sr, scB + 16)) = rb;
        *(short8*)((char*)Vs[0] + KSWZ(sr, scB))      = rc;
        *(short8*)((char*)Vs[0] + KSWZ(sr, scB + 16)) = rd;
    }
    __syncthreads();
    int cur = 0;
    const int NT = T_ / 64;

    for (int it = 0; it < NT; ++it) {
        // issue next tile's global loads early (latency hides under this tile's compute)
        short8 ra, rb, rc, rd;
        bool pfv = (it + 1 < NT);
        if (pfv) {
            int s0n = (it + 1) * 64;
            ra = *(const short8*)(kbase + (size_t)(s0n + sr)*HD_ + sce);
            rb = *(const short8*)(kbase + (size_t)(s0n + sr)*HD_ + sce + 8);
            rc = *(const short8*)(vbase + (size_t)sr*T_ + s0n + sce);
            rd = *(const short8*)(vbase + (size_t)sr*T_ + s0n + sce + 8);
        }
        char* KsB = (char*)Ks[cur];
        char* VsB = (char*)Vs[cur];

        // S^T = K Q^T
        f32x4 accs[4];
#pragma unroll
        for (int cb = 0; cb < 4; ++cb) {
            f32x4 z = {0.f, 0.f, 0.f, 0.f};
            short8 k0 = *(const short8*)(KsB + KSWZ(cb*16 + l15, lhi*16));
            short8 k1 = *(const short8*)(KsB + KSWZ(cb*16 + l15, 64 + lhi*16));
            __builtin_amdgcn_s_setprio(1);
            z = __builtin_amdgcn_mfma_f32_16x16x32_bf16(k0, qf0, z, 0, 0, 0);
            z = __builtin_amdgcn_mfma_f32_16x16x32_bf16(k1, qf1, z, 0, 0, 0);
            __builtin_amdgcn_s_setprio(0);
            accs[cb] = z;
        }

        // per-lane local max over this lane's 16 scores (no cross-lane reduce in common path)
        float mxl = -INFINITY;
#pragma unroll
        for (int cb = 0; cb < 4; ++cb)
#pragma unroll
            for (int r = 0; r < 4; ++r) mxl = fmaxf(mxl, accs[cb][r]);

        // defer-max (THR=8): group-max <= thr iff all lanes' local max <= thr
        if (!__all(mxl <= m_run + 8.0f)) {
            float mx = mxl;                         // exact group max (rare path)
            mx = fmaxf(mx, __shfl_xor(mx, 16));
            mx = fmaxf(mx, __shfl_xor(mx, 32));
            float mn = fmaxf(m_run, mx);
            float cr = __expf(m_run - mn);
            m_run = mn;
            l_part *= cr;
#pragma unroll
            for (int cb = 0; cb < 4; ++cb)
#pragma unroll
                for (int r = 0; r < 4; ++r) oacc[cb][r] *= cr;
        }

        int pr = w*16 + l15;               // per-wave P row
#pragma unroll
        for (int cb = 0; cb < 4; ++cb) {
            f32x4 p;
#pragma unroll
            for (int r = 0; r < 4; ++r) { p[r] = __expf(accs[cb][r] - m_run); l_part += p[r]; }
            short4v pk = { (short)f2bu(p[0]), (short)f2bu(p[1]),
                           (short)f2bu(p[2]), (short)f2bu(p[3]) };
            *(short4v*)(PsB + KSWZ(pr, cb*32 + lhi*8)) = pk;
        }
        // no per-tile l reduce: deferred to after the loop

        // O^T += V^T P^T
#pragma unroll
        for (int kk = 0; kk < 2; ++kk) {
            short8 pf = *(const short8*)(PsB + KSWZ(w*16 + l15, kk*64 + lhi*16));
            __builtin_amdgcn_s_setprio(1);
#pragma unroll
            for (int cb = 0; cb < 4; ++cb) {
                short8 vf = *(const short8*)(VsB + KSWZ(cb*16 + l15, kk*64 + lhi*16));
                oacc[cb] = __builtin_amdgcn_mfma_f32_16x16x32_bf16(vf, pf, oacc[cb], 0, 0, 0);
            }
            __builtin_amdgcn_s_setprio(0);
        }

        // write next tile into the other buffer (last read at t-1, behind barrier -> safe)
        if (pfv) {
            char* KnB = (char*)Ks[cur ^ 1];
            char* VnB = (char*)Vs[cur ^ 1];
            *(short8*)(KnB + KSWZ(sr, scB))      = ra;
            *(short8*)(KnB + KSWZ(sr, scB + 16)) = rb;
            *(short8*)(VnB + KSWZ(sr, scB))      = rc;
            *(short8*)(VnB + KSWZ(sr, scB + 16)) = rd;
        }
        __syncthreads();   // writes visible + all waves done reading cur
        cur ^= 1;
    }

    // final l reduction across the 4-lane group (xor 16, 32)
    float l_run = l_part;
    l_run += __shfl_xor(l_run, 16);
    l_run += __shfl_xor(l_run, 32);

    float inv = 1.0f / l_run;
    int t = qt0 + w*16 + l15;
    __hip_bfloat16* orow = ob + (size_t)(b*T_ + t) * D_ + h*HD_;
#pragma unroll
    for (int cb = 0; cb < 4; ++cb) {
        short4v okv = { (short)f2bu(oacc[cb][0] * inv), (short)f2bu(oacc[cb][1] * inv),
                        (short)f2bu(oacc[cb][2] * inv), (short)f2bu(oacc[cb][3] * inv) };
        *(short4v*)&orow[cb*16 + lhi*4] = okv;
    }
}

extern "C" void kernel_launch(void* const* d_in, const int* in_sizes, int n_in,
                              void* d_out, int out_size, void* d_ws, size_t ws_size,
                              hipStream_t stream) {
    const float* x    = (const float*)d_in[0];
    const float* cosb = (const float*)d_in[1];
    const float* sinb = (const float*)d_in[2];
    const float* Wq   = (const float*)d_in[3];
    const float* Wkv  = (const float*)d_in[4];
    const float* Wo   = (const float*)d_in[5];
    const float* ln1g = (const float*)d_in[6];
    const float* ln1b = (const float*)d_in[7];
    const float* ln2g = (const float*)d_in[8];
    const float* ln2b = (const float*)d_in[9];
    const float* W1   = (const float*)d_in[10];
    const float* b1   = (const float*)d_in[11];
    const float* W2   = (const float*)d_in[12];
    const float* b2   = (const float*)d_in[13];
    float* out = (float*)d_out;

    float* ws = (float*)d_ws;
    const size_t M = 1024 * 1024;
    __hip_bfloat16* hb   = (__hip_bfloat16*)(ws);
    float*          x2   = ws + 4*M;
    __hip_bfloat16* gbuf = (__hip_bfloat16*)(ws + 12*M);
    __hip_bfloat16* ob   = (__hip_bfloat16*)(ws + 20*M);
    __hip_bfloat16* qb   = (__hip_bfloat16*)(ws + 24*M);
    __hip_bfloat16* kbb  = (__hip_bfloat16*)(ws + 28*M);
    __hip_bfloat16* vbt  = (__hip_bfloat16*)(ws + 29*M);
    __hip_bfloat16* Wqkvb= (__hip_bfloat16*)(ws + 30*M);
    __hip_bfloat16* Wob  = (__hip_bfloat16*)(ws + 30*M + 3*M/4);
    __hip_bfloat16* W1b  = (__hip_bfloat16*)(ws + 31*M + M/4);
    __hip_bfloat16* W2b  = (__hip_bfloat16*)(ws + 32*M + M/4);

    // 0. all weight casts in one kernel (1703936 quads)
    castw_all<<<(1703936 + 255)/256, 256, 0, stream>>>(Wq, Wkv, Wo, W1, W2,
                                                       Wqkvb, Wob, W1b, W2b);

    // 1. LN1 -> hb (bf16)
    ln_bf16<<<R_, 256, 0, stream>>>(x, ln1g, ln1b, hb);
    // 2+3. qkv GEMM with fused RoPE -> qb/kbb/vbt (bf16), XCD-swizzled 1D grid (768 blocks)
    gemm_qkv_rope<<<(QKVW/128)*(R_/128), 256, 0, stream>>>(hb, Wqkvb, cosb, sinb, qb, kbb, vbt);
    // 4. attention -> ob (bf16)
    attn_mfma<<<dim3(T_/64, B_*QH), 256, 0, stream>>>(qb, kbb, vbt, ob);
    // 5. x2 = x + ob @ Wob^T (512 blocks)
    gemm_mfma<1><<<(D_/128)*(R_/128), 256, 0, stream>>>(ob, Wob, nullptr, x, x2, nullptr, R_, D_, D_);
    // 6. LN2 -> hb (bf16)
    ln_bf16<<<R_, 256, 0, stream>>>(x2, ln2g, ln2b, hb);
    // 7. gbuf = gelu(hb @ W1b^T + b1) (bf16 out, 1024 blocks)
    gemm_mfma<2><<<(DFF/128)*(R_/128), 256, 0, stream>>>(hb, W1b, b1, nullptr, nullptr, gbuf, R_, DFF, D_);
    // 8. out = x2 + gbuf @ W2b^T + b2 (512 blocks)
    gemm_mfma<3><<<(D_/128)*(R_/128), 256, 0, stream>>>(gbuf, W2b, b2, x2, out, nullptr, R_, D_, DFF);
}

// Round 20
// 349.057 us; speedup vs baseline: 1.1794x; 1.0094x over previous
//
#include <hip/hip_runtime.h>
#include <hip/hip_bf16.h>
#include <math.h>
#include <stdint.h>

#define B_   4
#define T_   2048
#define D_   1024
#define QH   16
#define KVH  4
#define HD_  64
#define R_   (B_*T_)      // 8192 rows
#define DFF  2048
#define QKVW 1536         // fused q(1024) + kv(512) output width

typedef short short8 __attribute__((ext_vector_type(8)));
typedef short short4v __attribute__((ext_vector_type(4)));
typedef float f32x4 __attribute__((ext_vector_type(4)));

static __device__ __forceinline__ unsigned short f2bu(float x) {
    __hip_bfloat16 h = __float2bfloat16(x);
    return *reinterpret_cast<unsigned short*>(&h);
}

// swizzled byte offset within a [64][64]-bf16 (128B/row) LDS tile
#define KSWZ(row, cbyte) (((row) << 7) + ((cbyte) ^ (((row) & 7) << 4)))

__device__ __forceinline__ void gload_lds16(const void* g, void* l) {
    typedef __attribute__((address_space(1))) void gv_t;
    typedef __attribute__((address_space(3))) void lv_t;
    __builtin_amdgcn_global_load_lds((gv_t*)g, (lv_t*)l, 16, 0, 0);
}

// XCD-aware linear block swizzle (requires nwg % 8 == 0)
__device__ __forceinline__ int xcd_swz(int bid, int nwg) {
    int cpx = nwg >> 3;
    return (bid & 7) * cpx + (bid >> 3);
}

// ---------------- prologue: weight casts (blocks [0,6656)) + LN1 (blocks [6656,14848)) --------
// cast quad prefix ranges: Wq 262144 | Wkv 131072 | Wo 262144 | W1 524288 | W2 524288
__global__ __launch_bounds__(256) void prologue_cast_ln(const float* __restrict__ Wq,
                                                        const float* __restrict__ Wkv,
                                                        const float* __restrict__ Wo,
                                                        const float* __restrict__ W1,
                                                        const float* __restrict__ W2,
                                                        __hip_bfloat16* __restrict__ dqkv,
                                                        __hip_bfloat16* __restrict__ dWo,
                                                        __hip_bfloat16* __restrict__ dW1,
                                                        __hip_bfloat16* __restrict__ dW2,
                                                        const float* __restrict__ x,
                                                        const float* __restrict__ g,
                                                        const float* __restrict__ bta,
                                                        __hip_bfloat16* __restrict__ hb) {
    int tid = threadIdx.x;
    if (blockIdx.x < 6656) {
        int i = blockIdx.x * 256 + tid;   // quad index, total exactly 6656*256 = 1703936
        const float* src; __hip_bfloat16* dst; int off;
        if (i < 262144)       { src = Wq;  dst = dqkv;            off = i; }
        else if (i < 393216)  { src = Wkv; dst = dqkv + 1048576;  off = i - 262144; }
        else if (i < 655360)  { src = Wo;  dst = dWo;             off = i - 393216; }
        else if (i < 1179648) { src = W1;  dst = dW1;             off = i - 655360; }
        else                  { src = W2;  dst = dW2;             off = i - 1179648; }
        float4 v = *(const float4*)&src[(size_t)off*4];
        ushort4 o = { f2bu(v.x), f2bu(v.y), f2bu(v.z), f2bu(v.w) };
        *(ushort4*)&dst[(size_t)off*4] = o;
        return;
    }
    int row = blockIdx.x - 6656;
    const float* xr = x + (size_t)row * D_;
    int c = tid * 4;
    float4 v = *(const float4*)&xr[c];
    float s = v.x + v.y + v.z + v.w;
#pragma unroll
    for (int off = 32; off >= 1; off >>= 1) s += __shfl_xor(s, off);
    __shared__ float sm[4], sv[4];
    int wid = tid >> 6, lane = tid & 63;
    if (lane == 0) sm[wid] = s;
    __syncthreads();
    float mean = (sm[0] + sm[1] + sm[2] + sm[3]) * (1.0f / D_);
    float d0 = v.x - mean, d1 = v.y - mean, d2 = v.z - mean, d3 = v.w - mean;
    float qq = d0*d0 + d1*d1 + d2*d2 + d3*d3;
#pragma unroll
    for (int off = 32; off >= 1; off >>= 1) qq += __shfl_xor(qq, off);
    if (lane == 0) sv[wid] = qq;
    __syncthreads();
    float var = (sv[0] + sv[1] + sv[2] + sv[3]) * (1.0f / D_);
    float rstd = rsqrtf(var + 1e-5f);
    float4 gg = *(const float4*)&g[c];
    float4 bb = *(const float4*)&bta[c];
    ushort4 o = { f2bu(d0 * rstd * gg.x + bb.x),
                  f2bu(d1 * rstd * gg.y + bb.y),
                  f2bu(d2 * rstd * gg.z + bb.z),
                  f2bu(d3 * rstd * gg.w + bb.w) };
    *(ushort4*)&(hb + (size_t)row * D_)[c] = o;
}

// ---------------- LayerNorm -> bf16 out: one block per row ----------------
__global__ __launch_bounds__(256) void ln_bf16(const float* __restrict__ x,
                                               const float* __restrict__ g,
                                               const float* __restrict__ bta,
                                               __hip_bfloat16* __restrict__ out) {
    int row = blockIdx.x;
    int tid = threadIdx.x;
    const float* xr = x + (size_t)row * D_;
    int c = tid * 4;
    float4 v = *(const float4*)&xr[c];
    float s = v.x + v.y + v.z + v.w;
#pragma unroll
    for (int off = 32; off >= 1; off >>= 1) s += __shfl_xor(s, off);
    __shared__ float sm[4], sv[4];
    int wid = tid >> 6, lane = tid & 63;
    if (lane == 0) sm[wid] = s;
    __syncthreads();
    float mean = (sm[0] + sm[1] + sm[2] + sm[3]) * (1.0f / D_);
    float d0 = v.x - mean, d1 = v.y - mean, d2 = v.z - mean, d3 = v.w - mean;
    float qq = d0*d0 + d1*d1 + d2*d2 + d3*d3;
#pragma unroll
    for (int off = 32; off >= 1; off >>= 1) qq += __shfl_xor(qq, off);
    if (lane == 0) sv[wid] = qq;
    __syncthreads();
    float var = (sv[0] + sv[1] + sv[2] + sv[3]) * (1.0f / D_);
    float rstd = rsqrtf(var + 1e-5f);
    float4 gg = *(const float4*)&g[c];
    float4 bb = *(const float4*)&bta[c];
    ushort4 o = { f2bu(d0 * rstd * gg.x + bb.x),
                  f2bu(d1 * rstd * gg.y + bb.y),
                  f2bu(d2 * rstd * gg.z + bb.z),
                  f2bu(d3 * rstd * gg.w + bb.w) };
    *(ushort4*)&(out + (size_t)row * D_)[c] = o;
}

// ---------------- bf16 MFMA GEMM: C = res + act(A(MxK) * W(NxK)^T + bias) ----------------
// 1D grid with XCD swizzle. MODE: 1 +res f32; 2 +bias,gelu -> bf16; 3 +bias,+res f32
template<int MODE>
__global__ __launch_bounds__(256) void gemm_mfma(const __hip_bfloat16* __restrict__ A,
                                                 const __hip_bfloat16* __restrict__ W,
                                                 const float* __restrict__ bias,
                                                 const float* __restrict__ res,
                                                 float* __restrict__ Cf,
                                                 __hip_bfloat16* __restrict__ Cb,
                                                 int M, int N, int K) {
    __shared__ __hip_bfloat16 At[128*32];
    __shared__ __hip_bfloat16 Bt[128*32];
    int tid = threadIdx.x;
    int w = tid >> 6, lane = tid & 63;
    int l15 = lane & 15, lhi = lane >> 4;
    int swz = xcd_swz(blockIdx.x, gridDim.x);
    int gx = N >> 7;
    int bn = (swz % gx) * 128, bm = (swz / gx) * 128;
    int wr = w >> 1, wc = w & 1;
    f32x4 acc[4][4] = {};

    for (int k0 = 0; k0 < K; k0 += 32) {
#pragma unroll
        for (int iss = 0; iss < 2; ++iss) {
            int off = (iss*256 + tid) * 8;     // element offset in 128x32 tile
            int row = off >> 5, col = off & 31;
            gload_lds16(A + (size_t)(bm + row) * K + k0 + col, &At[off]);
            gload_lds16(W + (size_t)(bn + row) * K + k0 + col, &Bt[off]);
        }
        __syncthreads();
        short8 af[4], bf[4];
#pragma unroll
        for (int m = 0; m < 4; ++m) af[m] = *(const short8*)&At[(wr*64 + m*16 + l15)*32 + lhi*8];
#pragma unroll
        for (int n = 0; n < 4; ++n) bf[n] = *(const short8*)&Bt[(wc*64 + n*16 + l15)*32 + lhi*8];
#pragma unroll
        for (int m = 0; m < 4; ++m)
#pragma unroll
            for (int n = 0; n < 4; ++n)
                acc[m][n] = __builtin_amdgcn_mfma_f32_16x16x32_bf16(af[m], bf[n], acc[m][n], 0, 0, 0);
        __syncthreads();
    }

#pragma unroll
    for (int m = 0; m < 4; ++m) {
#pragma unroll
        for (int j = 0; j < 4; ++j) {
            int row = bm + wr*64 + m*16 + lhi*4 + j;
#pragma unroll
            for (int n = 0; n < 4; ++n) {
                int col = bn + wc*64 + n*16 + l15;
                float val = acc[m][n][j];
                if (MODE == 2 || MODE == 3) val += bias[col];
                if (MODE == 2) val = 0.5f * val * (1.0f + erff(val * 0.70710678118654752f));
                if (MODE == 1 || MODE == 3) val += res[(size_t)row * N + col];
                if (MODE == 2) Cb[(size_t)row * N + col] = __float2bfloat16(val);
                else           Cf[(size_t)row * N + col] = val;
            }
        }
    }
}

// ---------------- QKV GEMM with fused RoPE epilogue (1D grid, XCD swizzle) ----------------
__global__ __launch_bounds__(256) void gemm_qkv_rope(const __hip_bfloat16* __restrict__ A,
                                                     const __hip_bfloat16* __restrict__ W,
                                                     const float* __restrict__ cosb,
                                                     const float* __restrict__ sinb,
                                                     __hip_bfloat16* __restrict__ qb,
                                                     __hip_bfloat16* __restrict__ kbb,
                                                     __hip_bfloat16* __restrict__ vbt) {
    const int K = D_;
    __shared__ __hip_bfloat16 At[128*32];
    __shared__ __hip_bfloat16 Bt[128*32];
    int tid = threadIdx.x;
    int w = tid >> 6, lane = tid & 63;
    int l15 = lane & 15, lhi = lane >> 4;
    int swz = xcd_swz(blockIdx.x, gridDim.x);
    const int gx = QKVW >> 7;   // 12
    int bn = (swz % gx) * 128, bm = (swz / gx) * 128;
    int wr = w >> 1, wc = w & 1;
    f32x4 acc[4][4] = {};

    for (int k0 = 0; k0 < K; k0 += 32) {
#pragma unroll
        for (int iss = 0; iss < 2; ++iss) {
            int off = (iss*256 + tid) * 8;
            int row = off >> 5, col = off & 31;
            gload_lds16(A + (size_t)(bm + row) * K + k0 + col, &At[off]);
            gload_lds16(W + (size_t)(bn + row) * K + k0 + col, &Bt[off]);
        }
        __syncthreads();
        short8 af[4], bf[4];
#pragma unroll
        for (int m = 0; m < 4; ++m) af[m] = *(const short8*)&At[(wr*64 + m*16 + l15)*32 + lhi*8];
#pragma unroll
        for (int n = 0; n < 4; ++n) bf[n] = *(const short8*)&Bt[(wc*64 + n*16 + l15)*32 + lhi*8];
#pragma unroll
        for (int m = 0; m < 4; ++m)
#pragma unroll
            for (int n = 0; n < 4; ++n)
                acc[m][n] = __builtin_amdgcn_mfma_f32_16x16x32_bf16(af[m], bf[n], acc[m][n], 0, 0, 0);
        __syncthreads();
    }

    bool is_q = (bn < 1024);
    bool is_v = (!is_q) && (wc == 1);   // wave-uniform
    if (!is_v) {
#pragma unroll
        for (int m = 0; m < 4; ++m) {
#pragma unroll
            for (int j = 0; j < 4; ++j) {
                int row = bm + wr*64 + m*16 + lhi*4 + j;
                int b = row >> 11, t = row & (T_ - 1);
                const float* crow = cosb + t*HD_;
                const float* srow = sinb + t*HD_;
#pragma unroll
                for (int n = 0; n < 4; ++n) {
                    int col = bn + wc*64 + n*16 + l15;
                    int hd = n*16 + l15;
                    float val = acc[m][n][j];
                    float part = __shfl_xor(val, 1);
                    float rot = (l15 & 1) ? part : -part;
                    float o = val * crow[hd] + rot * srow[hd];
                    if (is_q) {
                        int h = col >> 6;
                        qb[(((size_t)(b*QH + h))*T_ + t)*HD_ + hd] = __float2bfloat16(o * 0.125f);
                    } else {
                        int kvh = (col - 1024) >> 7;
                        kbb[(((size_t)(b*KVH + kvh))*T_ + t)*HD_ + hd] = __float2bfloat16(o);
                    }
                }
            }
        }
    } else {
#pragma unroll
        for (int m = 0; m < 4; ++m) {
            int row0 = bm + wr*64 + m*16 + lhi*4;
            int b = row0 >> 11, t0 = row0 & (T_ - 1);
#pragma unroll
            for (int n = 0; n < 4; ++n) {
                int col = bn + 64 + n*16 + l15;
                int kvh = (col - 1024) >> 7;
                int hd = n*16 + l15;
                short4v pk = { (short)f2bu(acc[m][n][0]), (short)f2bu(acc[m][n][1]),
                               (short)f2bu(acc[m][n][2]), (short)f2bu(acc[m][n][3]) };
                *(short4v*)&vbt[(((size_t)(b*KVH + kvh))*HD_ + hd)*T_ + t0] = pk;
            }
        }
    }
}

// ---------------- Flash attention: R19 structure + ones-MFMA l-accumulation ----------------
// QBLK=64 (4 waves x 16 q-rows), KVBLK=64, swapped MFMA operands, swizzled LDS, setprio.
// Reg-staged async split; predicate-only defer-max (THR=8).
// l computed by mfma(ones, P): lacc[r] = sum over all keys of P[qrow=l15] (identical across
// r and lhi) -> no VALU adds, no final reduce. Rescale path scales lacc by cr.
__global__ __launch_bounds__(256) void attn_mfma(const __hip_bfloat16* __restrict__ qb,
                                                 const __hip_bfloat16* __restrict__ kb,
                                                 const __hip_bfloat16* __restrict__ vbt,
                                                 __hip_bfloat16* __restrict__ ob) {
    __shared__ __hip_bfloat16 Ks[2][64*64];   // [key][d]   swizzled
    __shared__ __hip_bfloat16 Vs[2][64*64];   // [d][key]   swizzled
    __shared__ __hip_bfloat16 Ps[64*64];      // [qrow][key] swizzled, per-wave rows
    char* PsB = (char*)Ps;
    int tid = threadIdx.x;
    int w = tid >> 6, lane = tid & 63;
    int l15 = lane & 15, lhi = lane >> 4;
    int bh = blockIdx.y;
    int b = bh >> 4, h = bh & 15;
    int bk = b * KVH + (h >> 2);
    int qt0 = blockIdx.x * 64;

    const __hip_bfloat16* qrow = qb + ((size_t)bh * T_ + qt0 + w*16 + l15) * HD_;
    short8 qf0 = *(const short8*)(qrow + lhi*8);
    short8 qf1 = *(const short8*)(qrow + 32 + lhi*8);

    f32x4 oacc[4] = {};          // O^T[d=cb*16+lhi*4+r][qrow=l15]
    f32x4 lacc = {};             // l for qrow=l15 (all regs identical)
    float m_run = -INFINITY;
    const short ONE_BF = (short)0x3F80;   // bf16 1.0
    const short8 onesf = { ONE_BF, ONE_BF, ONE_BF, ONE_BF, ONE_BF, ONE_BF, ONE_BF, ONE_BF };

    int sr = tid >> 2;                 // staging row 0..63
    int scB = (tid & 3) * 32;          // staging col byte {0,32,64,96}
    const __hip_bfloat16* kbase = kb  + (size_t)bk * T_ * HD_;
    const __hip_bfloat16* vbase = vbt + (size_t)bk * HD_ * T_;
    int sce = (tid & 3) * 16;          // element offset for global side

    // prologue: stage tile 0 into buf0
    {
        short8 ra = *(const short8*)(kbase + (size_t)sr*HD_ + sce);
        short8 rb = *(const short8*)(kbase + (size_t)sr*HD_ + sce + 8);
        short8 rc = *(const short8*)(vbase + (size_t)sr*T_ + sce);
        short8 rd = *(const short8*)(vbase + (size_t)sr*T_ + sce + 8);
        *(short8*)((char*)Ks[0] + KSWZ(sr, scB))      = ra;
        *(short8*)((char*)Ks[0] + KSWZ(sr, scB + 16)) = rb;
        *(short8*)((char*)Vs[0] + KSWZ(sr, scB))      = rc;
        *(short8*)((char*)Vs[0] + KSWZ(sr, scB + 16)) = rd;
    }
    __syncthreads();
    int cur = 0;
    const int NT = T_ / 64;

    for (int it = 0; it < NT; ++it) {
        // issue next tile's global loads early (latency hides under this tile's compute)
        short8 ra, rb, rc, rd;
        bool pfv = (it + 1 < NT);
        if (pfv) {
            int s0n = (it + 1) * 64;
            ra = *(const short8*)(kbase + (size_t)(s0n + sr)*HD_ + sce);
            rb = *(const short8*)(kbase + (size_t)(s0n + sr)*HD_ + sce + 8);
            rc = *(const short8*)(vbase + (size_t)sr*T_ + s0n + sce);
            rd = *(const short8*)(vbase + (size_t)sr*T_ + s0n + sce + 8);
        }
        char* KsB = (char*)Ks[cur];
        char* VsB = (char*)Vs[cur];

        // S^T = K Q^T
        f32x4 accs[4];
#pragma unroll
        for (int cb = 0; cb < 4; ++cb) {
            f32x4 z = {0.f, 0.f, 0.f, 0.f};
            short8 k0 = *(const short8*)(KsB + KSWZ(cb*16 + l15, lhi*16));
            short8 k1 = *(const short8*)(KsB + KSWZ(cb*16 + l15, 64 + lhi*16));
            __builtin_amdgcn_s_setprio(1);
            z = __builtin_amdgcn_mfma_f32_16x16x32_bf16(k0, qf0, z, 0, 0, 0);
            z = __builtin_amdgcn_mfma_f32_16x16x32_bf16(k1, qf1, z, 0, 0, 0);
            __builtin_amdgcn_s_setprio(0);
            accs[cb] = z;
        }

        // per-lane local max over this lane's 16 scores (no cross-lane reduce in common path)
        float mxl = -INFINITY;
#pragma unroll
        for (int cb = 0; cb < 4; ++cb)
#pragma unroll
            for (int r = 0; r < 4; ++r) mxl = fmaxf(mxl, accs[cb][r]);

        // defer-max (THR=8): group-max <= thr iff all lanes' local max <= thr
        if (!__all(mxl <= m_run + 8.0f)) {
            float mx = mxl;                         // exact group max (rare path)
            mx = fmaxf(mx, __shfl_xor(mx, 16));
            mx = fmaxf(mx, __shfl_xor(mx, 32));
            float mn = fmaxf(m_run, mx);
            float cr = __expf(m_run - mn);
            m_run = mn;
#pragma unroll
            for (int r = 0; r < 4; ++r) lacc[r] *= cr;
#pragma unroll
            for (int cb = 0; cb < 4; ++cb)
#pragma unroll
                for (int r = 0; r < 4; ++r) oacc[cb][r] *= cr;
        }

        int pr = w*16 + l15;               // per-wave P row
#pragma unroll
        for (int cb = 0; cb < 4; ++cb) {
            f32x4 p;
#pragma unroll
            for (int r = 0; r < 4; ++r) p[r] = __expf(accs[cb][r] - m_run);
            short4v pk = { (short)f2bu(p[0]), (short)f2bu(p[1]),
                           (short)f2bu(p[2]), (short)f2bu(p[3]) };
            *(short4v*)(PsB + KSWZ(pr, cb*32 + lhi*8)) = pk;
        }

        // O^T += V^T P^T ; lacc += ones * P^T (row-sum of P via matrix pipe)
#pragma unroll
        for (int kk = 0; kk < 2; ++kk) {
            short8 pf = *(const short8*)(PsB + KSWZ(w*16 + l15, kk*64 + lhi*16));
            __builtin_amdgcn_s_setprio(1);
            lacc = __builtin_amdgcn_mfma_f32_16x16x32_bf16(onesf, pf, lacc, 0, 0, 0);
#pragma unroll
            for (int cb = 0; cb < 4; ++cb) {
                short8 vf = *(const short8*)(VsB + KSWZ(cb*16 + l15, kk*64 + lhi*16));
                oacc[cb] = __builtin_amdgcn_mfma_f32_16x16x32_bf16(vf, pf, oacc[cb], 0, 0, 0);
            }
            __builtin_amdgcn_s_setprio(0);
        }

        // write next tile into the other buffer (last read at t-1, behind barrier -> safe)
        if (pfv) {
            char* KnB = (char*)Ks[cur ^ 1];
            char* VnB = (char*)Vs[cur ^ 1];
            *(short8*)(KnB + KSWZ(sr, scB))      = ra;
            *(short8*)(KnB + KSWZ(sr, scB + 16)) = rb;
            *(short8*)(VnB + KSWZ(sr, scB))      = rc;
            *(short8*)(VnB + KSWZ(sr, scB + 16)) = rd;
        }
        __syncthreads();   // writes visible + all waves done reading cur
        cur ^= 1;
    }

    float inv = 1.0f / lacc[0];   // full sum over all keys (identical across regs/lhi)
    int t = qt0 + w*16 + l15;
    __hip_bfloat16* orow = ob + (size_t)(b*T_ + t) * D_ + h*HD_;
#pragma unroll
    for (int cb = 0; cb < 4; ++cb) {
        short4v okv = { (short)f2bu(oacc[cb][0] * inv), (short)f2bu(oacc[cb][1] * inv),
                        (short)f2bu(oacc[cb][2] * inv), (short)f2bu(oacc[cb][3] * inv) };
        *(short4v*)&orow[cb*16 + lhi*4] = okv;
    }
}

extern "C" void kernel_launch(void* const* d_in, const int* in_sizes, int n_in,
                              void* d_out, int out_size, void* d_ws, size_t ws_size,
                              hipStream_t stream) {
    const float* x    = (const float*)d_in[0];
    const float* cosb = (const float*)d_in[1];
    const float* sinb = (const float*)d_in[2];
    const float* Wq   = (const float*)d_in[3];
    const float* Wkv  = (const float*)d_in[4];
    const float* Wo   = (const float*)d_in[5];
    const float* ln1g = (const float*)d_in[6];
    const float* ln1b = (const float*)d_in[7];
    const float* ln2g = (const float*)d_in[8];
    const float* ln2b = (const float*)d_in[9];
    const float* W1   = (const float*)d_in[10];
    const float* b1   = (const float*)d_in[11];
    const float* W2   = (const float*)d_in[12];
    const float* b2   = (const float*)d_in[13];
    float* out = (float*)d_out;

    float* ws = (float*)d_ws;
    const size_t M = 1024 * 1024;
    __hip_bfloat16* hb   = (__hip_bfloat16*)(ws);
    float*          x2   = ws + 4*M;
    __hip_bfloat16* gbuf = (__hip_bfloat16*)(ws + 12*M);
    __hip_bfloat16* ob   = (__hip_bfloat16*)(ws + 20*M);
    __hip_bfloat16* qb   = (__hip_bfloat16*)(ws + 24*M);
    __hip_bfloat16* kbb  = (__hip_bfloat16*)(ws + 28*M);
    __hip_bfloat16* vbt  = (__hip_bfloat16*)(ws + 29*M);
    __hip_bfloat16* Wqkvb= (__hip_bfloat16*)(ws + 30*M);
    __hip_bfloat16* Wob  = (__hip_bfloat16*)(ws + 30*M + 3*M/4);
    __hip_bfloat16* W1b  = (__hip_bfloat16*)(ws + 31*M + M/4);
    __hip_bfloat16* W2b  = (__hip_bfloat16*)(ws + 32*M + M/4);

    // 0+1. weight casts + LN1 fused (6656 cast blocks + 8192 LN rows)
    prologue_cast_ln<<<6656 + R_, 256, 0, stream>>>(Wq, Wkv, Wo, W1, W2,
                                                    Wqkvb, Wob, W1b, W2b,
                                                    x, ln1g, ln1b, hb);

    // 2+3. qkv GEMM with fused RoPE -> qb/kbb/vbt (bf16), XCD-swizzled 1D grid (768 blocks)
    gemm_qkv_rope<<<(QKVW/128)*(R_/128), 256, 0, stream>>>(hb, Wqkvb, cosb, sinb, qb, kbb, vbt);
    // 4. attention -> ob (bf16)
    attn_mfma<<<dim3(T_/64, B_*QH), 256, 0, stream>>>(qb, kbb, vbt, ob);
    // 5. x2 = x + ob @ Wob^T (512 blocks)
    gemm_mfma<1><<<(D_/128)*(R_/128), 256, 0, stream>>>(ob, Wob, nullptr, x, x2, nullptr, R_, D_, D_);
    // 6. LN2 -> hb (bf16)
    ln_bf16<<<R_, 256, 0, stream>>>(x2, ln2g, ln2b, hb);
    // 7. gbuf = gelu(hb @ W1b^T + b1) (bf16 out, 1024 blocks)
    gemm_mfma<2><<<(DFF/128)*(R_/128), 256, 0, stream>>>(hb, W1b, b1, nullptr, nullptr, gbuf, R_, DFF, D_);
    // 8. out = x2 + gbuf @ W2b^T + b2 (512 blocks)
    gemm_mfma<3><<<(D_/128)*(R_/128), 256, 0, stream>>>(gbuf, W2b, b2, x2, out, nullptr, R_, D_, DFF);
}

// Round 21
// 312.398 us; speedup vs baseline: 1.3178x; 1.1173x over previous
//
#include <hip/hip_runtime.h>
#include <hip/hip_bf16.h>
#include <math.h>
#include <stdint.h>

#define B_   4
#define T_   2048
#define D_   1024
#define QH   16
#define KVH  4
#define HD_  64
#define R_   (B_*T_)      // 8192 rows
#define DFF  2048
#define QKVW 1536         // fused q(1024) + kv(512) output width

typedef short short8 __attribute__((ext_vector_type(8)));
typedef short short4v __attribute__((ext_vector_type(4)));
typedef float f32x4 __attribute__((ext_vector_type(4)));

static __device__ __forceinline__ unsigned short f2bu(float x) {
    __hip_bfloat16 h = __float2bfloat16(x);
    return *reinterpret_cast<unsigned short*>(&h);
}

// swizzled byte offset within a 128B/row LDS tile (8-row XOR stripe)
#define KSWZ(row, cbyte) (((row) << 7) + ((cbyte) ^ (((row) & 7) << 4)))

__device__ __forceinline__ void gload_lds16(const void* g, void* l) {
    typedef __attribute__((address_space(1))) void gv_t;
    typedef __attribute__((address_space(3))) void lv_t;
    __builtin_amdgcn_global_load_lds((gv_t*)g, (lv_t*)l, 16, 0, 0);
}

// XCD-aware linear block swizzle (requires nwg % 8 == 0)
__device__ __forceinline__ int xcd_swz(int bid, int nwg) {
    int cpx = nwg >> 3;
    return (bid & 7) * cpx + (bid >> 3);
}

// fast GELU (tanh form): x * sigmoid(1.59576912*(x + 0.044715 x^3)); |err| <= ~3e-3
__device__ __forceinline__ float gelu_fast(float x) {
    float g2 = 1.5957691216057308f * (x + 0.044715f * x * x * x);
    return x / (1.0f + __expf(-g2));
}

// ---------------- prologue: weight casts (blocks [0,6656)) + LN1 (blocks [6656,14848)) --------
__global__ __launch_bounds__(256) void prologue_cast_ln(const float* __restrict__ Wq,
                                                        const float* __restrict__ Wkv,
                                                        const float* __restrict__ Wo,
                                                        const float* __restrict__ W1,
                                                        const float* __restrict__ W2,
                                                        __hip_bfloat16* __restrict__ dqkv,
                                                        __hip_bfloat16* __restrict__ dWo,
                                                        __hip_bfloat16* __restrict__ dW1,
                                                        __hip_bfloat16* __restrict__ dW2,
                                                        const float* __restrict__ x,
                                                        const float* __restrict__ g,
                                                        const float* __restrict__ bta,
                                                        __hip_bfloat16* __restrict__ hb) {
    int tid = threadIdx.x;
    if (blockIdx.x < 6656) {
        int i = blockIdx.x * 256 + tid;   // quad index, total exactly 6656*256 = 1703936
        const float* src; __hip_bfloat16* dst; int off;
        if (i < 262144)       { src = Wq;  dst = dqkv;            off = i; }
        else if (i < 393216)  { src = Wkv; dst = dqkv + 1048576;  off = i - 262144; }
        else if (i < 655360)  { src = Wo;  dst = dWo;             off = i - 393216; }
        else if (i < 1179648) { src = W1;  dst = dW1;             off = i - 655360; }
        else                  { src = W2;  dst = dW2;             off = i - 1179648; }
        float4 v = *(const float4*)&src[(size_t)off*4];
        ushort4 o = { f2bu(v.x), f2bu(v.y), f2bu(v.z), f2bu(v.w) };
        *(ushort4*)&dst[(size_t)off*4] = o;
        return;
    }
    int row = blockIdx.x - 6656;
    const float* xr = x + (size_t)row * D_;
    int c = tid * 4;
    float4 v = *(const float4*)&xr[c];
    float s = v.x + v.y + v.z + v.w;
#pragma unroll
    for (int off = 32; off >= 1; off >>= 1) s += __shfl_xor(s, off);
    __shared__ float sm[4], sv[4];
    int wid = tid >> 6, lane = tid & 63;
    if (lane == 0) sm[wid] = s;
    __syncthreads();
    float mean = (sm[0] + sm[1] + sm[2] + sm[3]) * (1.0f / D_);
    float d0 = v.x - mean, d1 = v.y - mean, d2 = v.z - mean, d3 = v.w - mean;
    float qq = d0*d0 + d1*d1 + d2*d2 + d3*d3;
#pragma unroll
    for (int off = 32; off >= 1; off >>= 1) qq += __shfl_xor(qq, off);
    if (lane == 0) sv[wid] = qq;
    __syncthreads();
    float var = (sv[0] + sv[1] + sv[2] + sv[3]) * (1.0f / D_);
    float rstd = rsqrtf(var + 1e-5f);
    float4 gg = *(const float4*)&g[c];
    float4 bb = *(const float4*)&bta[c];
    ushort4 o = { f2bu(d0 * rstd * gg.x + bb.x),
                  f2bu(d1 * rstd * gg.y + bb.y),
                  f2bu(d2 * rstd * gg.z + bb.z),
                  f2bu(d3 * rstd * gg.w + bb.w) };
    *(ushort4*)&(hb + (size_t)row * D_)[c] = o;
}

// ---------------- LayerNorm -> bf16 out: one block per row ----------------
__global__ __launch_bounds__(256) void ln_bf16(const float* __restrict__ x,
                                               const float* __restrict__ g,
                                               const float* __restrict__ bta,
                                               __hip_bfloat16* __restrict__ out) {
    int row = blockIdx.x;
    int tid = threadIdx.x;
    const float* xr = x + (size_t)row * D_;
    int c = tid * 4;
    float4 v = *(const float4*)&xr[c];
    float s = v.x + v.y + v.z + v.w;
#pragma unroll
    for (int off = 32; off >= 1; off >>= 1) s += __shfl_xor(s, off);
    __shared__ float sm[4], sv[4];
    int wid = tid >> 6, lane = tid & 63;
    if (lane == 0) sm[wid] = s;
    __syncthreads();
    float mean = (sm[0] + sm[1] + sm[2] + sm[3]) * (1.0f / D_);
    float d0 = v.x - mean, d1 = v.y - mean, d2 = v.z - mean, d3 = v.w - mean;
    float qq = d0*d0 + d1*d1 + d2*d2 + d3*d3;
#pragma unroll
    for (int off = 32; off >= 1; off >>= 1) qq += __shfl_xor(qq, off);
    if (lane == 0) sv[wid] = qq;
    __syncthreads();
    float var = (sv[0] + sv[1] + sv[2] + sv[3]) * (1.0f / D_);
    float rstd = rsqrtf(var + 1e-5f);
    float4 gg = *(const float4*)&g[c];
    float4 bb = *(const float4*)&bta[c];
    ushort4 o = { f2bu(d0 * rstd * gg.x + bb.x),
                  f2bu(d1 * rstd * gg.y + bb.y),
                  f2bu(d2 * rstd * gg.z + bb.z),
                  f2bu(d3 * rstd * gg.w + bb.w) };
    *(ushort4*)&(out + (size_t)row * D_)[c] = o;
}

// ---------------- bf16 MFMA GEMM, BK=64, swizzled LDS: C = res + act(A*W^T + bias) --------------
// 1D grid with XCD swizzle. MODE: 1 +res f32; 2 +bias,gelu -> bf16; 3 +bias,+res f32
// LDS tiles 128x64 bf16 (128B rows), staged via gload_lds with pre-swizzled SOURCE col;
// reads use KSWZ. One barrier pair per 64-wide K-step (half the barrier count of BK=32).
template<int MODE>
__global__ __launch_bounds__(256) void gemm_mfma(const __hip_bfloat16* __restrict__ A,
                                                 const __hip_bfloat16* __restrict__ W,
                                                 const float* __restrict__ bias,
                                                 const float* __restrict__ res,
                                                 float* __restrict__ Cf,
                                                 __hip_bfloat16* __restrict__ Cb,
                                                 int M, int N, int K) {
    __shared__ __hip_bfloat16 At[128*64];
    __shared__ __hip_bfloat16 Bt[128*64];
    int tid = threadIdx.x;
    int w = tid >> 6, lane = tid & 63;
    int l15 = lane & 15, lhi = lane >> 4;
    int swz = xcd_swz(blockIdx.x, gridDim.x);
    int gx = N >> 7;
    int bn = (swz % gx) * 128, bm = (swz / gx) * 128;
    int wr = w >> 1, wc = w & 1;
    f32x4 acc[4][4] = {};

    for (int k0 = 0; k0 < K; k0 += 64) {
#pragma unroll
        for (int iss = 0; iss < 4; ++iss) {
            int idx = iss*256 + tid;               // 0..1023
            int row = idx >> 3;                    // 0..127
            int cb  = (idx & 7) * 16;              // byte col within 128B row
            int sce = (cb ^ ((row & 7) << 4)) >> 1;  // pre-swizzled source col (elements)
            int ldso = idx * 16;                   // linear LDS byte offset (base + lane*16)
            gload_lds16(A + (size_t)(bm + row) * K + k0 + sce, (char*)At + ldso);
            gload_lds16(W + (size_t)(bn + row) * K + k0 + sce, (char*)Bt + ldso);
        }
        __syncthreads();
#pragma unroll
        for (int kk = 0; kk < 2; ++kk) {
            short8 af[4], bf[4];
#pragma unroll
            for (int m = 0; m < 4; ++m)
                af[m] = *(const short8*)((char*)At + KSWZ(wr*64 + m*16 + l15, kk*64 + lhi*16));
#pragma unroll
            for (int n = 0; n < 4; ++n)
                bf[n] = *(const short8*)((char*)Bt + KSWZ(wc*64 + n*16 + l15, kk*64 + lhi*16));
#pragma unroll
            for (int m = 0; m < 4; ++m)
#pragma unroll
                for (int n = 0; n < 4; ++n)
                    acc[m][n] = __builtin_amdgcn_mfma_f32_16x16x32_bf16(af[m], bf[n], acc[m][n], 0, 0, 0);
        }
        __syncthreads();
    }

#pragma unroll
    for (int m = 0; m < 4; ++m) {
#pragma unroll
        for (int j = 0; j < 4; ++j) {
            int row = bm + wr*64 + m*16 + lhi*4 + j;
#pragma unroll
            for (int n = 0; n < 4; ++n) {
                int col = bn + wc*64 + n*16 + l15;
                float val = acc[m][n][j];
                if (MODE == 2 || MODE == 3) val += bias[col];
                if (MODE == 2) val = gelu_fast(val);
                if (MODE == 1 || MODE == 3) val += res[(size_t)row * N + col];
                if (MODE == 2) Cb[(size_t)row * N + col] = __float2bfloat16(val);
                else           Cf[(size_t)row * N + col] = val;
            }
        }
    }
}

// ---------------- QKV GEMM with fused RoPE epilogue (BK=64, swizzled, XCD swizzle) -------------
__global__ __launch_bounds__(256) void gemm_qkv_rope(const __hip_bfloat16* __restrict__ A,
                                                     const __hip_bfloat16* __restrict__ W,
                                                     const float* __restrict__ cosb,
                                                     const float* __restrict__ sinb,
                                                     __hip_bfloat16* __restrict__ qb,
                                                     __hip_bfloat16* __restrict__ kbb,
                                                     __hip_bfloat16* __restrict__ vbt) {
    const int K = D_;
    __shared__ __hip_bfloat16 At[128*64];
    __shared__ __hip_bfloat16 Bt[128*64];
    int tid = threadIdx.x;
    int w = tid >> 6, lane = tid & 63;
    int l15 = lane & 15, lhi = lane >> 4;
    int swz = xcd_swz(blockIdx.x, gridDim.x);
    const int gx = QKVW >> 7;   // 12
    int bn = (swz % gx) * 128, bm = (swz / gx) * 128;
    int wr = w >> 1, wc = w & 1;
    f32x4 acc[4][4] = {};

    for (int k0 = 0; k0 < K; k0 += 64) {
#pragma unroll
        for (int iss = 0; iss < 4; ++iss) {
            int idx = iss*256 + tid;
            int row = idx >> 3;
            int cb  = (idx & 7) * 16;
            int sce = (cb ^ ((row & 7) << 4)) >> 1;
            int ldso = idx * 16;
            gload_lds16(A + (size_t)(bm + row) * K + k0 + sce, (char*)At + ldso);
            gload_lds16(W + (size_t)(bn + row) * K + k0 + sce, (char*)Bt + ldso);
        }
        __syncthreads();
#pragma unroll
        for (int kk = 0; kk < 2; ++kk) {
            short8 af[4], bf[4];
#pragma unroll
            for (int m = 0; m < 4; ++m)
                af[m] = *(const short8*)((char*)At + KSWZ(wr*64 + m*16 + l15, kk*64 + lhi*16));
#pragma unroll
            for (int n = 0; n < 4; ++n)
                bf[n] = *(const short8*)((char*)Bt + KSWZ(wc*64 + n*16 + l15, kk*64 + lhi*16));
#pragma unroll
            for (int m = 0; m < 4; ++m)
#pragma unroll
                for (int n = 0; n < 4; ++n)
                    acc[m][n] = __builtin_amdgcn_mfma_f32_16x16x32_bf16(af[m], bf[n], acc[m][n], 0, 0, 0);
        }
        __syncthreads();
    }

    bool is_q = (bn < 1024);
    bool is_v = (!is_q) && (wc == 1);   // wave-uniform
    if (!is_v) {
#pragma unroll
        for (int m = 0; m < 4; ++m) {
#pragma unroll
            for (int j = 0; j < 4; ++j) {
                int row = bm + wr*64 + m*16 + lhi*4 + j;
                int b = row >> 11, t = row & (T_ - 1);
                const float* crow = cosb + t*HD_;
                const float* srow = sinb + t*HD_;
#pragma unroll
                for (int n = 0; n < 4; ++n) {
                    int col = bn + wc*64 + n*16 + l15;
                    int hd = n*16 + l15;
                    float val = acc[m][n][j];
                    float part = __shfl_xor(val, 1);
                    float rot = (l15 & 1) ? part : -part;
                    float o = val * crow[hd] + rot * srow[hd];
                    if (is_q) {
                        int h = col >> 6;
                        qb[(((size_t)(b*QH + h))*T_ + t)*HD_ + hd] = __float2bfloat16(o * 0.125f);
                    } else {
                        int kvh = (col - 1024) >> 7;
                        kbb[(((size_t)(b*KVH + kvh))*T_ + t)*HD_ + hd] = __float2bfloat16(o);
                    }
                }
            }
        }
    } else {
#pragma unroll
        for (int m = 0; m < 4; ++m) {
            int row0 = bm + wr*64 + m*16 + lhi*4;
            int b = row0 >> 11, t0 = row0 & (T_ - 1);
#pragma unroll
            for (int n = 0; n < 4; ++n) {
                int col = bn + 64 + n*16 + l15;
                int kvh = (col - 1024) >> 7;
                int hd = n*16 + l15;
                short4v pk = { (short)f2bu(acc[m][n][0]), (short)f2bu(acc[m][n][1]),
                               (short)f2bu(acc[m][n][2]), (short)f2bu(acc[m][n][3]) };
                *(short4v*)&vbt[(((size_t)(b*KVH + kvh))*HD_ + hd)*T_ + t0] = pk;
            }
        }
    }
}

// ---------------- Flash attention: R20 structure (unchanged, best measured 122.7us) ------------
__global__ __launch_bounds__(256) void attn_mfma(const __hip_bfloat16* __restrict__ qb,
                                                 const __hip_bfloat16* __restrict__ kb,
                                                 const __hip_bfloat16* __restrict__ vbt,
                                                 __hip_bfloat16* __restrict__ ob) {
    __shared__ __hip_bfloat16 Ks[2][64*64];   // [key][d]   swizzled
    __shared__ __hip_bfloat16 Vs[2][64*64];   // [d][key]   swizzled
    __shared__ __hip_bfloat16 Ps[64*64];      // [qrow][key] swizzled, per-wave rows
    char* PsB = (char*)Ps;
    int tid = threadIdx.x;
    int w = tid >> 6, lane = tid & 63;
    int l15 = lane & 15, lhi = lane >> 4;
    int bh = blockIdx.y;
    int b = bh >> 4, h = bh & 15;
    int bk = b * KVH + (h >> 2);
    int qt0 = blockIdx.x * 64;

    const __hip_bfloat16* qrow = qb + ((size_t)bh * T_ + qt0 + w*16 + l15) * HD_;
    short8 qf0 = *(const short8*)(qrow + lhi*8);
    short8 qf1 = *(const short8*)(qrow + 32 + lhi*8);

    f32x4 oacc[4] = {};          // O^T[d=cb*16+lhi*4+r][qrow=l15]
    f32x4 lacc = {};             // l for qrow=l15 (all regs identical)
    float m_run = -INFINITY;
    const short ONE_BF = (short)0x3F80;   // bf16 1.0
    const short8 onesf = { ONE_BF, ONE_BF, ONE_BF, ONE_BF, ONE_BF, ONE_BF, ONE_BF, ONE_BF };

    int sr = tid >> 2;                 // staging row 0..63
    int scB = (tid & 3) * 32;          // staging col byte {0,32,64,96}
    const __hip_bfloat16* kbase = kb  + (size_t)bk * T_ * HD_;
    const __hip_bfloat16* vbase = vbt + (size_t)bk * HD_ * T_;
    int sce = (tid & 3) * 16;          // element offset for global side

    // prologue: stage tile 0 into buf0
    {
        short8 ra = *(const short8*)(kbase + (size_t)sr*HD_ + sce);
        short8 rb = *(const short8*)(kbase + (size_t)sr*HD_ + sce + 8);
        short8 rc = *(const short8*)(vbase + (size_t)sr*T_ + sce);
        short8 rd = *(const short8*)(vbase + (size_t)sr*T_ + sce + 8);
        *(short8*)((char*)Ks[0] + KSWZ(sr, scB))      = ra;
        *(short8*)((char*)Ks[0] + KSWZ(sr, scB + 16)) = rb;
        *(short8*)((char*)Vs[0] + KSWZ(sr, scB))      = rc;
        *(short8*)((char*)Vs[0] + KSWZ(sr, scB + 16)) = rd;
    }
    __syncthreads();
    int cur = 0;
    const int NT = T_ / 64;

    for (int it = 0; it < NT; ++it) {
        short8 ra, rb, rc, rd;
        bool pfv = (it + 1 < NT);
        if (pfv) {
            int s0n = (it + 1) * 64;
            ra = *(const short8*)(kbase + (size_t)(s0n + sr)*HD_ + sce);
            rb = *(const short8*)(kbase + (size_t)(s0n + sr)*HD_ + sce + 8);
            rc = *(const short8*)(vbase + (size_t)sr*T_ + s0n + sce);
            rd = *(const short8*)(vbase + (size_t)sr*T_ + s0n + sce + 8);
        }
        char* KsB = (char*)Ks[cur];
        char* VsB = (char*)Vs[cur];

        // S^T = K Q^T
        f32x4 accs[4];
#pragma unroll
        for (int cb = 0; cb < 4; ++cb) {
            f32x4 z = {0.f, 0.f, 0.f, 0.f};
            short8 k0 = *(const short8*)(KsB + KSWZ(cb*16 + l15, lhi*16));
            short8 k1 = *(const short8*)(KsB + KSWZ(cb*16 + l15, 64 + lhi*16));
            __builtin_amdgcn_s_setprio(1);
            z = __builtin_amdgcn_mfma_f32_16x16x32_bf16(k0, qf0, z, 0, 0, 0);
            z = __builtin_amdgcn_mfma_f32_16x16x32_bf16(k1, qf1, z, 0, 0, 0);
            __builtin_amdgcn_s_setprio(0);
            accs[cb] = z;
        }

        // per-lane local max (no cross-lane reduce in common path)
        float mxl = -INFINITY;
#pragma unroll
        for (int cb = 0; cb < 4; ++cb)
#pragma unroll
            for (int r = 0; r < 4; ++r) mxl = fmaxf(mxl, accs[cb][r]);

        // defer-max (THR=8)
        if (!__all(mxl <= m_run + 8.0f)) {
            float mx = mxl;
            mx = fmaxf(mx, __shfl_xor(mx, 16));
            mx = fmaxf(mx, __shfl_xor(mx, 32));
            float mn = fmaxf(m_run, mx);
            float cr = __expf(m_run - mn);
            m_run = mn;
#pragma unroll
            for (int r = 0; r < 4; ++r) lacc[r] *= cr;
#pragma unroll
            for (int cb = 0; cb < 4; ++cb)
#pragma unroll
                for (int r = 0; r < 4; ++r) oacc[cb][r] *= cr;
        }

        int pr = w*16 + l15;               // per-wave P row
#pragma unroll
        for (int cb = 0; cb < 4; ++cb) {
            f32x4 p;
#pragma unroll
            for (int r = 0; r < 4; ++r) p[r] = __expf(accs[cb][r] - m_run);
            short4v pk = { (short)f2bu(p[0]), (short)f2bu(p[1]),
                           (short)f2bu(p[2]), (short)f2bu(p[3]) };
            *(short4v*)(PsB + KSWZ(pr, cb*32 + lhi*8)) = pk;
        }

        // O^T += V^T P^T ; lacc += ones * P^T
#pragma unroll
        for (int kk = 0; kk < 2; ++kk) {
            short8 pf = *(const short8*)(PsB + KSWZ(w*16 + l15, kk*64 + lhi*16));
            __builtin_amdgcn_s_setprio(1);
            lacc = __builtin_amdgcn_mfma_f32_16x16x32_bf16(onesf, pf, lacc, 0, 0, 0);
#pragma unroll
            for (int cb = 0; cb < 4; ++cb) {
                short8 vf = *(const short8*)(VsB + KSWZ(cb*16 + l15, kk*64 + lhi*16));
                oacc[cb] = __builtin_amdgcn_mfma_f32_16x16x32_bf16(vf, pf, oacc[cb], 0, 0, 0);
            }
            __builtin_amdgcn_s_setprio(0);
        }

        if (pfv) {
            char* KnB = (char*)Ks[cur ^ 1];
            char* VnB = (char*)Vs[cur ^ 1];
            *(short8*)(KnB + KSWZ(sr, scB))      = ra;
            *(short8*)(KnB + KSWZ(sr, scB + 16)) = rb;
            *(short8*)(VnB + KSWZ(sr, scB))      = rc;
            *(short8*)(VnB + KSWZ(sr, scB + 16)) = rd;
        }
        __syncthreads();
        cur ^= 1;
    }

    float inv = 1.0f / lacc[0];
    int t = qt0 + w*16 + l15;
    __hip_bfloat16* orow = ob + (size_t)(b*T_ + t) * D_ + h*HD_;
#pragma unroll
    for (int cb = 0; cb < 4; ++cb) {
        short4v okv = { (short)f2bu(oacc[cb][0] * inv), (short)f2bu(oacc[cb][1] * inv),
                        (short)f2bu(oacc[cb][2] * inv), (short)f2bu(oacc[cb][3] * inv) };
        *(short4v*)&orow[cb*16 + lhi*4] = okv;
    }
}

extern "C" void kernel_launch(void* const* d_in, const int* in_sizes, int n_in,
                              void* d_out, int out_size, void* d_ws, size_t ws_size,
                              hipStream_t stream) {
    const float* x    = (const float*)d_in[0];
    const float* cosb = (const float*)d_in[1];
    const float* sinb = (const float*)d_in[2];
    const float* Wq   = (const float*)d_in[3];
    const float* Wkv  = (const float*)d_in[4];
    const float* Wo   = (const float*)d_in[5];
    const float* ln1g = (const float*)d_in[6];
    const float* ln1b = (const float*)d_in[7];
    const float* ln2g = (const float*)d_in[8];
    const float* ln2b = (const float*)d_in[9];
    const float* W1   = (const float*)d_in[10];
    const float* b1   = (const float*)d_in[11];
    const float* W2   = (const float*)d_in[12];
    const float* b2   = (const float*)d_in[13];
    float* out = (float*)d_out;

    float* ws = (float*)d_ws;
    const size_t M = 1024 * 1024;
    __hip_bfloat16* hb   = (__hip_bfloat16*)(ws);
    float*          x2   = ws + 4*M;
    __hip_bfloat16* gbuf = (__hip_bfloat16*)(ws + 12*M);
    __hip_bfloat16* ob   = (__hip_bfloat16*)(ws + 20*M);
    __hip_bfloat16* qb   = (__hip_bfloat16*)(ws + 24*M);
    __hip_bfloat16* kbb  = (__hip_bfloat16*)(ws + 28*M);
    __hip_bfloat16* vbt  = (__hip_bfloat16*)(ws + 29*M);
    __hip_bfloat16* Wqkvb= (__hip_bfloat16*)(ws + 30*M);
    __hip_bfloat16* Wob  = (__hip_bfloat16*)(ws + 30*M + 3*M/4);
    __hip_bfloat16* W1b  = (__hip_bfloat16*)(ws + 31*M + M/4);
    __hip_bfloat16* W2b  = (__hip_bfloat16*)(ws + 32*M + M/4);

    // 0+1. weight casts + LN1 fused
    prologue_cast_ln<<<6656 + R_, 256, 0, stream>>>(Wq, Wkv, Wo, W1, W2,
                                                    Wqkvb, Wob, W1b, W2b,
                                                    x, ln1g, ln1b, hb);

    // 2+3. qkv GEMM with fused RoPE -> qb/kbb/vbt (bf16), XCD-swizzled 1D grid (768 blocks)
    gemm_qkv_rope<<<(QKVW/128)*(R_/128), 256, 0, stream>>>(hb, Wqkvb, cosb, sinb, qb, kbb, vbt);
    // 4. attention -> ob (bf16)
    attn_mfma<<<dim3(T_/64, B_*QH), 256, 0, stream>>>(qb, kbb, vbt, ob);
    // 5. x2 = x + ob @ Wob^T (512 blocks)
    gemm_mfma<1><<<(D_/128)*(R_/128), 256, 0, stream>>>(ob, Wob, nullptr, x, x2, nullptr, R_, D_, D_);
    // 6. LN2 -> hb (bf16)
    ln_bf16<<<R_, 256, 0, stream>>>(x2, ln2g, ln2b, hb);
    // 7. gbuf = gelu(hb @ W1b^T + b1) (bf16 out, 1024 blocks)
    gemm_mfma<2><<<(DFF/128)*(R_/128), 256, 0, stream>>>(hb, W1b, b1, nullptr, nullptr, gbuf, R_, DFF, D_);
    // 8. out = x2 + gbuf @ W2b^T + b2 (512 blocks)
    gemm_mfma<3><<<(D_/128)*(R_/128), 256, 0, stream>>>(gbuf, W2b, b2, x2, out, nullptr, R_, D_, DFF);
}

// Round 22
// 306.771 us; speedup vs baseline: 1.3420x; 1.0183x over previous
//
#include <hip/hip_runtime.h>
#include <hip/hip_bf16.h>
#include <math.h>
#include <stdint.h>

#define B_   4
#define T_   2048
#define D_   1024
#define QH   16
#define KVH  4
#define HD_  64
#define R_   (B_*T_)      // 8192 rows
#define DFF  2048
#define QKVW 1536         // fused q(1024) + kv(512) output width

typedef short short8 __attribute__((ext_vector_type(8)));
typedef short short4v __attribute__((ext_vector_type(4)));
typedef float f32x4 __attribute__((ext_vector_type(4)));

static __device__ __forceinline__ unsigned short f2bu(float x) {
    __hip_bfloat16 h = __float2bfloat16(x);
    return *reinterpret_cast<unsigned short*>(&h);
}
static __device__ __forceinline__ float bu2f(unsigned short u) {
    unsigned int w = ((unsigned int)u) << 16;
    return *reinterpret_cast<float*>(&w);
}

// swizzled byte offset within a 128B/row LDS tile (8-row XOR stripe)
#define KSWZ(row, cbyte) (((row) << 7) + ((cbyte) ^ (((row) & 7) << 4)))

__device__ __forceinline__ void gload_lds16(const void* g, void* l) {
    typedef __attribute__((address_space(1))) void gv_t;
    typedef __attribute__((address_space(3))) void lv_t;
    __builtin_amdgcn_global_load_lds((gv_t*)g, (lv_t*)l, 16, 0, 0);
}

// XCD-aware linear block swizzle (requires nwg % 8 == 0)
__device__ __forceinline__ int xcd_swz(int bid, int nwg) {
    int cpx = nwg >> 3;
    return (bid & 7) * cpx + (bid >> 3);
}

// fast GELU (tanh form): x * sigmoid(1.59576912*(x + 0.044715 x^3)); |err| <= ~3e-3
__device__ __forceinline__ float gelu_fast(float x) {
    float g2 = 1.5957691216057308f * (x + 0.044715f * x * x * x);
    return x / (1.0f + __expf(-g2));
}

// ---------------- prologue: weight casts (blocks [0,6656)) + LN1 (blocks [6656,14848)) --------
__global__ __launch_bounds__(256) void prologue_cast_ln(const float* __restrict__ Wq,
                                                        const float* __restrict__ Wkv,
                                                        const float* __restrict__ Wo,
                                                        const float* __restrict__ W1,
                                                        const float* __restrict__ W2,
                                                        __hip_bfloat16* __restrict__ dqkv,
                                                        __hip_bfloat16* __restrict__ dWo,
                                                        __hip_bfloat16* __restrict__ dW1,
                                                        __hip_bfloat16* __restrict__ dW2,
                                                        const float* __restrict__ x,
                                                        const float* __restrict__ g,
                                                        const float* __restrict__ bta,
                                                        __hip_bfloat16* __restrict__ hb) {
    int tid = threadIdx.x;
    if (blockIdx.x < 6656) {
        int i = blockIdx.x * 256 + tid;   // quad index, total exactly 6656*256 = 1703936
        const float* src; __hip_bfloat16* dst; int off;
        if (i < 262144)       { src = Wq;  dst = dqkv;            off = i; }
        else if (i < 393216)  { src = Wkv; dst = dqkv + 1048576;  off = i - 262144; }
        else if (i < 655360)  { src = Wo;  dst = dWo;             off = i - 393216; }
        else if (i < 1179648) { src = W1;  dst = dW1;             off = i - 655360; }
        else                  { src = W2;  dst = dW2;             off = i - 1179648; }
        float4 v = *(const float4*)&src[(size_t)off*4];
        ushort4 o = { f2bu(v.x), f2bu(v.y), f2bu(v.z), f2bu(v.w) };
        *(ushort4*)&dst[(size_t)off*4] = o;
        return;
    }
    int row = blockIdx.x - 6656;
    const float* xr = x + (size_t)row * D_;
    int c = tid * 4;
    float4 v = *(const float4*)&xr[c];
    float s = v.x + v.y + v.z + v.w;
#pragma unroll
    for (int off = 32; off >= 1; off >>= 1) s += __shfl_xor(s, off);
    __shared__ float sm[4], sv[4];
    int wid = tid >> 6, lane = tid & 63;
    if (lane == 0) sm[wid] = s;
    __syncthreads();
    float mean = (sm[0] + sm[1] + sm[2] + sm[3]) * (1.0f / D_);
    float d0 = v.x - mean, d1 = v.y - mean, d2 = v.z - mean, d3 = v.w - mean;
    float qq = d0*d0 + d1*d1 + d2*d2 + d3*d3;
#pragma unroll
    for (int off = 32; off >= 1; off >>= 1) qq += __shfl_xor(qq, off);
    if (lane == 0) sv[wid] = qq;
    __syncthreads();
    float var = (sv[0] + sv[1] + sv[2] + sv[3]) * (1.0f / D_);
    float rstd = rsqrtf(var + 1e-5f);
    float4 gg = *(const float4*)&g[c];
    float4 bb = *(const float4*)&bta[c];
    ushort4 o = { f2bu(d0 * rstd * gg.x + bb.x),
                  f2bu(d1 * rstd * gg.y + bb.y),
                  f2bu(d2 * rstd * gg.z + bb.z),
                  f2bu(d3 * rstd * gg.w + bb.w) };
    *(ushort4*)&(hb + (size_t)row * D_)[c] = o;
}

// ---------------- LayerNorm with bf16 input -> bf16 out: one block per row ----------------
__global__ __launch_bounds__(256) void ln_bf16_in(const __hip_bfloat16* __restrict__ x,
                                                  const float* __restrict__ g,
                                                  const float* __restrict__ bta,
                                                  __hip_bfloat16* __restrict__ out) {
    int row = blockIdx.x;
    int tid = threadIdx.x;
    const __hip_bfloat16* xr = x + (size_t)row * D_;
    int c = tid * 4;
    ushort4 u = *(const ushort4*)&xr[c];
    float v0 = bu2f(u.x), v1 = bu2f(u.y), v2 = bu2f(u.z), v3 = bu2f(u.w);
    float s = v0 + v1 + v2 + v3;
#pragma unroll
    for (int off = 32; off >= 1; off >>= 1) s += __shfl_xor(s, off);
    __shared__ float sm[4], sv[4];
    int wid = tid >> 6, lane = tid & 63;
    if (lane == 0) sm[wid] = s;
    __syncthreads();
    float mean = (sm[0] + sm[1] + sm[2] + sm[3]) * (1.0f / D_);
    float d0 = v0 - mean, d1 = v1 - mean, d2 = v2 - mean, d3 = v3 - mean;
    float qq = d0*d0 + d1*d1 + d2*d2 + d3*d3;
#pragma unroll
    for (int off = 32; off >= 1; off >>= 1) qq += __shfl_xor(qq, off);
    if (lane == 0) sv[wid] = qq;
    __syncthreads();
    float var = (sv[0] + sv[1] + sv[2] + sv[3]) * (1.0f / D_);
    float rstd = rsqrtf(var + 1e-5f);
    float4 gg = *(const float4*)&g[c];
    float4 bb = *(const float4*)&bta[c];
    ushort4 o = { f2bu(d0 * rstd * gg.x + bb.x),
                  f2bu(d1 * rstd * gg.y + bb.y),
                  f2bu(d2 * rstd * gg.z + bb.z),
                  f2bu(d3 * rstd * gg.w + bb.w) };
    *(ushort4*)&(out + (size_t)row * D_)[c] = o;
}

// ---------------- bf16 MFMA GEMM, BK=64, swizzled LDS ----------------
// MODE 1: += res(f32), out bf16 Cb  (x2b = x + attn@Wo)
// MODE 2: += bias, gelu, out bf16 Cb (gbuf)
// MODE 3: += bias, += resb(bf16), out f32 Cf (final out)
template<int MODE>
__global__ __launch_bounds__(256) void gemm_mfma(const __hip_bfloat16* __restrict__ A,
                                                 const __hip_bfloat16* __restrict__ W,
                                                 const float* __restrict__ bias,
                                                 const float* __restrict__ res,
                                                 const __hip_bfloat16* __restrict__ resb,
                                                 float* __restrict__ Cf,
                                                 __hip_bfloat16* __restrict__ Cb,
                                                 int M, int N, int K) {
    __shared__ __hip_bfloat16 At[128*64];
    __shared__ __hip_bfloat16 Bt[128*64];
    int tid = threadIdx.x;
    int w = tid >> 6, lane = tid & 63;
    int l15 = lane & 15, lhi = lane >> 4;
    int swz = xcd_swz(blockIdx.x, gridDim.x);
    int gx = N >> 7;
    int bn = (swz % gx) * 128, bm = (swz / gx) * 128;
    int wr = w >> 1, wc = w & 1;
    f32x4 acc[4][4] = {};

    for (int k0 = 0; k0 < K; k0 += 64) {
#pragma unroll
        for (int iss = 0; iss < 4; ++iss) {
            int idx = iss*256 + tid;               // 0..1023
            int row = idx >> 3;                    // 0..127
            int cb  = (idx & 7) * 16;              // byte col within 128B row
            int sce = (cb ^ ((row & 7) << 4)) >> 1;  // pre-swizzled source col (elements)
            int ldso = idx * 16;                   // linear LDS byte offset
            gload_lds16(A + (size_t)(bm + row) * K + k0 + sce, (char*)At + ldso);
            gload_lds16(W + (size_t)(bn + row) * K + k0 + sce, (char*)Bt + ldso);
        }
        __syncthreads();
#pragma unroll
        for (int kk = 0; kk < 2; ++kk) {
            short8 af[4], bf[4];
#pragma unroll
            for (int m = 0; m < 4; ++m)
                af[m] = *(const short8*)((char*)At + KSWZ(wr*64 + m*16 + l15, kk*64 + lhi*16));
#pragma unroll
            for (int n = 0; n < 4; ++n)
                bf[n] = *(const short8*)((char*)Bt + KSWZ(wc*64 + n*16 + l15, kk*64 + lhi*16));
#pragma unroll
            for (int m = 0; m < 4; ++m)
#pragma unroll
                for (int n = 0; n < 4; ++n)
                    acc[m][n] = __builtin_amdgcn_mfma_f32_16x16x32_bf16(af[m], bf[n], acc[m][n], 0, 0, 0);
        }
        __syncthreads();
    }

#pragma unroll
    for (int m = 0; m < 4; ++m) {
#pragma unroll
        for (int j = 0; j < 4; ++j) {
            int row = bm + wr*64 + m*16 + lhi*4 + j;
#pragma unroll
            for (int n = 0; n < 4; ++n) {
                int col = bn + wc*64 + n*16 + l15;
                float val = acc[m][n][j];
                if (MODE == 2 || MODE == 3) val += bias[col];
                if (MODE == 2) val = gelu_fast(val);
                if (MODE == 1) val += res[(size_t)row * N + col];
                if (MODE == 3) val += bu2f(*(const unsigned short*)&resb[(size_t)row * N + col]);
                if (MODE == 3) Cf[(size_t)row * N + col] = val;
                else           Cb[(size_t)row * N + col] = __float2bfloat16(val);
            }
        }
    }
}

// ---------------- QKV GEMM with fused RoPE epilogue (BK=64, swizzled, XCD swizzle) -------------
__global__ __launch_bounds__(256) void gemm_qkv_rope(const __hip_bfloat16* __restrict__ A,
                                                     const __hip_bfloat16* __restrict__ W,
                                                     const float* __restrict__ cosb,
                                                     const float* __restrict__ sinb,
                                                     __hip_bfloat16* __restrict__ qb,
                                                     __hip_bfloat16* __restrict__ kbb,
                                                     __hip_bfloat16* __restrict__ vbt) {
    const int K = D_;
    __shared__ __hip_bfloat16 At[128*64];
    __shared__ __hip_bfloat16 Bt[128*64];
    int tid = threadIdx.x;
    int w = tid >> 6, lane = tid & 63;
    int l15 = lane & 15, lhi = lane >> 4;
    int swz = xcd_swz(blockIdx.x, gridDim.x);
    const int gx = QKVW >> 7;   // 12
    int bn = (swz % gx) * 128, bm = (swz / gx) * 128;
    int wr = w >> 1, wc = w & 1;
    f32x4 acc[4][4] = {};

    for (int k0 = 0; k0 < K; k0 += 64) {
#pragma unroll
        for (int iss = 0; iss < 4; ++iss) {
            int idx = iss*256 + tid;
            int row = idx >> 3;
            int cb  = (idx & 7) * 16;
            int sce = (cb ^ ((row & 7) << 4)) >> 1;
            int ldso = idx * 16;
            gload_lds16(A + (size_t)(bm + row) * K + k0 + sce, (char*)At + ldso);
            gload_lds16(W + (size_t)(bn + row) * K + k0 + sce, (char*)Bt + ldso);
        }
        __syncthreads();
#pragma unroll
        for (int kk = 0; kk < 2; ++kk) {
            short8 af[4], bf[4];
#pragma unroll
            for (int m = 0; m < 4; ++m)
                af[m] = *(const short8*)((char*)At + KSWZ(wr*64 + m*16 + l15, kk*64 + lhi*16));
#pragma unroll
            for (int n = 0; n < 4; ++n)
                bf[n] = *(const short8*)((char*)Bt + KSWZ(wc*64 + n*16 + l15, kk*64 + lhi*16));
#pragma unroll
            for (int m = 0; m < 4; ++m)
#pragma unroll
                for (int n = 0; n < 4; ++n)
                    acc[m][n] = __builtin_amdgcn_mfma_f32_16x16x32_bf16(af[m], bf[n], acc[m][n], 0, 0, 0);
        }
        __syncthreads();
    }

    bool is_q = (bn < 1024);
    bool is_v = (!is_q) && (wc == 1);   // wave-uniform
    if (!is_v) {
#pragma unroll
        for (int m = 0; m < 4; ++m) {
#pragma unroll
            for (int j = 0; j < 4; ++j) {
                int row = bm + wr*64 + m*16 + lhi*4 + j;
                int b = row >> 11, t = row & (T_ - 1);
                const float* crow = cosb + t*HD_;
                const float* srow = sinb + t*HD_;
#pragma unroll
                for (int n = 0; n < 4; ++n) {
                    int col = bn + wc*64 + n*16 + l15;
                    int hd = n*16 + l15;
                    float val = acc[m][n][j];
                    float part = __shfl_xor(val, 1);
                    float rot = (l15 & 1) ? part : -part;
                    float o = val * crow[hd] + rot * srow[hd];
                    if (is_q) {
                        int h = col >> 6;
                        qb[(((size_t)(b*QH + h))*T_ + t)*HD_ + hd] = __float2bfloat16(o * 0.125f);
                    } else {
                        int kvh = (col - 1024) >> 7;
                        kbb[(((size_t)(b*KVH + kvh))*T_ + t)*HD_ + hd] = __float2bfloat16(o);
                    }
                }
            }
        }
    } else {
#pragma unroll
        for (int m = 0; m < 4; ++m) {
            int row0 = bm + wr*64 + m*16 + lhi*4;
            int b = row0 >> 11, t0 = row0 & (T_ - 1);
#pragma unroll
            for (int n = 0; n < 4; ++n) {
                int col = bn + 64 + n*16 + l15;
                int kvh = (col - 1024) >> 7;
                int hd = n*16 + l15;
                short4v pk = { (short)f2bu(acc[m][n][0]), (short)f2bu(acc[m][n][1]),
                               (short)f2bu(acc[m][n][2]), (short)f2bu(acc[m][n][3]) };
                *(short4v*)&vbt[(((size_t)(b*KVH + kvh))*HD_ + hd)*T_ + t0] = pk;
            }
        }
    }
}

// ---------------- Flash attention: R20 structure (unchanged, best measured 122.7us) ------------
__global__ __launch_bounds__(256) void attn_mfma(const __hip_bfloat16* __restrict__ qb,
                                                 const __hip_bfloat16* __restrict__ kb,
                                                 const __hip_bfloat16* __restrict__ vbt,
                                                 __hip_bfloat16* __restrict__ ob) {
    __shared__ __hip_bfloat16 Ks[2][64*64];   // [key][d]   swizzled
    __shared__ __hip_bfloat16 Vs[2][64*64];   // [d][key]   swizzled
    __shared__ __hip_bfloat16 Ps[64*64];      // [qrow][key] swizzled, per-wave rows
    char* PsB = (char*)Ps;
    int tid = threadIdx.x;
    int w = tid >> 6, lane = tid & 63;
    int l15 = lane & 15, lhi = lane >> 4;
    int bh = blockIdx.y;
    int b = bh >> 4, h = bh & 15;
    int bk = b * KVH + (h >> 2);
    int qt0 = blockIdx.x * 64;

    const __hip_bfloat16* qrow = qb + ((size_t)bh * T_ + qt0 + w*16 + l15) * HD_;
    short8 qf0 = *(const short8*)(qrow + lhi*8);
    short8 qf1 = *(const short8*)(qrow + 32 + lhi*8);

    f32x4 oacc[4] = {};          // O^T[d=cb*16+lhi*4+r][qrow=l15]
    f32x4 lacc = {};             // l for qrow=l15 (all regs identical)
    float m_run = -INFINITY;
    const short ONE_BF = (short)0x3F80;   // bf16 1.0
    const short8 onesf = { ONE_BF, ONE_BF, ONE_BF, ONE_BF, ONE_BF, ONE_BF, ONE_BF, ONE_BF };

    int sr = tid >> 2;                 // staging row 0..63
    int scB = (tid & 3) * 32;          // staging col byte {0,32,64,96}
    const __hip_bfloat16* kbase = kb  + (size_t)bk * T_ * HD_;
    const __hip_bfloat16* vbase = vbt + (size_t)bk * HD_ * T_;
    int sce = (tid & 3) * 16;          // element offset for global side

    // prologue: stage tile 0 into buf0
    {
        short8 ra = *(const short8*)(kbase + (size_t)sr*HD_ + sce);
        short8 rb = *(const short8*)(kbase + (size_t)sr*HD_ + sce + 8);
        short8 rc = *(const short8*)(vbase + (size_t)sr*T_ + sce);
        short8 rd = *(const short8*)(vbase + (size_t)sr*T_ + sce + 8);
        *(short8*)((char*)Ks[0] + KSWZ(sr, scB))      = ra;
        *(short8*)((char*)Ks[0] + KSWZ(sr, scB + 16)) = rb;
        *(short8*)((char*)Vs[0] + KSWZ(sr, scB))      = rc;
        *(short8*)((char*)Vs[0] + KSWZ(sr, scB + 16)) = rd;
    }
    __syncthreads();
    int cur = 0;
    const int NT = T_ / 64;

    for (int it = 0; it < NT; ++it) {
        short8 ra, rb, rc, rd;
        bool pfv = (it + 1 < NT);
        if (pfv) {
            int s0n = (it + 1) * 64;
            ra = *(const short8*)(kbase + (size_t)(s0n + sr)*HD_ + sce);
            rb = *(const short8*)(kbase + (size_t)(s0n + sr)*HD_ + sce + 8);
            rc = *(const short8*)(vbase + (size_t)sr*T_ + s0n + sce);
            rd = *(const short8*)(vbase + (size_t)sr*T_ + s0n + sce + 8);
        }
        char* KsB = (char*)Ks[cur];
        char* VsB = (char*)Vs[cur];

        // S^T = K Q^T
        f32x4 accs[4];
#pragma unroll
        for (int cb = 0; cb < 4; ++cb) {
            f32x4 z = {0.f, 0.f, 0.f, 0.f};
            short8 k0 = *(const short8*)(KsB + KSWZ(cb*16 + l15, lhi*16));
            short8 k1 = *(const short8*)(KsB + KSWZ(cb*16 + l15, 64 + lhi*16));
            __builtin_amdgcn_s_setprio(1);
            z = __builtin_amdgcn_mfma_f32_16x16x32_bf16(k0, qf0, z, 0, 0, 0);
            z = __builtin_amdgcn_mfma_f32_16x16x32_bf16(k1, qf1, z, 0, 0, 0);
            __builtin_amdgcn_s_setprio(0);
            accs[cb] = z;
        }

        // per-lane local max (no cross-lane reduce in common path)
        float mxl = -INFINITY;
#pragma unroll
        for (int cb = 0; cb < 4; ++cb)
#pragma unroll
            for (int r = 0; r < 4; ++r) mxl = fmaxf(mxl, accs[cb][r]);

        // defer-max (THR=8)
        if (!__all(mxl <= m_run + 8.0f)) {
            float mx = mxl;
            mx = fmaxf(mx, __shfl_xor(mx, 16));
            mx = fmaxf(mx, __shfl_xor(mx, 32));
            float mn = fmaxf(m_run, mx);
            float cr = __expf(m_run - mn);
            m_run = mn;
#pragma unroll
            for (int r = 0; r < 4; ++r) lacc[r] *= cr;
#pragma unroll
            for (int cb = 0; cb < 4; ++cb)
#pragma unroll
                for (int r = 0; r < 4; ++r) oacc[cb][r] *= cr;
        }

        int pr = w*16 + l15;               // per-wave P row
#pragma unroll
        for (int cb = 0; cb < 4; ++cb) {
            f32x4 p;
#pragma unroll
            for (int r = 0; r < 4; ++r) p[r] = __expf(accs[cb][r] - m_run);
            short4v pk = { (short)f2bu(p[0]), (short)f2bu(p[1]),
                           (short)f2bu(p[2]), (short)f2bu(p[3]) };
            *(short4v*)(PsB + KSWZ(pr, cb*32 + lhi*8)) = pk;
        }

        // O^T += V^T P^T ; lacc += ones * P^T
#pragma unroll
        for (int kk = 0; kk < 2; ++kk) {
            short8 pf = *(const short8*)(PsB + KSWZ(w*16 + l15, kk*64 + lhi*16));
            __builtin_amdgcn_s_setprio(1);
            lacc = __builtin_amdgcn_mfma_f32_16x16x32_bf16(onesf, pf, lacc, 0, 0, 0);
#pragma unroll
            for (int cb = 0; cb < 4; ++cb) {
                short8 vf = *(const short8*)(VsB + KSWZ(cb*16 + l15, kk*64 + lhi*16));
                oacc[cb] = __builtin_amdgcn_mfma_f32_16x16x32_bf16(vf, pf, oacc[cb], 0, 0, 0);
            }
            __builtin_amdgcn_s_setprio(0);
        }

        if (pfv) {
            char* KnB = (char*)Ks[cur ^ 1];
            char* VnB = (char*)Vs[cur ^ 1];
            *(short8*)(KnB + KSWZ(sr, scB))      = ra;
            *(short8*)(KnB + KSWZ(sr, scB + 16)) = rb;
            *(short8*)(VnB + KSWZ(sr, scB))      = rc;
            *(short8*)(VnB + KSWZ(sr, scB + 16)) = rd;
        }
        __syncthreads();
        cur ^= 1;
    }

    float inv = 1.0f / lacc[0];
    int t = qt0 + w*16 + l15;
    __hip_bfloat16* orow = ob + (size_t)(b*T_ + t) * D_ + h*HD_;
#pragma unroll
    for (int cb = 0; cb < 4; ++cb) {
        short4v okv = { (short)f2bu(oacc[cb][0] * inv), (short)f2bu(oacc[cb][1] * inv),
                        (short)f2bu(oacc[cb][2] * inv), (short)f2bu(oacc[cb][3] * inv) };
        *(short4v*)&orow[cb*16 + lhi*4] = okv;
    }
}

extern "C" void kernel_launch(void* const* d_in, const int* in_sizes, int n_in,
                              void* d_out, int out_size, void* d_ws, size_t ws_size,
                              hipStream_t stream) {
    const float* x    = (const float*)d_in[0];
    const float* cosb = (const float*)d_in[1];
    const float* sinb = (const float*)d_in[2];
    const float* Wq   = (const float*)d_in[3];
    const float* Wkv  = (const float*)d_in[4];
    const float* Wo   = (const float*)d_in[5];
    const float* ln1g = (const float*)d_in[6];
    const float* ln1b = (const float*)d_in[7];
    const float* ln2g = (const float*)d_in[8];
    const float* ln2b = (const float*)d_in[9];
    const float* W1   = (const float*)d_in[10];
    const float* b1   = (const float*)d_in[11];
    const float* W2   = (const float*)d_in[12];
    const float* b2   = (const float*)d_in[13];
    float* out = (float*)d_out;

    float* ws = (float*)d_ws;
    const size_t M = 1024 * 1024;
    __hip_bfloat16* hb   = (__hip_bfloat16*)(ws);
    __hip_bfloat16* x2b  = (__hip_bfloat16*)(ws + 4*M);    // bf16 residual x2
    __hip_bfloat16* gbuf = (__hip_bfloat16*)(ws + 12*M);
    __hip_bfloat16* ob   = (__hip_bfloat16*)(ws + 20*M);
    __hip_bfloat16* qb   = (__hip_bfloat16*)(ws + 24*M);
    __hip_bfloat16* kbb  = (__hip_bfloat16*)(ws + 28*M);
    __hip_bfloat16* vbt  = (__hip_bfloat16*)(ws + 29*M);
    __hip_bfloat16* Wqkvb= (__hip_bfloat16*)(ws + 30*M);
    __hip_bfloat16* Wob  = (__hip_bfloat16*)(ws + 30*M + 3*M/4);
    __hip_bfloat16* W1b  = (__hip_bfloat16*)(ws + 31*M + M/4);
    __hip_bfloat16* W2b  = (__hip_bfloat16*)(ws + 32*M + M/4);

    // 0+1. weight casts + LN1 fused
    prologue_cast_ln<<<6656 + R_, 256, 0, stream>>>(Wq, Wkv, Wo, W1, W2,
                                                    Wqkvb, Wob, W1b, W2b,
                                                    x, ln1g, ln1b, hb);

    // 2+3. qkv GEMM with fused RoPE -> qb/kbb/vbt (bf16), XCD-swizzled 1D grid (768 blocks)
    gemm_qkv_rope<<<(QKVW/128)*(R_/128), 256, 0, stream>>>(hb, Wqkvb, cosb, sinb, qb, kbb, vbt);
    // 4. attention -> ob (bf16)
    attn_mfma<<<dim3(T_/64, B_*QH), 256, 0, stream>>>(qb, kbb, vbt, ob);
    // 5. x2b = x + ob @ Wob^T (bf16 out, 512 blocks)
    gemm_mfma<1><<<(D_/128)*(R_/128), 256, 0, stream>>>(ob, Wob, nullptr, x, nullptr, nullptr, x2b, R_, D_, D_);
    // 6. LN2 (bf16 in) -> hb (bf16)
    ln_bf16_in<<<R_, 256, 0, stream>>>(x2b, ln2g, ln2b, hb);
    // 7. gbuf = gelu(hb @ W1b^T + b1) (bf16 out, 1024 blocks)
    gemm_mfma<2><<<(DFF/128)*(R_/128), 256, 0, stream>>>(hb, W1b, b1, nullptr, nullptr, nullptr, gbuf, R_, DFF, D_);
    // 8. out = x2b + gbuf @ W2b^T + b2 (f32 out, 512 blocks)
    gemm_mfma<3><<<(D_/128)*(R_/128), 256, 0, stream>>>(gbuf, W2b, b2, nullptr, x2b, out, nullptr, R_, D_, DFF);
}

// Round 23
// 301.963 us; speedup vs baseline: 1.3633x; 1.0159x over previous
//
#include <hip/hip_runtime.h>
#include <hip/hip_bf16.h>
#include <math.h>
#include <stdint.h>

#define B_   4
#define T_   2048
#define D_   1024
#define QH   16
#define KVH  4
#define HD_  64
#define R_   (B_*T_)      // 8192 rows
#define DFF  2048
#define QKVW 1536         // fused q(1024) + kv(512) output width

typedef short short8 __attribute__((ext_vector_type(8)));
typedef short short4v __attribute__((ext_vector_type(4)));
typedef float f32x4 __attribute__((ext_vector_type(4)));

// native exp2 (bare v_exp_f32); guarded fallback is mathematically identical
#if __has_builtin(__builtin_amdgcn_exp2f)
#define EXP2(x) __builtin_amdgcn_exp2f(x)
#else
#define EXP2(x) __expf((x) * 0.6931471805599453f)
#endif

static __device__ __forceinline__ unsigned short f2bu(float x) {
    __hip_bfloat16 h = __float2bfloat16(x);
    return *reinterpret_cast<unsigned short*>(&h);
}
static __device__ __forceinline__ float bu2f(unsigned short u) {
    unsigned int w = ((unsigned int)u) << 16;
    return *reinterpret_cast<float*>(&w);
}

// swizzled byte offset within a 128B/row LDS tile (8-row XOR stripe)
#define KSWZ(row, cbyte) (((row) << 7) + ((cbyte) ^ (((row) & 7) << 4)))

__device__ __forceinline__ void gload_lds16(const void* g, void* l) {
    typedef __attribute__((address_space(1))) void gv_t;
    typedef __attribute__((address_space(3))) void lv_t;
    __builtin_amdgcn_global_load_lds((gv_t*)g, (lv_t*)l, 16, 0, 0);
}

// XCD-aware linear block swizzle (requires nwg % 8 == 0)
__device__ __forceinline__ int xcd_swz(int bid, int nwg) {
    int cpx = nwg >> 3;
    return (bid & 7) * cpx + (bid >> 3);
}

// fast GELU (tanh form) in exp2 domain: x * sigmoid(1.5958*(x+0.044715x^3))
// sigmoid(g) = 1/(1+exp(-g)) = 1/(1+exp2(-g*log2e)); 1.5957691*log2e = 2.3024523
__device__ __forceinline__ float gelu_fast(float x) {
    float g2 = 2.3024523389544817f * (x + 0.044715f * x * x * x);
    return x / (1.0f + EXP2(-g2));
}

// ---------------- prologue: weight casts (blocks [0,6656)) + LN1 (blocks [6656,14848)) --------
__global__ __launch_bounds__(256) void prologue_cast_ln(const float* __restrict__ Wq,
                                                        const float* __restrict__ Wkv,
                                                        const float* __restrict__ Wo,
                                                        const float* __restrict__ W1,
                                                        const float* __restrict__ W2,
                                                        __hip_bfloat16* __restrict__ dqkv,
                                                        __hip_bfloat16* __restrict__ dWo,
                                                        __hip_bfloat16* __restrict__ dW1,
                                                        __hip_bfloat16* __restrict__ dW2,
                                                        const float* __restrict__ x,
                                                        const float* __restrict__ g,
                                                        const float* __restrict__ bta,
                                                        __hip_bfloat16* __restrict__ hb) {
    int tid = threadIdx.x;
    if (blockIdx.x < 6656) {
        int i = blockIdx.x * 256 + tid;   // quad index, total exactly 6656*256 = 1703936
        const float* src; __hip_bfloat16* dst; int off;
        if (i < 262144)       { src = Wq;  dst = dqkv;            off = i; }
        else if (i < 393216)  { src = Wkv; dst = dqkv + 1048576;  off = i - 262144; }
        else if (i < 655360)  { src = Wo;  dst = dWo;             off = i - 393216; }
        else if (i < 1179648) { src = W1;  dst = dW1;             off = i - 655360; }
        else                  { src = W2;  dst = dW2;             off = i - 1179648; }
        float4 v = *(const float4*)&src[(size_t)off*4];
        ushort4 o = { f2bu(v.x), f2bu(v.y), f2bu(v.z), f2bu(v.w) };
        *(ushort4*)&dst[(size_t)off*4] = o;
        return;
    }
    int row = blockIdx.x - 6656;
    const float* xr = x + (size_t)row * D_;
    int c = tid * 4;
    float4 v = *(const float4*)&xr[c];
    float s = v.x + v.y + v.z + v.w;
#pragma unroll
    for (int off = 32; off >= 1; off >>= 1) s += __shfl_xor(s, off);
    __shared__ float sm[4], sv[4];
    int wid = tid >> 6, lane = tid & 63;
    if (lane == 0) sm[wid] = s;
    __syncthreads();
    float mean = (sm[0] + sm[1] + sm[2] + sm[3]) * (1.0f / D_);
    float d0 = v.x - mean, d1 = v.y - mean, d2 = v.z - mean, d3 = v.w - mean;
    float qq = d0*d0 + d1*d1 + d2*d2 + d3*d3;
#pragma unroll
    for (int off = 32; off >= 1; off >>= 1) qq += __shfl_xor(qq, off);
    if (lane == 0) sv[wid] = qq;
    __syncthreads();
    float var = (sv[0] + sv[1] + sv[2] + sv[3]) * (1.0f / D_);
    float rstd = rsqrtf(var + 1e-5f);
    float4 gg = *(const float4*)&g[c];
    float4 bb = *(const float4*)&bta[c];
    ushort4 o = { f2bu(d0 * rstd * gg.x + bb.x),
                  f2bu(d1 * rstd * gg.y + bb.y),
                  f2bu(d2 * rstd * gg.z + bb.z),
                  f2bu(d3 * rstd * gg.w + bb.w) };
    *(ushort4*)&(hb + (size_t)row * D_)[c] = o;
}

// ---------------- LayerNorm with bf16 input -> bf16 out: one block per row ----------------
__global__ __launch_bounds__(256) void ln_bf16_in(const __hip_bfloat16* __restrict__ x,
                                                  const float* __restrict__ g,
                                                  const float* __restrict__ bta,
                                                  __hip_bfloat16* __restrict__ out) {
    int row = blockIdx.x;
    int tid = threadIdx.x;
    const __hip_bfloat16* xr = x + (size_t)row * D_;
    int c = tid * 4;
    ushort4 u = *(const ushort4*)&xr[c];
    float v0 = bu2f(u.x), v1 = bu2f(u.y), v2 = bu2f(u.z), v3 = bu2f(u.w);
    float s = v0 + v1 + v2 + v3;
#pragma unroll
    for (int off = 32; off >= 1; off >>= 1) s += __shfl_xor(s, off);
    __shared__ float sm[4], sv[4];
    int wid = tid >> 6, lane = tid & 63;
    if (lane == 0) sm[wid] = s;
    __syncthreads();
    float mean = (sm[0] + sm[1] + sm[2] + sm[3]) * (1.0f / D_);
    float d0 = v0 - mean, d1 = v1 - mean, d2 = v2 - mean, d3 = v3 - mean;
    float qq = d0*d0 + d1*d1 + d2*d2 + d3*d3;
#pragma unroll
    for (int off = 32; off >= 1; off >>= 1) qq += __shfl_xor(qq, off);
    if (lane == 0) sv[wid] = qq;
    __syncthreads();
    float var = (sv[0] + sv[1] + sv[2] + sv[3]) * (1.0f / D_);
    float rstd = rsqrtf(var + 1e-5f);
    float4 gg = *(const float4*)&g[c];
    float4 bb = *(const float4*)&bta[c];
    ushort4 o = { f2bu(d0 * rstd * gg.x + bb.x),
                  f2bu(d1 * rstd * gg.y + bb.y),
                  f2bu(d2 * rstd * gg.z + bb.z),
                  f2bu(d3 * rstd * gg.w + bb.w) };
    *(ushort4*)&(out + (size_t)row * D_)[c] = o;
}

// ---------------- bf16 MFMA GEMM, BK=64, swizzled LDS ----------------
// MODE 1: += res(f32), out bf16 Cb  (x2b = x + attn@Wo)
// MODE 2: += bias, gelu, out bf16 Cb (gbuf)
// MODE 3: += bias, += resb(bf16), out f32 Cf (final out)
template<int MODE>
__global__ __launch_bounds__(256) void gemm_mfma(const __hip_bfloat16* __restrict__ A,
                                                 const __hip_bfloat16* __restrict__ W,
                                                 const float* __restrict__ bias,
                                                 const float* __restrict__ res,
                                                 const __hip_bfloat16* __restrict__ resb,
                                                 float* __restrict__ Cf,
                                                 __hip_bfloat16* __restrict__ Cb,
                                                 int M, int N, int K) {
    __shared__ __hip_bfloat16 At[128*64];
    __shared__ __hip_bfloat16 Bt[128*64];
    int tid = threadIdx.x;
    int w = tid >> 6, lane = tid & 63;
    int l15 = lane & 15, lhi = lane >> 4;
    int swz = xcd_swz(blockIdx.x, gridDim.x);
    int gx = N >> 7;
    int bn = (swz % gx) * 128, bm = (swz / gx) * 128;
    int wr = w >> 1, wc = w & 1;
    f32x4 acc[4][4] = {};

    for (int k0 = 0; k0 < K; k0 += 64) {
#pragma unroll
        for (int iss = 0; iss < 4; ++iss) {
            int idx = iss*256 + tid;               // 0..1023
            int row = idx >> 3;                    // 0..127
            int cb  = (idx & 7) * 16;              // byte col within 128B row
            int sce = (cb ^ ((row & 7) << 4)) >> 1;  // pre-swizzled source col (elements)
            int ldso = idx * 16;                   // linear LDS byte offset
            gload_lds16(A + (size_t)(bm + row) * K + k0 + sce, (char*)At + ldso);
            gload_lds16(W + (size_t)(bn + row) * K + k0 + sce, (char*)Bt + ldso);
        }
        __syncthreads();
#pragma unroll
        for (int kk = 0; kk < 2; ++kk) {
            short8 af[4], bf[4];
#pragma unroll
            for (int m = 0; m < 4; ++m)
                af[m] = *(const short8*)((char*)At + KSWZ(wr*64 + m*16 + l15, kk*64 + lhi*16));
#pragma unroll
            for (int n = 0; n < 4; ++n)
                bf[n] = *(const short8*)((char*)Bt + KSWZ(wc*64 + n*16 + l15, kk*64 + lhi*16));
#pragma unroll
            for (int m = 0; m < 4; ++m)
#pragma unroll
                for (int n = 0; n < 4; ++n)
                    acc[m][n] = __builtin_amdgcn_mfma_f32_16x16x32_bf16(af[m], bf[n], acc[m][n], 0, 0, 0);
        }
        __syncthreads();
    }

#pragma unroll
    for (int m = 0; m < 4; ++m) {
#pragma unroll
        for (int j = 0; j < 4; ++j) {
            int row = bm + wr*64 + m*16 + lhi*4 + j;
#pragma unroll
            for (int n = 0; n < 4; ++n) {
                int col = bn + wc*64 + n*16 + l15;
                float val = acc[m][n][j];
                if (MODE == 2 || MODE == 3) val += bias[col];
                if (MODE == 2) val = gelu_fast(val);
                if (MODE == 1) val += res[(size_t)row * N + col];
                if (MODE == 3) val += bu2f(*(const unsigned short*)&resb[(size_t)row * N + col]);
                if (MODE == 3) Cf[(size_t)row * N + col] = val;
                else           Cb[(size_t)row * N + col] = __float2bfloat16(val);
            }
        }
    }
}

// ---------------- QKV GEMM with fused RoPE epilogue (BK=64, swizzled, XCD swizzle) -------------
// q is pre-scaled by (1/8)*log2e so attention scores land in the exp2 domain.
__global__ __launch_bounds__(256) void gemm_qkv_rope(const __hip_bfloat16* __restrict__ A,
                                                     const __hip_bfloat16* __restrict__ W,
                                                     const float* __restrict__ cosb,
                                                     const float* __restrict__ sinb,
                                                     __hip_bfloat16* __restrict__ qb,
                                                     __hip_bfloat16* __restrict__ kbb,
                                                     __hip_bfloat16* __restrict__ vbt) {
    const int K = D_;
    const float QS = 0.125f * 1.4426950408889634f;
    __shared__ __hip_bfloat16 At[128*64];
    __shared__ __hip_bfloat16 Bt[128*64];
    int tid = threadIdx.x;
    int w = tid >> 6, lane = tid & 63;
    int l15 = lane & 15, lhi = lane >> 4;
    int swz = xcd_swz(blockIdx.x, gridDim.x);
    const int gx = QKVW >> 7;   // 12
    int bn = (swz % gx) * 128, bm = (swz / gx) * 128;
    int wr = w >> 1, wc = w & 1;
    f32x4 acc[4][4] = {};

    for (int k0 = 0; k0 < K; k0 += 64) {
#pragma unroll
        for (int iss = 0; iss < 4; ++iss) {
            int idx = iss*256 + tid;
            int row = idx >> 3;
            int cb  = (idx & 7) * 16;
            int sce = (cb ^ ((row & 7) << 4)) >> 1;
            int ldso = idx * 16;
            gload_lds16(A + (size_t)(bm + row) * K + k0 + sce, (char*)At + ldso);
            gload_lds16(W + (size_t)(bn + row) * K + k0 + sce, (char*)Bt + ldso);
        }
        __syncthreads();
#pragma unroll
        for (int kk = 0; kk < 2; ++kk) {
            short8 af[4], bf[4];
#pragma unroll
            for (int m = 0; m < 4; ++m)
                af[m] = *(const short8*)((char*)At + KSWZ(wr*64 + m*16 + l15, kk*64 + lhi*16));
#pragma unroll
            for (int n = 0; n < 4; ++n)
                bf[n] = *(const short8*)((char*)Bt + KSWZ(wc*64 + n*16 + l15, kk*64 + lhi*16));
#pragma unroll
            for (int m = 0; m < 4; ++m)
#pragma unroll
                for (int n = 0; n < 4; ++n)
                    acc[m][n] = __builtin_amdgcn_mfma_f32_16x16x32_bf16(af[m], bf[n], acc[m][n], 0, 0, 0);
        }
        __syncthreads();
    }

    bool is_q = (bn < 1024);
    bool is_v = (!is_q) && (wc == 1);   // wave-uniform
    if (!is_v) {
#pragma unroll
        for (int m = 0; m < 4; ++m) {
#pragma unroll
            for (int j = 0; j < 4; ++j) {
                int row = bm + wr*64 + m*16 + lhi*4 + j;
                int b = row >> 11, t = row & (T_ - 1);
                const float* crow = cosb + t*HD_;
                const float* srow = sinb + t*HD_;
#pragma unroll
                for (int n = 0; n < 4; ++n) {
                    int col = bn + wc*64 + n*16 + l15;
                    int hd = n*16 + l15;
                    float val = acc[m][n][j];
                    float part = __shfl_xor(val, 1);
                    float rot = (l15 & 1) ? part : -part;
                    float o = val * crow[hd] + rot * srow[hd];
                    if (is_q) {
                        int h = col >> 6;
                        qb[(((size_t)(b*QH + h))*T_ + t)*HD_ + hd] = __float2bfloat16(o * QS);
                    } else {
                        int kvh = (col - 1024) >> 7;
                        kbb[(((size_t)(b*KVH + kvh))*T_ + t)*HD_ + hd] = __float2bfloat16(o);
                    }
                }
            }
        }
    } else {
#pragma unroll
        for (int m = 0; m < 4; ++m) {
            int row0 = bm + wr*64 + m*16 + lhi*4;
            int b = row0 >> 11, t0 = row0 & (T_ - 1);
#pragma unroll
            for (int n = 0; n < 4; ++n) {
                int col = bn + 64 + n*16 + l15;
                int kvh = (col - 1024) >> 7;
                int hd = n*16 + l15;
                short4v pk = { (short)f2bu(acc[m][n][0]), (short)f2bu(acc[m][n][1]),
                               (short)f2bu(acc[m][n][2]), (short)f2bu(acc[m][n][3]) };
                *(short4v*)&vbt[(((size_t)(b*KVH + kvh))*HD_ + hd)*T_ + t0] = pk;
            }
        }
    }
}

// ---------------- Flash attention: R20 structure, exp2-domain softmax ----------------
// Scores are in log2 units (q pre-scaled by log2e/8). EXP2 = bare v_exp_f32.
__global__ __launch_bounds__(256) void attn_mfma(const __hip_bfloat16* __restrict__ qb,
                                                 const __hip_bfloat16* __restrict__ kb,
                                                 const __hip_bfloat16* __restrict__ vbt,
                                                 __hip_bfloat16* __restrict__ ob) {
    __shared__ __hip_bfloat16 Ks[2][64*64];   // [key][d]   swizzled
    __shared__ __hip_bfloat16 Vs[2][64*64];   // [d][key]   swizzled
    __shared__ __hip_bfloat16 Ps[64*64];      // [qrow][key] swizzled, per-wave rows
    char* PsB = (char*)Ps;
    int tid = threadIdx.x;
    int w = tid >> 6, lane = tid & 63;
    int l15 = lane & 15, lhi = lane >> 4;
    int bh = blockIdx.y;
    int b = bh >> 4, h = bh & 15;
    int bk = b * KVH + (h >> 2);
    int qt0 = blockIdx.x * 64;

    const __hip_bfloat16* qrow = qb + ((size_t)bh * T_ + qt0 + w*16 + l15) * HD_;
    short8 qf0 = *(const short8*)(qrow + lhi*8);
    short8 qf1 = *(const short8*)(qrow + 32 + lhi*8);

    f32x4 oacc[4] = {};          // O^T[d=cb*16+lhi*4+r][qrow=l15]
    f32x4 lacc = {};             // l for qrow=l15 (all regs identical)
    float m_run = -INFINITY;     // running max in log2 units
    const short ONE_BF = (short)0x3F80;   // bf16 1.0
    const short8 onesf = { ONE_BF, ONE_BF, ONE_BF, ONE_BF, ONE_BF, ONE_BF, ONE_BF, ONE_BF };

    int sr = tid >> 2;                 // staging row 0..63
    int scB = (tid & 3) * 32;          // staging col byte {0,32,64,96}
    const __hip_bfloat16* kbase = kb  + (size_t)bk * T_ * HD_;
    const __hip_bfloat16* vbase = vbt + (size_t)bk * HD_ * T_;
    int sce = (tid & 3) * 16;          // element offset for global side

    // prologue: stage tile 0 into buf0
    {
        short8 ra = *(const short8*)(kbase + (size_t)sr*HD_ + sce);
        short8 rb = *(const short8*)(kbase + (size_t)sr*HD_ + sce + 8);
        short8 rc = *(const short8*)(vbase + (size_t)sr*T_ + sce);
        short8 rd = *(const short8*)(vbase + (size_t)sr*T_ + sce + 8);
        *(short8*)((char*)Ks[0] + KSWZ(sr, scB))      = ra;
        *(short8*)((char*)Ks[0] + KSWZ(sr, scB + 16)) = rb;
        *(short8*)((char*)Vs[0] + KSWZ(sr, scB))      = rc;
        *(short8*)((char*)Vs[0] + KSWZ(sr, scB + 16)) = rd;
    }
    __syncthreads();
    int cur = 0;
    const int NT = T_ / 64;

    for (int it = 0; it < NT; ++it) {
        short8 ra, rb, rc, rd;
        bool pfv = (it + 1 < NT);
        if (pfv) {
            int s0n = (it + 1) * 64;
            ra = *(const short8*)(kbase + (size_t)(s0n + sr)*HD_ + sce);
            rb = *(const short8*)(kbase + (size_t)(s0n + sr)*HD_ + sce + 8);
            rc = *(const short8*)(vbase + (size_t)sr*T_ + s0n + sce);
            rd = *(const short8*)(vbase + (size_t)sr*T_ + s0n + sce + 8);
        }
        char* KsB = (char*)Ks[cur];
        char* VsB = (char*)Vs[cur];

        // S^T = K Q^T (scores in log2 units)
        f32x4 accs[4];
#pragma unroll
        for (int cb = 0; cb < 4; ++cb) {
            f32x4 z = {0.f, 0.f, 0.f, 0.f};
            short8 k0 = *(const short8*)(KsB + KSWZ(cb*16 + l15, lhi*16));
            short8 k1 = *(const short8*)(KsB + KSWZ(cb*16 + l15, 64 + lhi*16));
            __builtin_amdgcn_s_setprio(1);
            z = __builtin_amdgcn_mfma_f32_16x16x32_bf16(k0, qf0, z, 0, 0, 0);
            z = __builtin_amdgcn_mfma_f32_16x16x32_bf16(k1, qf1, z, 0, 0, 0);
            __builtin_amdgcn_s_setprio(0);
            accs[cb] = z;
        }

        // per-lane local max (no cross-lane reduce in common path)
        float mxl = -INFINITY;
#pragma unroll
        for (int cb = 0; cb < 4; ++cb)
#pragma unroll
            for (int r = 0; r < 4; ++r) mxl = fmaxf(mxl, accs[cb][r]);

        // defer-max (THR=8 in log2 units: P bounded by 2^8)
        if (!__all(mxl <= m_run + 8.0f)) {
            float mx = mxl;
            mx = fmaxf(mx, __shfl_xor(mx, 16));
            mx = fmaxf(mx, __shfl_xor(mx, 32));
            float mn = fmaxf(m_run, mx);
            float cr = EXP2(m_run - mn);
            m_run = mn;
#pragma unroll
            for (int r = 0; r < 4; ++r) lacc[r] *= cr;
#pragma unroll
            for (int cb = 0; cb < 4; ++cb)
#pragma unroll
                for (int r = 0; r < 4; ++r) oacc[cb][r] *= cr;
        }

        int pr = w*16 + l15;               // per-wave P row
#pragma unroll
        for (int cb = 0; cb < 4; ++cb) {
            f32x4 p;
#pragma unroll
            for (int r = 0; r < 4; ++r) p[r] = EXP2(accs[cb][r] - m_run);
            short4v pk = { (short)f2bu(p[0]), (short)f2bu(p[1]),
                           (short)f2bu(p[2]), (short)f2bu(p[3]) };
            *(short4v*)(PsB + KSWZ(pr, cb*32 + lhi*8)) = pk;
        }

        // O^T += V^T P^T ; lacc += ones * P^T
#pragma unroll
        for (int kk = 0; kk < 2; ++kk) {
            short8 pf = *(const short8*)(PsB + KSWZ(w*16 + l15, kk*64 + lhi*16));
            __builtin_amdgcn_s_setprio(1);
            lacc = __builtin_amdgcn_mfma_f32_16x16x32_bf16(onesf, pf, lacc, 0, 0, 0);
#pragma unroll
            for (int cb = 0; cb < 4; ++cb) {
                short8 vf = *(const short8*)(VsB + KSWZ(cb*16 + l15, kk*64 + lhi*16));
                oacc[cb] = __builtin_amdgcn_mfma_f32_16x16x32_bf16(vf, pf, oacc[cb], 0, 0, 0);
            }
            __builtin_amdgcn_s_setprio(0);
        }

        if (pfv) {
            char* KnB = (char*)Ks[cur ^ 1];
            char* VnB = (char*)Vs[cur ^ 1];
            *(short8*)(KnB + KSWZ(sr, scB))      = ra;
            *(short8*)(KnB + KSWZ(sr, scB + 16)) = rb;
            *(short8*)(VnB + KSWZ(sr, scB))      = rc;
            *(short8*)(VnB + KSWZ(sr, scB + 16)) = rd;
        }
        __syncthreads();
        cur ^= 1;
    }

    float inv = 1.0f / lacc[0];
    int t = qt0 + w*16 + l15;
    __hip_bfloat16* orow = ob + (size_t)(b*T_ + t) * D_ + h*HD_;
#pragma unroll
    for (int cb = 0; cb < 4; ++cb) {
        short4v okv = { (short)f2bu(oacc[cb][0] * inv), (short)f2bu(oacc[cb][1] * inv),
                        (short)f2bu(oacc[cb][2] * inv), (short)f2bu(oacc[cb][3] * inv) };
        *(short4v*)&orow[cb*16 + lhi*4] = okv;
    }
}

extern "C" void kernel_launch(void* const* d_in, const int* in_sizes, int n_in,
                              void* d_out, int out_size, void* d_ws, size_t ws_size,
                              hipStream_t stream) {
    const float* x    = (const float*)d_in[0];
    const float* cosb = (const float*)d_in[1];
    const float* sinb = (const float*)d_in[2];
    const float* Wq   = (const float*)d_in[3];
    const float* Wkv  = (const float*)d_in[4];
    const float* Wo   = (const float*)d_in[5];
    const float* ln1g = (const float*)d_in[6];
    const float* ln1b = (const float*)d_in[7];
    const float* ln2g = (const float*)d_in[8];
    const float* ln2b = (const float*)d_in[9];
    const float* W1   = (const float*)d_in[10];
    const float* b1   = (const float*)d_in[11];
    const float* W2   = (const float*)d_in[12];
    const float* b2   = (const float*)d_in[13];
    float* out = (float*)d_out;

    float* ws = (float*)d_ws;
    const size_t M = 1024 * 1024;
    __hip_bfloat16* hb   = (__hip_bfloat16*)(ws);
    __hip_bfloat16* x2b  = (__hip_bfloat16*)(ws + 4*M);    // bf16 residual x2
    __hip_bfloat16* gbuf = (__hip_bfloat16*)(ws + 12*M);
    __hip_bfloat16* ob   = (__hip_bfloat16*)(ws + 20*M);
    __hip_bfloat16* qb   = (__hip_bfloat16*)(ws + 24*M);
    __hip_bfloat16* kbb  = (__hip_bfloat16*)(ws + 28*M);
    __hip_bfloat16* vbt  = (__hip_bfloat16*)(ws + 29*M);
    __hip_bfloat16* Wqkvb= (__hip_bfloat16*)(ws + 30*M);
    __hip_bfloat16* Wob  = (__hip_bfloat16*)(ws + 30*M + 3*M/4);
    __hip_bfloat16* W1b  = (__hip_bfloat16*)(ws + 31*M + M/4);
    __hip_bfloat16* W2b  = (__hip_bfloat16*)(ws + 32*M + M/4);

    // 0+1. weight casts + LN1 fused
    prologue_cast_ln<<<6656 + R_, 256, 0, stream>>>(Wq, Wkv, Wo, W1, W2,
                                                    Wqkvb, Wob, W1b, W2b,
                                                    x, ln1g, ln1b, hb);

    // 2+3. qkv GEMM with fused RoPE -> qb/kbb/vbt (bf16), XCD-swizzled 1D grid (768 blocks)
    gemm_qkv_rope<<<(QKVW/128)*(R_/128), 256, 0, stream>>>(hb, Wqkvb, cosb, sinb, qb, kbb, vbt);
    // 4. attention -> ob (bf16)
    attn_mfma<<<dim3(T_/64, B_*QH), 256, 0, stream>>>(qb, kbb, vbt, ob);
    // 5. x2b = x + ob @ Wob^T (bf16 out, 512 blocks)
    gemm_mfma<1><<<(D_/128)*(R_/128), 256, 0, stream>>>(ob, Wob, nullptr, x, nullptr, nullptr, x2b, R_, D_, D_);
    // 6. LN2 (bf16 in) -> hb (bf16)
    ln_bf16_in<<<R_, 256, 0, stream>>>(x2b, ln2g, ln2b, hb);
    // 7. gbuf = gelu(hb @ W1b^T + b1) (bf16 out, 1024 blocks)
    gemm_mfma<2><<<(DFF/128)*(R_/128), 256, 0, stream>>>(hb, W1b, b1, nullptr, nullptr, nullptr, gbuf, R_, DFF, D_);
    // 8. out = x2b + gbuf @ W2b^T + b2 (f32 out, 512 blocks)
    gemm_mfma<3><<<(D_/128)*(R_/128), 256, 0, stream>>>(gbuf, W2b, b2, nullptr, x2b, out, nullptr, R_, D_, DFF);
}

// Round 24
// 283.505 us; speedup vs baseline: 1.4521x; 1.0651x over previous
//
#include <hip/hip_runtime.h>
#include <hip/hip_bf16.h>
#include <math.h>
#include <stdint.h>

#define B_   4
#define T_   2048
#define D_   1024
#define QH   16
#define KVH  4
#define HD_  64
#define R_   (B_*T_)      // 8192 rows
#define DFF  2048
#define QKVW 1536         // fused q(1024) + kv(512) output width

typedef short short8 __attribute__((ext_vector_type(8)));
typedef short short4v __attribute__((ext_vector_type(4)));
typedef float f32x4 __attribute__((ext_vector_type(4)));

// native exp2 (bare v_exp_f32); guarded fallback is mathematically identical
#if __has_builtin(__builtin_amdgcn_exp2f)
#define EXP2(x) __builtin_amdgcn_exp2f(x)
#else
#define EXP2(x) __expf((x) * 0.6931471805599453f)
#endif

static __device__ __forceinline__ unsigned short f2bu(float x) {
    __hip_bfloat16 h = __float2bfloat16(x);
    return *reinterpret_cast<unsigned short*>(&h);
}
static __device__ __forceinline__ float bu2f(unsigned short u) {
    unsigned int w = ((unsigned int)u) << 16;
    return *reinterpret_cast<float*>(&w);
}

// swizzled byte offset within a 128B/row LDS tile (8-row XOR stripe)
#define KSWZ(row, cbyte) (((row) << 7) + ((cbyte) ^ (((row) & 7) << 4)))

__device__ __forceinline__ void gload_lds16(const void* g, void* l) {
    typedef __attribute__((address_space(1))) void gv_t;
    typedef __attribute__((address_space(3))) void lv_t;
    __builtin_amdgcn_global_load_lds((gv_t*)g, (lv_t*)l, 16, 0, 0);
}

// XCD-aware linear block swizzle (requires nwg % 8 == 0)
__device__ __forceinline__ int xcd_swz(int bid, int nwg) {
    int cpx = nwg >> 3;
    return (bid & 7) * cpx + (bid >> 3);
}

// fast GELU (tanh form) in exp2 domain
__device__ __forceinline__ float gelu_fast(float x) {
    float g2 = 2.3024523389544817f * (x + 0.044715f * x * x * x);
    return x / (1.0f + EXP2(-g2));
}

// ---------------- prologue: weight casts (blocks [0,6656)) + LN1 (blocks [6656,14848)) --------
__global__ __launch_bounds__(256) void prologue_cast_ln(const float* __restrict__ Wq,
                                                        const float* __restrict__ Wkv,
                                                        const float* __restrict__ Wo,
                                                        const float* __restrict__ W1,
                                                        const float* __restrict__ W2,
                                                        __hip_bfloat16* __restrict__ dqkv,
                                                        __hip_bfloat16* __restrict__ dWo,
                                                        __hip_bfloat16* __restrict__ dW1,
                                                        __hip_bfloat16* __restrict__ dW2,
                                                        const float* __restrict__ x,
                                                        const float* __restrict__ g,
                                                        const float* __restrict__ bta,
                                                        __hip_bfloat16* __restrict__ hb) {
    int tid = threadIdx.x;
    if (blockIdx.x < 6656) {
        int i = blockIdx.x * 256 + tid;   // quad index, total exactly 6656*256 = 1703936
        const float* src; __hip_bfloat16* dst; int off;
        if (i < 262144)       { src = Wq;  dst = dqkv;            off = i; }
        else if (i < 393216)  { src = Wkv; dst = dqkv + 1048576;  off = i - 262144; }
        else if (i < 655360)  { src = Wo;  dst = dWo;             off = i - 393216; }
        else if (i < 1179648) { src = W1;  dst = dW1;             off = i - 655360; }
        else                  { src = W2;  dst = dW2;             off = i - 1179648; }
        float4 v = *(const float4*)&src[(size_t)off*4];
        ushort4 o = { f2bu(v.x), f2bu(v.y), f2bu(v.z), f2bu(v.w) };
        *(ushort4*)&dst[(size_t)off*4] = o;
        return;
    }
    int row = blockIdx.x - 6656;
    const float* xr = x + (size_t)row * D_;
    int c = tid * 4;
    float4 v = *(const float4*)&xr[c];
    float s = v.x + v.y + v.z + v.w;
#pragma unroll
    for (int off = 32; off >= 1; off >>= 1) s += __shfl_xor(s, off);
    __shared__ float sm[4], sv[4];
    int wid = tid >> 6, lane = tid & 63;
    if (lane == 0) sm[wid] = s;
    __syncthreads();
    float mean = (sm[0] + sm[1] + sm[2] + sm[3]) * (1.0f / D_);
    float d0 = v.x - mean, d1 = v.y - mean, d2 = v.z - mean, d3 = v.w - mean;
    float qq = d0*d0 + d1*d1 + d2*d2 + d3*d3;
#pragma unroll
    for (int off = 32; off >= 1; off >>= 1) qq += __shfl_xor(qq, off);
    if (lane == 0) sv[wid] = qq;
    __syncthreads();
    float var = (sv[0] + sv[1] + sv[2] + sv[3]) * (1.0f / D_);
    float rstd = rsqrtf(var + 1e-5f);
    float4 gg = *(const float4*)&g[c];
    float4 bb = *(const float4*)&bta[c];
    ushort4 o = { f2bu(d0 * rstd * gg.x + bb.x),
                  f2bu(d1 * rstd * gg.y + bb.y),
                  f2bu(d2 * rstd * gg.z + bb.z),
                  f2bu(d3 * rstd * gg.w + bb.w) };
    *(ushort4*)&(hb + (size_t)row * D_)[c] = o;
}

// ---------------- LayerNorm with bf16 input -> bf16 out: one block per row ----------------
__global__ __launch_bounds__(256) void ln_bf16_in(const __hip_bfloat16* __restrict__ x,
                                                  const float* __restrict__ g,
                                                  const float* __restrict__ bta,
                                                  __hip_bfloat16* __restrict__ out) {
    int row = blockIdx.x;
    int tid = threadIdx.x;
    const __hip_bfloat16* xr = x + (size_t)row * D_;
    int c = tid * 4;
    ushort4 u = *(const ushort4*)&xr[c];
    float v0 = bu2f(u.x), v1 = bu2f(u.y), v2 = bu2f(u.z), v3 = bu2f(u.w);
    float s = v0 + v1 + v2 + v3;
#pragma unroll
    for (int off = 32; off >= 1; off >>= 1) s += __shfl_xor(s, off);
    __shared__ float sm[4], sv[4];
    int wid = tid >> 6, lane = tid & 63;
    if (lane == 0) sm[wid] = s;
    __syncthreads();
    float mean = (sm[0] + sm[1] + sm[2] + sm[3]) * (1.0f / D_);
    float d0 = v0 - mean, d1 = v1 - mean, d2 = v2 - mean, d3 = v3 - mean;
    float qq = d0*d0 + d1*d1 + d2*d2 + d3*d3;
#pragma unroll
    for (int off = 32; off >= 1; off >>= 1) qq += __shfl_xor(qq, off);
    if (lane == 0) sv[wid] = qq;
    __syncthreads();
    float var = (sv[0] + sv[1] + sv[2] + sv[3]) * (1.0f / D_);
    float rstd = rsqrtf(var + 1e-5f);
    float4 gg = *(const float4*)&g[c];
    float4 bb = *(const float4*)&bta[c];
    ushort4 o = { f2bu(d0 * rstd * gg.x + bb.x),
                  f2bu(d1 * rstd * gg.y + bb.y),
                  f2bu(d2 * rstd * gg.z + bb.z),
                  f2bu(d3 * rstd * gg.w + bb.w) };
    *(ushort4*)&(out + (size_t)row * D_)[c] = o;
}

// ---------------- bf16 MFMA GEMM, BK=64, swizzled LDS ----------------
// MODE 1: += res(f32), out bf16 Cb; MODE 2: += bias, gelu, out bf16 Cb;
// MODE 3: += bias, += resb(bf16), out f32 Cf
template<int MODE>
__global__ __launch_bounds__(256) void gemm_mfma(const __hip_bfloat16* __restrict__ A,
                                                 const __hip_bfloat16* __restrict__ W,
                                                 const float* __restrict__ bias,
                                                 const float* __restrict__ res,
                                                 const __hip_bfloat16* __restrict__ resb,
                                                 float* __restrict__ Cf,
                                                 __hip_bfloat16* __restrict__ Cb,
                                                 int M, int N, int K) {
    __shared__ __hip_bfloat16 At[128*64];
    __shared__ __hip_bfloat16 Bt[128*64];
    int tid = threadIdx.x;
    int w = tid >> 6, lane = tid & 63;
    int l15 = lane & 15, lhi = lane >> 4;
    int swz = xcd_swz(blockIdx.x, gridDim.x);
    int gx = N >> 7;
    int bn = (swz % gx) * 128, bm = (swz / gx) * 128;
    int wr = w >> 1, wc = w & 1;
    f32x4 acc[4][4] = {};

    for (int k0 = 0; k0 < K; k0 += 64) {
#pragma unroll
        for (int iss = 0; iss < 4; ++iss) {
            int idx = iss*256 + tid;               // 0..1023
            int row = idx >> 3;                    // 0..127
            int cb  = (idx & 7) * 16;              // byte col within 128B row
            int sce = (cb ^ ((row & 7) << 4)) >> 1;  // pre-swizzled source col (elements)
            int ldso = idx * 16;                   // linear LDS byte offset
            gload_lds16(A + (size_t)(bm + row) * K + k0 + sce, (char*)At + ldso);
            gload_lds16(W + (size_t)(bn + row) * K + k0 + sce, (char*)Bt + ldso);
        }
        __syncthreads();
#pragma unroll
        for (int kk = 0; kk < 2; ++kk) {
            short8 af[4], bf[4];
#pragma unroll
            for (int m = 0; m < 4; ++m)
                af[m] = *(const short8*)((char*)At + KSWZ(wr*64 + m*16 + l15, kk*64 + lhi*16));
#pragma unroll
            for (int n = 0; n < 4; ++n)
                bf[n] = *(const short8*)((char*)Bt + KSWZ(wc*64 + n*16 + l15, kk*64 + lhi*16));
#pragma unroll
            for (int m = 0; m < 4; ++m)
#pragma unroll
                for (int n = 0; n < 4; ++n)
                    acc[m][n] = __builtin_amdgcn_mfma_f32_16x16x32_bf16(af[m], bf[n], acc[m][n], 0, 0, 0);
        }
        __syncthreads();
    }

#pragma unroll
    for (int m = 0; m < 4; ++m) {
#pragma unroll
        for (int j = 0; j < 4; ++j) {
            int row = bm + wr*64 + m*16 + lhi*4 + j;
#pragma unroll
            for (int n = 0; n < 4; ++n) {
                int col = bn + wc*64 + n*16 + l15;
                float val = acc[m][n][j];
                if (MODE == 2 || MODE == 3) val += bias[col];
                if (MODE == 2) val = gelu_fast(val);
                if (MODE == 1) val += res[(size_t)row * N + col];
                if (MODE == 3) val += bu2f(*(const unsigned short*)&resb[(size_t)row * N + col]);
                if (MODE == 3) Cf[(size_t)row * N + col] = val;
                else           Cb[(size_t)row * N + col] = __float2bfloat16(val);
            }
        }
    }
}

// ---------------- QKV GEMM with fused RoPE epilogue (BK=64, swizzled, XCD swizzle) -------------
// q is pre-scaled by (1/8)*log2e so attention scores land in the exp2 domain.
__global__ __launch_bounds__(256) void gemm_qkv_rope(const __hip_bfloat16* __restrict__ A,
                                                     const __hip_bfloat16* __restrict__ W,
                                                     const float* __restrict__ cosb,
                                                     const float* __restrict__ sinb,
                                                     __hip_bfloat16* __restrict__ qb,
                                                     __hip_bfloat16* __restrict__ kbb,
                                                     __hip_bfloat16* __restrict__ vbt) {
    const int K = D_;
    const float QS = 0.125f * 1.4426950408889634f;
    __shared__ __hip_bfloat16 At[128*64];
    __shared__ __hip_bfloat16 Bt[128*64];
    int tid = threadIdx.x;
    int w = tid >> 6, lane = tid & 63;
    int l15 = lane & 15, lhi = lane >> 4;
    int swz = xcd_swz(blockIdx.x, gridDim.x);
    const int gx = QKVW >> 7;   // 12
    int bn = (swz % gx) * 128, bm = (swz / gx) * 128;
    int wr = w >> 1, wc = w & 1;
    f32x4 acc[4][4] = {};

    for (int k0 = 0; k0 < K; k0 += 64) {
#pragma unroll
        for (int iss = 0; iss < 4; ++iss) {
            int idx = iss*256 + tid;
            int row = idx >> 3;
            int cb  = (idx & 7) * 16;
            int sce = (cb ^ ((row & 7) << 4)) >> 1;
            int ldso = idx * 16;
            gload_lds16(A + (size_t)(bm + row) * K + k0 + sce, (char*)At + ldso);
            gload_lds16(W + (size_t)(bn + row) * K + k0 + sce, (char*)Bt + ldso);
        }
        __syncthreads();
#pragma unroll
        for (int kk = 0; kk < 2; ++kk) {
            short8 af[4], bf[4];
#pragma unroll
            for (int m = 0; m < 4; ++m)
                af[m] = *(const short8*)((char*)At + KSWZ(wr*64 + m*16 + l15, kk*64 + lhi*16));
#pragma unroll
            for (int n = 0; n < 4; ++n)
                bf[n] = *(const short8*)((char*)Bt + KSWZ(wc*64 + n*16 + l15, kk*64 + lhi*16));
#pragma unroll
            for (int m = 0; m < 4; ++m)
#pragma unroll
                for (int n = 0; n < 4; ++n)
                    acc[m][n] = __builtin_amdgcn_mfma_f32_16x16x32_bf16(af[m], bf[n], acc[m][n], 0, 0, 0);
        }
        __syncthreads();
    }

    bool is_q = (bn < 1024);
    bool is_v = (!is_q) && (wc == 1);   // wave-uniform
    if (!is_v) {
#pragma unroll
        for (int m = 0; m < 4; ++m) {
#pragma unroll
            for (int j = 0; j < 4; ++j) {
                int row = bm + wr*64 + m*16 + lhi*4 + j;
                int b = row >> 11, t = row & (T_ - 1);
                const float* crow = cosb + t*HD_;
                const float* srow = sinb + t*HD_;
#pragma unroll
                for (int n = 0; n < 4; ++n) {
                    int col = bn + wc*64 + n*16 + l15;
                    int hd = n*16 + l15;
                    float val = acc[m][n][j];
                    float part = __shfl_xor(val, 1);
                    float rot = (l15 & 1) ? part : -part;
                    float o = val * crow[hd] + rot * srow[hd];
                    if (is_q) {
                        int h = col >> 6;
                        qb[(((size_t)(b*QH + h))*T_ + t)*HD_ + hd] = __float2bfloat16(o * QS);
                    } else {
                        int kvh = (col - 1024) >> 7;
                        kbb[(((size_t)(b*KVH + kvh))*T_ + t)*HD_ + hd] = __float2bfloat16(o);
                    }
                }
            }
        }
    } else {
#pragma unroll
        for (int m = 0; m < 4; ++m) {
            int row0 = bm + wr*64 + m*16 + lhi*4;
            int b = row0 >> 11, t0 = row0 & (T_ - 1);
#pragma unroll
            for (int n = 0; n < 4; ++n) {
                int col = bn + 64 + n*16 + l15;
                int kvh = (col - 1024) >> 7;
                int hd = n*16 + l15;
                short4v pk = { (short)f2bu(acc[m][n][0]), (short)f2bu(acc[m][n][1]),
                               (short)f2bu(acc[m][n][2]), (short)f2bu(acc[m][n][3]) };
                *(short4v*)&vbt[(((size_t)(b*KVH + kvh))*HD_ + hd)*T_ + t0] = pk;
            }
        }
    }
}

// ---------------- Flash attention: 8 waves x 16 q-rows (QBLK=128), shared K/V staging ----------
// Per-wave work identical to R23; 8 waves share one K/V dbuf -> LDS 48KB, 3 blocks/CU
// = 24 waves/CU (75% occupancy vs 37%). Staging: 512 thr x 1 load per tile (K and V).
// exp2-domain softmax, predicate-only defer-max, ones-MFMA l, setprio.
__global__ __launch_bounds__(512) void attn_mfma(const __hip_bfloat16* __restrict__ qb,
                                                 const __hip_bfloat16* __restrict__ kb,
                                                 const __hip_bfloat16* __restrict__ vbt,
                                                 __hip_bfloat16* __restrict__ ob) {
    __shared__ __hip_bfloat16 Ks[2][64*64];   // [key][d]   swizzled, 2x8KB
    __shared__ __hip_bfloat16 Vs[2][64*64];   // [d][key]   swizzled, 2x8KB
    __shared__ __hip_bfloat16 Ps[128*64];     // [qrow][key] swizzled, per-wave rows, 16KB
    char* PsB = (char*)Ps;
    int tid = threadIdx.x;
    int w = tid >> 6, lane = tid & 63;        // w in 0..7
    int l15 = lane & 15, lhi = lane >> 4;
    int bh = blockIdx.y;
    int b = bh >> 4, h = bh & 15;
    int bk = b * KVH + (h >> 2);
    int qt0 = blockIdx.x * 128;

    const __hip_bfloat16* qrow = qb + ((size_t)bh * T_ + qt0 + w*16 + l15) * HD_;
    short8 qf0 = *(const short8*)(qrow + lhi*8);
    short8 qf1 = *(const short8*)(qrow + 32 + lhi*8);

    f32x4 oacc[4] = {};          // O^T[d=cb*16+lhi*4+r][qrow=l15]
    f32x4 lacc = {};             // l for qrow=l15 (all regs identical)
    float m_run = -INFINITY;     // running max in log2 units
    const short ONE_BF = (short)0x3F80;   // bf16 1.0
    const short8 onesf = { ONE_BF, ONE_BF, ONE_BF, ONE_BF, ONE_BF, ONE_BF, ONE_BF, ONE_BF };

    int sr  = tid >> 3;                // staging row 0..63 (512 thr, 8 chunks/row)
    int scB = (tid & 7) * 16;          // staging col byte {0,16,..,112}
    int sce = (tid & 7) * 8;           // linear source col (elements)
    const __hip_bfloat16* kbase = kb  + (size_t)bk * T_ * HD_;
    const __hip_bfloat16* vbase = vbt + (size_t)bk * HD_ * T_;

    // prologue: stage tile 0 into buf0 (1 K-load + 1 V-load per thread)
    {
        short8 ra = *(const short8*)(kbase + (size_t)sr*HD_ + sce);
        short8 rc = *(const short8*)(vbase + (size_t)sr*T_ + sce);
        *(short8*)((char*)Ks[0] + KSWZ(sr, scB)) = ra;
        *(short8*)((char*)Vs[0] + KSWZ(sr, scB)) = rc;
    }
    __syncthreads();
    int cur = 0;
    const int NT = T_ / 64;

    for (int it = 0; it < NT; ++it) {
        short8 ra, rc;
        bool pfv = (it + 1 < NT);
        if (pfv) {
            int s0n = (it + 1) * 64;
            ra = *(const short8*)(kbase + (size_t)(s0n + sr)*HD_ + sce);
            rc = *(const short8*)(vbase + (size_t)sr*T_ + s0n + sce);
        }
        char* KsB = (char*)Ks[cur];
        char* VsB = (char*)Vs[cur];

        // S^T = K Q^T (scores in log2 units)
        f32x4 accs[4];
#pragma unroll
        for (int cb = 0; cb < 4; ++cb) {
            f32x4 z = {0.f, 0.f, 0.f, 0.f};
            short8 k0 = *(const short8*)(KsB + KSWZ(cb*16 + l15, lhi*16));
            short8 k1 = *(const short8*)(KsB + KSWZ(cb*16 + l15, 64 + lhi*16));
            __builtin_amdgcn_s_setprio(1);
            z = __builtin_amdgcn_mfma_f32_16x16x32_bf16(k0, qf0, z, 0, 0, 0);
            z = __builtin_amdgcn_mfma_f32_16x16x32_bf16(k1, qf1, z, 0, 0, 0);
            __builtin_amdgcn_s_setprio(0);
            accs[cb] = z;
        }

        // per-lane local max (no cross-lane reduce in common path)
        float mxl = -INFINITY;
#pragma unroll
        for (int cb = 0; cb < 4; ++cb)
#pragma unroll
            for (int r = 0; r < 4; ++r) mxl = fmaxf(mxl, accs[cb][r]);

        // defer-max (THR=8 in log2 units: P bounded by 2^8)
        if (!__all(mxl <= m_run + 8.0f)) {
            float mx = mxl;
            mx = fmaxf(mx, __shfl_xor(mx, 16));
            mx = fmaxf(mx, __shfl_xor(mx, 32));
            float mn = fmaxf(m_run, mx);
            float cr = EXP2(m_run - mn);
            m_run = mn;
#pragma unroll
            for (int r = 0; r < 4; ++r) lacc[r] *= cr;
#pragma unroll
            for (int cb = 0; cb < 4; ++cb)
#pragma unroll
                for (int r = 0; r < 4; ++r) oacc[cb][r] *= cr;
        }

        int pr = w*16 + l15;               // per-wave P row (0..127)
#pragma unroll
        for (int cb = 0; cb < 4; ++cb) {
            f32x4 p;
#pragma unroll
            for (int r = 0; r < 4; ++r) p[r] = EXP2(accs[cb][r] - m_run);
            short4v pk = { (short)f2bu(p[0]), (short)f2bu(p[1]),
                           (short)f2bu(p[2]), (short)f2bu(p[3]) };
            *(short4v*)(PsB + KSWZ(pr, cb*32 + lhi*8)) = pk;
        }

        // O^T += V^T P^T ; lacc += ones * P^T
#pragma unroll
        for (int kk = 0; kk < 2; ++kk) {
            short8 pf = *(const short8*)(PsB + KSWZ(w*16 + l15, kk*64 + lhi*16));
            __builtin_amdgcn_s_setprio(1);
            lacc = __builtin_amdgcn_mfma_f32_16x16x32_bf16(onesf, pf, lacc, 0, 0, 0);
#pragma unroll
            for (int cb = 0; cb < 4; ++cb) {
                short8 vf = *(const short8*)(VsB + KSWZ(cb*16 + l15, kk*64 + lhi*16));
                oacc[cb] = __builtin_amdgcn_mfma_f32_16x16x32_bf16(vf, pf, oacc[cb], 0, 0, 0);
            }
            __builtin_amdgcn_s_setprio(0);
        }

        // write next tile into the other buffer (last read at t-1, behind barrier -> safe)
        if (pfv) {
            *(short8*)((char*)Ks[cur ^ 1] + KSWZ(sr, scB)) = ra;
            *(short8*)((char*)Vs[cur ^ 1] + KSWZ(sr, scB)) = rc;
        }
        __syncthreads();   // writes visible + all waves done reading cur
        cur ^= 1;
    }

    float inv = 1.0f / lacc[0];
    int t = qt0 + w*16 + l15;
    __hip_bfloat16* orow = ob + (size_t)(b*T_ + t) * D_ + h*HD_;
#pragma unroll
    for (int cb = 0; cb < 4; ++cb) {
        short4v okv = { (short)f2bu(oacc[cb][0] * inv), (short)f2bu(oacc[cb][1] * inv),
                        (short)f2bu(oacc[cb][2] * inv), (short)f2bu(oacc[cb][3] * inv) };
        *(short4v*)&orow[cb*16 + lhi*4] = okv;
    }
}

extern "C" void kernel_launch(void* const* d_in, const int* in_sizes, int n_in,
                              void* d_out, int out_size, void* d_ws, size_t ws_size,
                              hipStream_t stream) {
    const float* x    = (const float*)d_in[0];
    const float* cosb = (const float*)d_in[1];
    const float* sinb = (const float*)d_in[2];
    const float* Wq   = (const float*)d_in[3];
    const float* Wkv  = (const float*)d_in[4];
    const float* Wo   = (const float*)d_in[5];
    const float* ln1g = (const float*)d_in[6];
    const float* ln1b = (const float*)d_in[7];
    const float* ln2g = (const float*)d_in[8];
    const float* ln2b = (const float*)d_in[9];
    const float* W1   = (const float*)d_in[10];
    const float* b1   = (const float*)d_in[11];
    const float* W2   = (const float*)d_in[12];
    const float* b2   = (const float*)d_in[13];
    float* out = (float*)d_out;

    float* ws = (float*)d_ws;
    const size_t M = 1024 * 1024;
    __hip_bfloat16* hb   = (__hip_bfloat16*)(ws);
    __hip_bfloat16* x2b  = (__hip_bfloat16*)(ws + 4*M);    // bf16 residual x2
    __hip_bfloat16* gbuf = (__hip_bfloat16*)(ws + 12*M);
    __hip_bfloat16* ob   = (__hip_bfloat16*)(ws + 20*M);
    __hip_bfloat16* qb   = (__hip_bfloat16*)(ws + 24*M);
    __hip_bfloat16* kbb  = (__hip_bfloat16*)(ws + 28*M);
    __hip_bfloat16* vbt  = (__hip_bfloat16*)(ws + 29*M);
    __hip_bfloat16* Wqkvb= (__hip_bfloat16*)(ws + 30*M);
    __hip_bfloat16* Wob  = (__hip_bfloat16*)(ws + 30*M + 3*M/4);
    __hip_bfloat16* W1b  = (__hip_bfloat16*)(ws + 31*M + M/4);
    __hip_bfloat16* W2b  = (__hip_bfloat16*)(ws + 32*M + M/4);

    // 0+1. weight casts + LN1 fused
    prologue_cast_ln<<<6656 + R_, 256, 0, stream>>>(Wq, Wkv, Wo, W1, W2,
                                                    Wqkvb, Wob, W1b, W2b,
                                                    x, ln1g, ln1b, hb);

    // 2+3. qkv GEMM with fused RoPE -> qb/kbb/vbt (bf16), XCD-swizzled 1D grid (768 blocks)
    gemm_qkv_rope<<<(QKVW/128)*(R_/128), 256, 0, stream>>>(hb, Wqkvb, cosb, sinb, qb, kbb, vbt);
    // 4. attention -> ob (bf16), 8-wave blocks, QBLK=128
    attn_mfma<<<dim3(T_/128, B_*QH), 512, 0, stream>>>(qb, kbb, vbt, ob);
    // 5. x2b = x + ob @ Wob^T (bf16 out, 512 blocks)
    gemm_mfma<1><<<(D_/128)*(R_/128), 256, 0, stream>>>(ob, Wob, nullptr, x, nullptr, nullptr, x2b, R_, D_, D_);
    // 6. LN2 (bf16 in) -> hb (bf16)
    ln_bf16_in<<<R_, 256, 0, stream>>>(x2b, ln2g, ln2b, hb);
    // 7. gbuf = gelu(hb @ W1b^T + b1) (bf16 out, 1024 blocks)
    gemm_mfma<2><<<(DFF/128)*(R_/128), 256, 0, stream>>>(hb, W1b, b1, nullptr, nullptr, nullptr, gbuf, R_, DFF, D_);
    // 8. out = x2b + gbuf @ W2b^T + b2 (f32 out, 512 blocks)
    gemm_mfma<3><<<(D_/128)*(R_/128), 256, 0, stream>>>(gbuf, W2b, b2, nullptr, x2b, out, nullptr, R_, D_, DFF);
}

// Round 25
// 283.154 us; speedup vs baseline: 1.4539x; 1.0012x over previous
//
#include <hip/hip_runtime.h>
#include <hip/hip_bf16.h>
#include <math.h>
#include <stdint.h>

#define B_   4
#define T_   2048
#define D_   1024
#define QH   16
#define KVH  4
#define HD_  64
#define R_   (B_*T_)      // 8192 rows
#define DFF  2048
#define QKVW 1536         // fused q(1024) + kv(512) output width

typedef short short8 __attribute__((ext_vector_type(8)));
typedef short short4v __attribute__((ext_vector_type(4)));
typedef float f32x4 __attribute__((ext_vector_type(4)));

// native exp2 (bare v_exp_f32); guarded fallback is mathematically identical
#if __has_builtin(__builtin_amdgcn_exp2f)
#define EXP2(x) __builtin_amdgcn_exp2f(x)
#else
#define EXP2(x) __expf((x) * 0.6931471805599453f)
#endif

static __device__ __forceinline__ unsigned short f2bu(float x) {
    __hip_bfloat16 h = __float2bfloat16(x);
    return *reinterpret_cast<unsigned short*>(&h);
}
static __device__ __forceinline__ float bu2f(unsigned short u) {
    unsigned int w = ((unsigned int)u) << 16;
    return *reinterpret_cast<float*>(&w);
}

// swizzled byte offset within a 128B/row LDS tile (8-row XOR stripe)
#define KSWZ(row, cbyte) (((row) << 7) + ((cbyte) ^ (((row) & 7) << 4)))

__device__ __forceinline__ void gload_lds16(const void* g, void* l) {
    typedef __attribute__((address_space(1))) void gv_t;
    typedef __attribute__((address_space(3))) void lv_t;
    __builtin_amdgcn_global_load_lds((gv_t*)g, (lv_t*)l, 16, 0, 0);
}

// XCD-aware linear block swizzle (requires nwg % 8 == 0)
__device__ __forceinline__ int xcd_swz(int bid, int nwg) {
    int cpx = nwg >> 3;
    return (bid & 7) * cpx + (bid >> 3);
}

// fast GELU (tanh form) in exp2 domain
__device__ __forceinline__ float gelu_fast(float x) {
    float g2 = 2.3024523389544817f * (x + 0.044715f * x * x * x);
    return x / (1.0f + EXP2(-g2));
}

// ---------------- prologue: weight casts (blocks [0,6656)) + LN1 (blocks [6656,14848)) --------
__global__ __launch_bounds__(256) void prologue_cast_ln(const float* __restrict__ Wq,
                                                        const float* __restrict__ Wkv,
                                                        const float* __restrict__ Wo,
                                                        const float* __restrict__ W1,
                                                        const float* __restrict__ W2,
                                                        __hip_bfloat16* __restrict__ dqkv,
                                                        __hip_bfloat16* __restrict__ dWo,
                                                        __hip_bfloat16* __restrict__ dW1,
                                                        __hip_bfloat16* __restrict__ dW2,
                                                        const float* __restrict__ x,
                                                        const float* __restrict__ g,
                                                        const float* __restrict__ bta,
                                                        __hip_bfloat16* __restrict__ hb) {
    int tid = threadIdx.x;
    if (blockIdx.x < 6656) {
        int i = blockIdx.x * 256 + tid;   // quad index, total exactly 6656*256 = 1703936
        const float* src; __hip_bfloat16* dst; int off;
        if (i < 262144)       { src = Wq;  dst = dqkv;            off = i; }
        else if (i < 393216)  { src = Wkv; dst = dqkv + 1048576;  off = i - 262144; }
        else if (i < 655360)  { src = Wo;  dst = dWo;             off = i - 393216; }
        else if (i < 1179648) { src = W1;  dst = dW1;             off = i - 655360; }
        else                  { src = W2;  dst = dW2;             off = i - 1179648; }
        float4 v = *(const float4*)&src[(size_t)off*4];
        ushort4 o = { f2bu(v.x), f2bu(v.y), f2bu(v.z), f2bu(v.w) };
        *(ushort4*)&dst[(size_t)off*4] = o;
        return;
    }
    int row = blockIdx.x - 6656;
    const float* xr = x + (size_t)row * D_;
    int c = tid * 4;
    float4 v = *(const float4*)&xr[c];
    float s = v.x + v.y + v.z + v.w;
#pragma unroll
    for (int off = 32; off >= 1; off >>= 1) s += __shfl_xor(s, off);
    __shared__ float sm[4], sv[4];
    int wid = tid >> 6, lane = tid & 63;
    if (lane == 0) sm[wid] = s;
    __syncthreads();
    float mean = (sm[0] + sm[1] + sm[2] + sm[3]) * (1.0f / D_);
    float d0 = v.x - mean, d1 = v.y - mean, d2 = v.z - mean, d3 = v.w - mean;
    float qq = d0*d0 + d1*d1 + d2*d2 + d3*d3;
#pragma unroll
    for (int off = 32; off >= 1; off >>= 1) qq += __shfl_xor(qq, off);
    if (lane == 0) sv[wid] = qq;
    __syncthreads();
    float var = (sv[0] + sv[1] + sv[2] + sv[3]) * (1.0f / D_);
    float rstd = rsqrtf(var + 1e-5f);
    float4 gg = *(const float4*)&g[c];
    float4 bb = *(const float4*)&bta[c];
    ushort4 o = { f2bu(d0 * rstd * gg.x + bb.x),
                  f2bu(d1 * rstd * gg.y + bb.y),
                  f2bu(d2 * rstd * gg.z + bb.z),
                  f2bu(d3 * rstd * gg.w + bb.w) };
    *(ushort4*)&(hb + (size_t)row * D_)[c] = o;
}

// ---------------- LayerNorm with bf16 input -> bf16 out: one block per row ----------------
__global__ __launch_bounds__(256) void ln_bf16_in(const __hip_bfloat16* __restrict__ x,
                                                  const float* __restrict__ g,
                                                  const float* __restrict__ bta,
                                                  __hip_bfloat16* __restrict__ out) {
    int row = blockIdx.x;
    int tid = threadIdx.x;
    const __hip_bfloat16* xr = x + (size_t)row * D_;
    int c = tid * 4;
    ushort4 u = *(const ushort4*)&xr[c];
    float v0 = bu2f(u.x), v1 = bu2f(u.y), v2 = bu2f(u.z), v3 = bu2f(u.w);
    float s = v0 + v1 + v2 + v3;
#pragma unroll
    for (int off = 32; off >= 1; off >>= 1) s += __shfl_xor(s, off);
    __shared__ float sm[4], sv[4];
    int wid = tid >> 6, lane = tid & 63;
    if (lane == 0) sm[wid] = s;
    __syncthreads();
    float mean = (sm[0] + sm[1] + sm[2] + sm[3]) * (1.0f / D_);
    float d0 = v0 - mean, d1 = v1 - mean, d2 = v2 - mean, d3 = v3 - mean;
    float qq = d0*d0 + d1*d1 + d2*d2 + d3*d3;
#pragma unroll
    for (int off = 32; off >= 1; off >>= 1) qq += __shfl_xor(qq, off);
    if (lane == 0) sv[wid] = qq;
    __syncthreads();
    float var = (sv[0] + sv[1] + sv[2] + sv[3]) * (1.0f / D_);
    float rstd = rsqrtf(var + 1e-5f);
    float4 gg = *(const float4*)&g[c];
    float4 bb = *(const float4*)&bta[c];
    ushort4 o = { f2bu(d0 * rstd * gg.x + bb.x),
                  f2bu(d1 * rstd * gg.y + bb.y),
                  f2bu(d2 * rstd * gg.z + bb.z),
                  f2bu(d3 * rstd * gg.w + bb.w) };
    *(ushort4*)&(out + (size_t)row * D_)[c] = o;
}

// ---------------- bf16 MFMA GEMM, BK=64, swizzled LDS ----------------
// MODE 1: += res(f32), out bf16 Cb; MODE 2: += bias, gelu, out bf16 Cb;
// MODE 3: += bias, += resb(bf16), out f32 Cf
template<int MODE>
__global__ __launch_bounds__(256) void gemm_mfma(const __hip_bfloat16* __restrict__ A,
                                                 const __hip_bfloat16* __restrict__ W,
                                                 const float* __restrict__ bias,
                                                 const float* __restrict__ res,
                                                 const __hip_bfloat16* __restrict__ resb,
                                                 float* __restrict__ Cf,
                                                 __hip_bfloat16* __restrict__ Cb,
                                                 int M, int N, int K) {
    __shared__ __hip_bfloat16 At[128*64];
    __shared__ __hip_bfloat16 Bt[128*64];
    int tid = threadIdx.x;
    int w = tid >> 6, lane = tid & 63;
    int l15 = lane & 15, lhi = lane >> 4;
    int swz = xcd_swz(blockIdx.x, gridDim.x);
    int gx = N >> 7;
    int bn = (swz % gx) * 128, bm = (swz / gx) * 128;
    int wr = w >> 1, wc = w & 1;
    f32x4 acc[4][4] = {};

    for (int k0 = 0; k0 < K; k0 += 64) {
#pragma unroll
        for (int iss = 0; iss < 4; ++iss) {
            int idx = iss*256 + tid;               // 0..1023
            int row = idx >> 3;                    // 0..127
            int cb  = (idx & 7) * 16;              // byte col within 128B row
            int sce = (cb ^ ((row & 7) << 4)) >> 1;  // pre-swizzled source col (elements)
            int ldso = idx * 16;                   // linear LDS byte offset
            gload_lds16(A + (size_t)(bm + row) * K + k0 + sce, (char*)At + ldso);
            gload_lds16(W + (size_t)(bn + row) * K + k0 + sce, (char*)Bt + ldso);
        }
        __syncthreads();
#pragma unroll
        for (int kk = 0; kk < 2; ++kk) {
            short8 af[4], bf[4];
#pragma unroll
            for (int m = 0; m < 4; ++m)
                af[m] = *(const short8*)((char*)At + KSWZ(wr*64 + m*16 + l15, kk*64 + lhi*16));
#pragma unroll
            for (int n = 0; n < 4; ++n)
                bf[n] = *(const short8*)((char*)Bt + KSWZ(wc*64 + n*16 + l15, kk*64 + lhi*16));
#pragma unroll
            for (int m = 0; m < 4; ++m)
#pragma unroll
                for (int n = 0; n < 4; ++n)
                    acc[m][n] = __builtin_amdgcn_mfma_f32_16x16x32_bf16(af[m], bf[n], acc[m][n], 0, 0, 0);
        }
        __syncthreads();
    }

#pragma unroll
    for (int m = 0; m < 4; ++m) {
#pragma unroll
        for (int j = 0; j < 4; ++j) {
            int row = bm + wr*64 + m*16 + lhi*4 + j;
#pragma unroll
            for (int n = 0; n < 4; ++n) {
                int col = bn + wc*64 + n*16 + l15;
                float val = acc[m][n][j];
                if (MODE == 2 || MODE == 3) val += bias[col];
                if (MODE == 2) val = gelu_fast(val);
                if (MODE == 1) val += res[(size_t)row * N + col];
                if (MODE == 3) val += bu2f(*(const unsigned short*)&resb[(size_t)row * N + col]);
                if (MODE == 3) Cf[(size_t)row * N + col] = val;
                else           Cb[(size_t)row * N + col] = __float2bfloat16(val);
            }
        }
    }
}

// ---------------- QKV GEMM with fused RoPE epilogue (BK=64, swizzled, XCD swizzle) -------------
// q is pre-scaled by (1/8)*log2e so attention scores land in the exp2 domain.
__global__ __launch_bounds__(256) void gemm_qkv_rope(const __hip_bfloat16* __restrict__ A,
                                                     const __hip_bfloat16* __restrict__ W,
                                                     const float* __restrict__ cosb,
                                                     const float* __restrict__ sinb,
                                                     __hip_bfloat16* __restrict__ qb,
                                                     __hip_bfloat16* __restrict__ kbb,
                                                     __hip_bfloat16* __restrict__ vbt) {
    const int K = D_;
    const float QS = 0.125f * 1.4426950408889634f;
    __shared__ __hip_bfloat16 At[128*64];
    __shared__ __hip_bfloat16 Bt[128*64];
    int tid = threadIdx.x;
    int w = tid >> 6, lane = tid & 63;
    int l15 = lane & 15, lhi = lane >> 4;
    int swz = xcd_swz(blockIdx.x, gridDim.x);
    const int gx = QKVW >> 7;   // 12
    int bn = (swz % gx) * 128, bm = (swz / gx) * 128;
    int wr = w >> 1, wc = w & 1;
    f32x4 acc[4][4] = {};

    for (int k0 = 0; k0 < K; k0 += 64) {
#pragma unroll
        for (int iss = 0; iss < 4; ++iss) {
            int idx = iss*256 + tid;
            int row = idx >> 3;
            int cb  = (idx & 7) * 16;
            int sce = (cb ^ ((row & 7) << 4)) >> 1;
            int ldso = idx * 16;
            gload_lds16(A + (size_t)(bm + row) * K + k0 + sce, (char*)At + ldso);
            gload_lds16(W + (size_t)(bn + row) * K + k0 + sce, (char*)Bt + ldso);
        }
        __syncthreads();
#pragma unroll
        for (int kk = 0; kk < 2; ++kk) {
            short8 af[4], bf[4];
#pragma unroll
            for (int m = 0; m < 4; ++m)
                af[m] = *(const short8*)((char*)At + KSWZ(wr*64 + m*16 + l15, kk*64 + lhi*16));
#pragma unroll
            for (int n = 0; n < 4; ++n)
                bf[n] = *(const short8*)((char*)Bt + KSWZ(wc*64 + n*16 + l15, kk*64 + lhi*16));
#pragma unroll
            for (int m = 0; m < 4; ++m)
#pragma unroll
                for (int n = 0; n < 4; ++n)
                    acc[m][n] = __builtin_amdgcn_mfma_f32_16x16x32_bf16(af[m], bf[n], acc[m][n], 0, 0, 0);
        }
        __syncthreads();
    }

    bool is_q = (bn < 1024);
    bool is_v = (!is_q) && (wc == 1);   // wave-uniform
    if (!is_v) {
#pragma unroll
        for (int m = 0; m < 4; ++m) {
#pragma unroll
            for (int j = 0; j < 4; ++j) {
                int row = bm + wr*64 + m*16 + lhi*4 + j;
                int b = row >> 11, t = row & (T_ - 1);
                const float* crow = cosb + t*HD_;
                const float* srow = sinb + t*HD_;
#pragma unroll
                for (int n = 0; n < 4; ++n) {
                    int col = bn + wc*64 + n*16 + l15;
                    int hd = n*16 + l15;
                    float val = acc[m][n][j];
                    float part = __shfl_xor(val, 1);
                    float rot = (l15 & 1) ? part : -part;
                    float o = val * crow[hd] + rot * srow[hd];
                    if (is_q) {
                        int h = col >> 6;
                        qb[(((size_t)(b*QH + h))*T_ + t)*HD_ + hd] = __float2bfloat16(o * QS);
                    } else {
                        int kvh = (col - 1024) >> 7;
                        kbb[(((size_t)(b*KVH + kvh))*T_ + t)*HD_ + hd] = __float2bfloat16(o);
                    }
                }
            }
        }
    } else {
#pragma unroll
        for (int m = 0; m < 4; ++m) {
            int row0 = bm + wr*64 + m*16 + lhi*4;
            int b = row0 >> 11, t0 = row0 & (T_ - 1);
#pragma unroll
            for (int n = 0; n < 4; ++n) {
                int col = bn + 64 + n*16 + l15;
                int kvh = (col - 1024) >> 7;
                int hd = n*16 + l15;
                short4v pk = { (short)f2bu(acc[m][n][0]), (short)f2bu(acc[m][n][1]),
                               (short)f2bu(acc[m][n][2]), (short)f2bu(acc[m][n][3]) };
                *(short4v*)&vbt[(((size_t)(b*KVH + kvh))*HD_ + hd)*T_ + t0] = pk;
            }
        }
    }
}

// ---------------- Flash attention: 8 waves x 16 q-rows, SINGLE K/V buffer (32KB LDS) ----------
// Per-wave work identical to R24. K/V prefetched into REGISTERS (1 K + 1 V short8/thread),
// ds_written into the same buffer after PV (write-after-read protected by barrier; next
// tile's reads protected by second barrier). LDS 32KB -> up to 4 blocks/CU = 32 waves (cap).
__global__ __launch_bounds__(512) void attn_mfma(const __hip_bfloat16* __restrict__ qb,
                                                 const __hip_bfloat16* __restrict__ kb,
                                                 const __hip_bfloat16* __restrict__ vbt,
                                                 __hip_bfloat16* __restrict__ ob) {
    __shared__ __hip_bfloat16 Ks[64*64];      // [key][d]   swizzled, 8KB
    __shared__ __hip_bfloat16 Vs[64*64];      // [d][key]   swizzled, 8KB
    __shared__ __hip_bfloat16 Ps[128*64];     // [qrow][key] swizzled, per-wave rows, 16KB
    char* PsB = (char*)Ps;
    char* KsB = (char*)Ks;
    char* VsB = (char*)Vs;
    int tid = threadIdx.x;
    int w = tid >> 6, lane = tid & 63;        // w in 0..7
    int l15 = lane & 15, lhi = lane >> 4;
    int bh = blockIdx.y;
    int b = bh >> 4, h = bh & 15;
    int bk = b * KVH + (h >> 2);
    int qt0 = blockIdx.x * 128;

    const __hip_bfloat16* qrow = qb + ((size_t)bh * T_ + qt0 + w*16 + l15) * HD_;
    short8 qf0 = *(const short8*)(qrow + lhi*8);
    short8 qf1 = *(const short8*)(qrow + 32 + lhi*8);

    f32x4 oacc[4] = {};          // O^T[d=cb*16+lhi*4+r][qrow=l15]
    f32x4 lacc = {};             // l for qrow=l15 (all regs identical)
    float m_run = -INFINITY;     // running max in log2 units
    const short ONE_BF = (short)0x3F80;   // bf16 1.0
    const short8 onesf = { ONE_BF, ONE_BF, ONE_BF, ONE_BF, ONE_BF, ONE_BF, ONE_BF, ONE_BF };

    int sr  = tid >> 3;                // staging row 0..63 (512 thr, 8 chunks/row)
    int scB = (tid & 7) * 16;          // staging col byte {0,16,..,112}
    int sce = (tid & 7) * 8;           // linear source col (elements)
    const __hip_bfloat16* kbase = kb  + (size_t)bk * T_ * HD_;
    const __hip_bfloat16* vbase = vbt + (size_t)bk * HD_ * T_;

    // prologue: stage tile 0
    {
        short8 ra = *(const short8*)(kbase + (size_t)sr*HD_ + sce);
        short8 rc = *(const short8*)(vbase + (size_t)sr*T_ + sce);
        *(short8*)(KsB + KSWZ(sr, scB)) = ra;
        *(short8*)(VsB + KSWZ(sr, scB)) = rc;
    }
    __syncthreads();
    const int NT = T_ / 64;

    for (int it = 0; it < NT; ++it) {
        short8 ra, rc;
        bool pfv = (it + 1 < NT);
        if (pfv) {
            int s0n = (it + 1) * 64;
            ra = *(const short8*)(kbase + (size_t)(s0n + sr)*HD_ + sce);
            rc = *(const short8*)(vbase + (size_t)sr*T_ + s0n + sce);
        }

        // S^T = K Q^T (scores in log2 units)
        f32x4 accs[4];
#pragma unroll
        for (int cb = 0; cb < 4; ++cb) {
            f32x4 z = {0.f, 0.f, 0.f, 0.f};
            short8 k0 = *(const short8*)(KsB + KSWZ(cb*16 + l15, lhi*16));
            short8 k1 = *(const short8*)(KsB + KSWZ(cb*16 + l15, 64 + lhi*16));
            __builtin_amdgcn_s_setprio(1);
            z = __builtin_amdgcn_mfma_f32_16x16x32_bf16(k0, qf0, z, 0, 0, 0);
            z = __builtin_amdgcn_mfma_f32_16x16x32_bf16(k1, qf1, z, 0, 0, 0);
            __builtin_amdgcn_s_setprio(0);
            accs[cb] = z;
        }

        // per-lane local max (no cross-lane reduce in common path)
        float mxl = -INFINITY;
#pragma unroll
        for (int cb = 0; cb < 4; ++cb)
#pragma unroll
            for (int r = 0; r < 4; ++r) mxl = fmaxf(mxl, accs[cb][r]);

        // defer-max (THR=8 in log2 units: P bounded by 2^8)
        if (!__all(mxl <= m_run + 8.0f)) {
            float mx = mxl;
            mx = fmaxf(mx, __shfl_xor(mx, 16));
            mx = fmaxf(mx, __shfl_xor(mx, 32));
            float mn = fmaxf(m_run, mx);
            float cr = EXP2(m_run - mn);
            m_run = mn;
#pragma unroll
            for (int r = 0; r < 4; ++r) lacc[r] *= cr;
#pragma unroll
            for (int cb = 0; cb < 4; ++cb)
#pragma unroll
                for (int r = 0; r < 4; ++r) oacc[cb][r] *= cr;
        }

        int pr = w*16 + l15;               // per-wave P row (0..127)
#pragma unroll
        for (int cb = 0; cb < 4; ++cb) {
            f32x4 p;
#pragma unroll
            for (int r = 0; r < 4; ++r) p[r] = EXP2(accs[cb][r] - m_run);
            short4v pk = { (short)f2bu(p[0]), (short)f2bu(p[1]),
                           (short)f2bu(p[2]), (short)f2bu(p[3]) };
            *(short4v*)(PsB + KSWZ(pr, cb*32 + lhi*8)) = pk;
        }

        // O^T += V^T P^T ; lacc += ones * P^T
#pragma unroll
        for (int kk = 0; kk < 2; ++kk) {
            short8 pf = *(const short8*)(PsB + KSWZ(w*16 + l15, kk*64 + lhi*16));
            __builtin_amdgcn_s_setprio(1);
            lacc = __builtin_amdgcn_mfma_f32_16x16x32_bf16(onesf, pf, lacc, 0, 0, 0);
#pragma unroll
            for (int cb = 0; cb < 4; ++cb) {
                short8 vf = *(const short8*)(VsB + KSWZ(cb*16 + l15, kk*64 + lhi*16));
                oacc[cb] = __builtin_amdgcn_mfma_f32_16x16x32_bf16(vf, pf, oacc[cb], 0, 0, 0);
            }
            __builtin_amdgcn_s_setprio(0);
        }

        __syncthreads();   // all waves done READING Ks/Vs for this tile
        if (pfv) {
            *(short8*)(KsB + KSWZ(sr, scB)) = ra;   // overwrite same buffer
            *(short8*)(VsB + KSWZ(sr, scB)) = rc;
        }
        __syncthreads();   // writes visible before next tile's reads
    }

    float inv = 1.0f / lacc[0];
    int t = qt0 + w*16 + l15;
    __hip_bfloat16* orow = ob + (size_t)(b*T_ + t) * D_ + h*HD_;
#pragma unroll
    for (int cb = 0; cb < 4; ++cb) {
        short4v okv = { (short)f2bu(oacc[cb][0] * inv), (short)f2bu(oacc[cb][1] * inv),
                        (short)f2bu(oacc[cb][2] * inv), (short)f2bu(oacc[cb][3] * inv) };
        *(short4v*)&orow[cb*16 + lhi*4] = okv;
    }
}

extern "C" void kernel_launch(void* const* d_in, const int* in_sizes, int n_in,
                              void* d_out, int out_size, void* d_ws, size_t ws_size,
                              hipStream_t stream) {
    const float* x    = (const float*)d_in[0];
    const float* cosb = (const float*)d_in[1];
    const float* sinb = (const float*)d_in[2];
    const float* Wq   = (const float*)d_in[3];
    const float* Wkv  = (const float*)d_in[4];
    const float* Wo   = (const float*)d_in[5];
    const float* ln1g = (const float*)d_in[6];
    const float* ln1b = (const float*)d_in[7];
    const float* ln2g = (const float*)d_in[8];
    const float* ln2b = (const float*)d_in[9];
    const float* W1   = (const float*)d_in[10];
    const float* b1   = (const float*)d_in[11];
    const float* W2   = (const float*)d_in[12];
    const float* b2   = (const float*)d_in[13];
    float* out = (float*)d_out;

    float* ws = (float*)d_ws;
    const size_t M = 1024 * 1024;
    __hip_bfloat16* hb   = (__hip_bfloat16*)(ws);
    __hip_bfloat16* x2b  = (__hip_bfloat16*)(ws + 4*M);    // bf16 residual x2
    __hip_bfloat16* gbuf = (__hip_bfloat16*)(ws + 12*M);
    __hip_bfloat16* ob   = (__hip_bfloat16*)(ws + 20*M);
    __hip_bfloat16* qb   = (__hip_bfloat16*)(ws + 24*M);
    __hip_bfloat16* kbb  = (__hip_bfloat16*)(ws + 28*M);
    __hip_bfloat16* vbt  = (__hip_bfloat16*)(ws + 29*M);
    __hip_bfloat16* Wqkvb= (__hip_bfloat16*)(ws + 30*M);
    __hip_bfloat16* Wob  = (__hip_bfloat16*)(ws + 30*M + 3*M/4);
    __hip_bfloat16* W1b  = (__hip_bfloat16*)(ws + 31*M + M/4);
    __hip_bfloat16* W2b  = (__hip_bfloat16*)(ws + 32*M + M/4);

    // 0+1. weight casts + LN1 fused
    prologue_cast_ln<<<6656 + R_, 256, 0, stream>>>(Wq, Wkv, Wo, W1, W2,
                                                    Wqkvb, Wob, W1b, W2b,
                                                    x, ln1g, ln1b, hb);

    // 2+3. qkv GEMM with fused RoPE -> qb/kbb/vbt (bf16), XCD-swizzled 1D grid (768 blocks)
    gemm_qkv_rope<<<(QKVW/128)*(R_/128), 256, 0, stream>>>(hb, Wqkvb, cosb, sinb, qb, kbb, vbt);
    // 4. attention -> ob (bf16), 8-wave blocks, QBLK=128, 32KB LDS
    attn_mfma<<<dim3(T_/128, B_*QH), 512, 0, stream>>>(qb, kbb, vbt, ob);
    // 5. x2b = x + ob @ Wob^T (bf16 out, 512 blocks)
    gemm_mfma<1><<<(D_/128)*(R_/128), 256, 0, stream>>>(ob, Wob, nullptr, x, nullptr, nullptr, x2b, R_, D_, D_);
    // 6. LN2 (bf16 in) -> hb (bf16)
    ln_bf16_in<<<R_, 256, 0, stream>>>(x2b, ln2g, ln2b, hb);
    // 7. gbuf = gelu(hb @ W1b^T + b1) (bf16 out, 1024 blocks)
    gemm_mfma<2><<<(DFF/128)*(R_/128), 256, 0, stream>>>(hb, W1b, b1, nullptr, nullptr, nullptr, gbuf, R_, DFF, D_);
    // 8. out = x2b + gbuf @ W2b^T + b2 (f32 out, 512 blocks)
    gemm_mfma<3><<<(D_/128)*(R_/128), 256, 0, stream>>>(gbuf, W2b, b2, nullptr, x2b, out, nullptr, R_, D_, DFF);
}

// Round 26
// 276.373 us; speedup vs baseline: 1.4896x; 1.0245x over previous
//
#include <hip/hip_runtime.h>
#include <hip/hip_bf16.h>
#include <math.h>
#include <stdint.h>

#define B_   4
#define T_   2048
#define D_   1024
#define QH   16
#define KVH  4
#define HD_  64
#define R_   (B_*T_)      // 8192 rows
#define DFF  2048
#define QKVW 1536         // fused q(1024) + kv(512) output width

typedef short short8 __attribute__((ext_vector_type(8)));
typedef short short4v __attribute__((ext_vector_type(4)));
typedef float f32x4 __attribute__((ext_vector_type(4)));

// native exp2 (bare v_exp_f32); guarded fallback is mathematically identical
#if __has_builtin(__builtin_amdgcn_exp2f)
#define EXP2(x) __builtin_amdgcn_exp2f(x)
#else
#define EXP2(x) __expf((x) * 0.6931471805599453f)
#endif

static __device__ __forceinline__ unsigned short f2bu(float x) {
    __hip_bfloat16 h = __float2bfloat16(x);
    return *reinterpret_cast<unsigned short*>(&h);
}
static __device__ __forceinline__ float bu2f(unsigned short u) {
    unsigned int w = ((unsigned int)u) << 16;
    return *reinterpret_cast<float*>(&w);
}

// swizzled byte offset within a 128B/row LDS tile (8-row XOR stripe)
#define KSWZ(row, cbyte) (((row) << 7) + ((cbyte) ^ (((row) & 7) << 4)))

__device__ __forceinline__ void gload_lds16(const void* g, void* l) {
    typedef __attribute__((address_space(1))) void gv_t;
    typedef __attribute__((address_space(3))) void lv_t;
    __builtin_amdgcn_global_load_lds((gv_t*)g, (lv_t*)l, 16, 0, 0);
}

// XCD-aware linear block swizzle (requires nwg % 8 == 0)
__device__ __forceinline__ int xcd_swz(int bid, int nwg) {
    int cpx = nwg >> 3;
    return (bid & 7) * cpx + (bid >> 3);
}

// fast GELU (tanh form) in exp2 domain
__device__ __forceinline__ float gelu_fast(float x) {
    float g2 = 2.3024523389544817f * (x + 0.044715f * x * x * x);
    return x / (1.0f + EXP2(-g2));
}

// ---------------- prologue: weight casts (blocks [0,6656)) + LN1 (blocks [6656,14848)) --------
__global__ __launch_bounds__(256) void prologue_cast_ln(const float* __restrict__ Wq,
                                                        const float* __restrict__ Wkv,
                                                        const float* __restrict__ Wo,
                                                        const float* __restrict__ W1,
                                                        const float* __restrict__ W2,
                                                        __hip_bfloat16* __restrict__ dqkv,
                                                        __hip_bfloat16* __restrict__ dWo,
                                                        __hip_bfloat16* __restrict__ dW1,
                                                        __hip_bfloat16* __restrict__ dW2,
                                                        const float* __restrict__ x,
                                                        const float* __restrict__ g,
                                                        const float* __restrict__ bta,
                                                        __hip_bfloat16* __restrict__ hb) {
    int tid = threadIdx.x;
    if (blockIdx.x < 6656) {
        int i = blockIdx.x * 256 + tid;   // quad index, total exactly 6656*256 = 1703936
        const float* src; __hip_bfloat16* dst; int off;
        if (i < 262144)       { src = Wq;  dst = dqkv;            off = i; }
        else if (i < 393216)  { src = Wkv; dst = dqkv + 1048576;  off = i - 262144; }
        else if (i < 655360)  { src = Wo;  dst = dWo;             off = i - 393216; }
        else if (i < 1179648) { src = W1;  dst = dW1;             off = i - 655360; }
        else                  { src = W2;  dst = dW2;             off = i - 1179648; }
        float4 v = *(const float4*)&src[(size_t)off*4];
        ushort4 o = { f2bu(v.x), f2bu(v.y), f2bu(v.z), f2bu(v.w) };
        *(ushort4*)&dst[(size_t)off*4] = o;
        return;
    }
    int row = blockIdx.x - 6656;
    const float* xr = x + (size_t)row * D_;
    int c = tid * 4;
    float4 v = *(const float4*)&xr[c];
    float s = v.x + v.y + v.z + v.w;
#pragma unroll
    for (int off = 32; off >= 1; off >>= 1) s += __shfl_xor(s, off);
    __shared__ float sm[4], sv[4];
    int wid = tid >> 6, lane = tid & 63;
    if (lane == 0) sm[wid] = s;
    __syncthreads();
    float mean = (sm[0] + sm[1] + sm[2] + sm[3]) * (1.0f / D_);
    float d0 = v.x - mean, d1 = v.y - mean, d2 = v.z - mean, d3 = v.w - mean;
    float qq = d0*d0 + d1*d1 + d2*d2 + d3*d3;
#pragma unroll
    for (int off = 32; off >= 1; off >>= 1) qq += __shfl_xor(qq, off);
    if (lane == 0) sv[wid] = qq;
    __syncthreads();
    float var = (sv[0] + sv[1] + sv[2] + sv[3]) * (1.0f / D_);
    float rstd = rsqrtf(var + 1e-5f);
    float4 gg = *(const float4*)&g[c];
    float4 bb = *(const float4*)&bta[c];
    ushort4 o = { f2bu(d0 * rstd * gg.x + bb.x),
                  f2bu(d1 * rstd * gg.y + bb.y),
                  f2bu(d2 * rstd * gg.z + bb.z),
                  f2bu(d3 * rstd * gg.w + bb.w) };
    *(ushort4*)&(hb + (size_t)row * D_)[c] = o;
}

// ---------------- LayerNorm with bf16 input -> bf16 out: one block per row ----------------
__global__ __launch_bounds__(256) void ln_bf16_in(const __hip_bfloat16* __restrict__ x,
                                                  const float* __restrict__ g,
                                                  const float* __restrict__ bta,
                                                  __hip_bfloat16* __restrict__ out) {
    int row = blockIdx.x;
    int tid = threadIdx.x;
    const __hip_bfloat16* xr = x + (size_t)row * D_;
    int c = tid * 4;
    ushort4 u = *(const ushort4*)&xr[c];
    float v0 = bu2f(u.x), v1 = bu2f(u.y), v2 = bu2f(u.z), v3 = bu2f(u.w);
    float s = v0 + v1 + v2 + v3;
#pragma unroll
    for (int off = 32; off >= 1; off >>= 1) s += __shfl_xor(s, off);
    __shared__ float sm[4], sv[4];
    int wid = tid >> 6, lane = tid & 63;
    if (lane == 0) sm[wid] = s;
    __syncthreads();
    float mean = (sm[0] + sm[1] + sm[2] + sm[3]) * (1.0f / D_);
    float d0 = v0 - mean, d1 = v1 - mean, d2 = v2 - mean, d3 = v3 - mean;
    float qq = d0*d0 + d1*d1 + d2*d2 + d3*d3;
#pragma unroll
    for (int off = 32; off >= 1; off >>= 1) qq += __shfl_xor(qq, off);
    if (lane == 0) sv[wid] = qq;
    __syncthreads();
    float var = (sv[0] + sv[1] + sv[2] + sv[3]) * (1.0f / D_);
    float rstd = rsqrtf(var + 1e-5f);
    float4 gg = *(const float4*)&g[c];
    float4 bb = *(const float4*)&bta[c];
    ushort4 o = { f2bu(d0 * rstd * gg.x + bb.x),
                  f2bu(d1 * rstd * gg.y + bb.y),
                  f2bu(d2 * rstd * gg.z + bb.z),
                  f2bu(d3 * rstd * gg.w + bb.w) };
    *(ushort4*)&(out + (size_t)row * D_)[c] = o;
}

// ---------------- bf16 MFMA GEMM, BK=64, swizzled LDS, 8 waves (wave-tile 64x32) --------------
// MODE 1: += res(f32), out bf16 Cb; MODE 2: += bias, gelu, out bf16 Cb;
// MODE 3: += bias, += resb(bf16), out f32 Cf
template<int MODE>
__global__ __launch_bounds__(512) void gemm_mfma(const __hip_bfloat16* __restrict__ A,
                                                 const __hip_bfloat16* __restrict__ W,
                                                 const float* __restrict__ bias,
                                                 const float* __restrict__ res,
                                                 const __hip_bfloat16* __restrict__ resb,
                                                 float* __restrict__ Cf,
                                                 __hip_bfloat16* __restrict__ Cb,
                                                 int M, int N, int K) {
    __shared__ __hip_bfloat16 At[128*64];
    __shared__ __hip_bfloat16 Bt[128*64];
    int tid = threadIdx.x;
    int w = tid >> 6, lane = tid & 63;        // w in 0..7
    int l15 = lane & 15, lhi = lane >> 4;
    int swz = xcd_swz(blockIdx.x, gridDim.x);
    int gx = N >> 7;
    int bn = (swz % gx) * 128, bm = (swz / gx) * 128;
    int wr = w >> 2, wc = w & 3;              // wave tile 64(M) x 32(N)
    f32x4 acc[4][2] = {};

    for (int k0 = 0; k0 < K; k0 += 64) {
#pragma unroll
        for (int iss = 0; iss < 2; ++iss) {
            int idx = iss*512 + tid;               // 0..1023
            int row = idx >> 3;                    // 0..127
            int cb  = (idx & 7) * 16;              // byte col within 128B row
            int sce = (cb ^ ((row & 7) << 4)) >> 1;  // pre-swizzled source col (elements)
            int ldso = idx * 16;                   // linear LDS byte offset
            gload_lds16(A + (size_t)(bm + row) * K + k0 + sce, (char*)At + ldso);
            gload_lds16(W + (size_t)(bn + row) * K + k0 + sce, (char*)Bt + ldso);
        }
        __syncthreads();
#pragma unroll
        for (int kk = 0; kk < 2; ++kk) {
            short8 af[4], bf[2];
#pragma unroll
            for (int m = 0; m < 4; ++m)
                af[m] = *(const short8*)((char*)At + KSWZ(wr*64 + m*16 + l15, kk*64 + lhi*16));
#pragma unroll
            for (int n = 0; n < 2; ++n)
                bf[n] = *(const short8*)((char*)Bt + KSWZ(wc*32 + n*16 + l15, kk*64 + lhi*16));
#pragma unroll
            for (int m = 0; m < 4; ++m)
#pragma unroll
                for (int n = 0; n < 2; ++n)
                    acc[m][n] = __builtin_amdgcn_mfma_f32_16x16x32_bf16(af[m], bf[n], acc[m][n], 0, 0, 0);
        }
        __syncthreads();
    }

#pragma unroll
    for (int m = 0; m < 4; ++m) {
#pragma unroll
        for (int j = 0; j < 4; ++j) {
            int row = bm + wr*64 + m*16 + lhi*4 + j;
#pragma unroll
            for (int n = 0; n < 2; ++n) {
                int col = bn + wc*32 + n*16 + l15;
                float val = acc[m][n][j];
                if (MODE == 2 || MODE == 3) val += bias[col];
                if (MODE == 2) val = gelu_fast(val);
                if (MODE == 1) val += res[(size_t)row * N + col];
                if (MODE == 3) val += bu2f(*(const unsigned short*)&resb[(size_t)row * N + col]);
                if (MODE == 3) Cf[(size_t)row * N + col] = val;
                else           Cb[(size_t)row * N + col] = __float2bfloat16(val);
            }
        }
    }
}

// ---------------- QKV GEMM with fused RoPE epilogue (8 waves, wave-tile 64x32) ----------------
// q is pre-scaled by (1/8)*log2e so attention scores land in the exp2 domain.
__global__ __launch_bounds__(512) void gemm_qkv_rope(const __hip_bfloat16* __restrict__ A,
                                                     const __hip_bfloat16* __restrict__ W,
                                                     const float* __restrict__ cosb,
                                                     const float* __restrict__ sinb,
                                                     __hip_bfloat16* __restrict__ qb,
                                                     __hip_bfloat16* __restrict__ kbb,
                                                     __hip_bfloat16* __restrict__ vbt) {
    const int K = D_;
    const float QS = 0.125f * 1.4426950408889634f;
    __shared__ __hip_bfloat16 At[128*64];
    __shared__ __hip_bfloat16 Bt[128*64];
    int tid = threadIdx.x;
    int w = tid >> 6, lane = tid & 63;        // w in 0..7
    int l15 = lane & 15, lhi = lane >> 4;
    int swz = xcd_swz(blockIdx.x, gridDim.x);
    const int gx = QKVW >> 7;   // 12
    int bn = (swz % gx) * 128, bm = (swz / gx) * 128;
    int wr = w >> 2, wc = w & 3;              // wave tile 64(M) x 32(N)
    f32x4 acc[4][2] = {};

    for (int k0 = 0; k0 < K; k0 += 64) {
#pragma unroll
        for (int iss = 0; iss < 2; ++iss) {
            int idx = iss*512 + tid;
            int row = idx >> 3;
            int cb  = (idx & 7) * 16;
            int sce = (cb ^ ((row & 7) << 4)) >> 1;
            int ldso = idx * 16;
            gload_lds16(A + (size_t)(bm + row) * K + k0 + sce, (char*)At + ldso);
            gload_lds16(W + (size_t)(bn + row) * K + k0 + sce, (char*)Bt + ldso);
        }
        __syncthreads();
#pragma unroll
        for (int kk = 0; kk < 2; ++kk) {
            short8 af[4], bf[2];
#pragma unroll
            for (int m = 0; m < 4; ++m)
                af[m] = *(const short8*)((char*)At + KSWZ(wr*64 + m*16 + l15, kk*64 + lhi*16));
#pragma unroll
            for (int n = 0; n < 2; ++n)
                bf[n] = *(const short8*)((char*)Bt + KSWZ(wc*32 + n*16 + l15, kk*64 + lhi*16));
#pragma unroll
            for (int m = 0; m < 4; ++m)
#pragma unroll
                for (int n = 0; n < 2; ++n)
                    acc[m][n] = __builtin_amdgcn_mfma_f32_16x16x32_bf16(af[m], bf[n], acc[m][n], 0, 0, 0);
        }
        __syncthreads();
    }

    bool is_q = (bn < 1024);
    bool is_v = (!is_q) && (wc >= 2);   // wave-uniform (v = upper 64 cols of kv tile)
    if (!is_v) {
#pragma unroll
        for (int m = 0; m < 4; ++m) {
#pragma unroll
            for (int j = 0; j < 4; ++j) {
                int row = bm + wr*64 + m*16 + lhi*4 + j;
                int b = row >> 11, t = row & (T_ - 1);
                const float* crow = cosb + t*HD_;
                const float* srow = sinb + t*HD_;
#pragma unroll
                for (int n = 0; n < 2; ++n) {
                    int col = bn + wc*32 + n*16 + l15;
                    float val = acc[m][n][j];
                    float part = __shfl_xor(val, 1);
                    float rot = (l15 & 1) ? part : -part;
                    if (is_q) {
                        int hd = col & 63;
                        float o = val * crow[hd] + rot * srow[hd];
                        int h = col >> 6;
                        qb[(((size_t)(b*QH + h))*T_ + t)*HD_ + hd] = __float2bfloat16(o * QS);
                    } else {
                        int hd = (col - 1024) & 127;   // < 64 here
                        float o = val * crow[hd] + rot * srow[hd];
                        int kvh = (col - 1024) >> 7;
                        kbb[(((size_t)(b*KVH + kvh))*T_ + t)*HD_ + hd] = __float2bfloat16(o);
                    }
                }
            }
        }
    } else {
#pragma unroll
        for (int m = 0; m < 4; ++m) {
            int row0 = bm + wr*64 + m*16 + lhi*4;
            int b = row0 >> 11, t0 = row0 & (T_ - 1);
#pragma unroll
            for (int n = 0; n < 2; ++n) {
                int col = bn + wc*32 + n*16 + l15;
                int kvh = (col - 1024) >> 7;
                int hd = ((col - 1024) & 127) - 64;
                short4v pk = { (short)f2bu(acc[m][n][0]), (short)f2bu(acc[m][n][1]),
                               (short)f2bu(acc[m][n][2]), (short)f2bu(acc[m][n][3]) };
                *(short4v*)&vbt[(((size_t)(b*KVH + kvh))*HD_ + hd)*T_ + t0] = pk;
            }
        }
    }
}

// ---------------- Flash attention: R25 structure (unchanged, 95.6us) ----------------
__global__ __launch_bounds__(512) void attn_mfma(const __hip_bfloat16* __restrict__ qb,
                                                 const __hip_bfloat16* __restrict__ kb,
                                                 const __hip_bfloat16* __restrict__ vbt,
                                                 __hip_bfloat16* __restrict__ ob) {
    __shared__ __hip_bfloat16 Ks[64*64];      // [key][d]   swizzled, 8KB
    __shared__ __hip_bfloat16 Vs[64*64];      // [d][key]   swizzled, 8KB
    __shared__ __hip_bfloat16 Ps[128*64];     // [qrow][key] swizzled, per-wave rows, 16KB
    char* PsB = (char*)Ps;
    char* KsB = (char*)Ks;
    char* VsB = (char*)Vs;
    int tid = threadIdx.x;
    int w = tid >> 6, lane = tid & 63;        // w in 0..7
    int l15 = lane & 15, lhi = lane >> 4;
    int bh = blockIdx.y;
    int b = bh >> 4, h = bh & 15;
    int bk = b * KVH + (h >> 2);
    int qt0 = blockIdx.x * 128;

    const __hip_bfloat16* qrow = qb + ((size_t)bh * T_ + qt0 + w*16 + l15) * HD_;
    short8 qf0 = *(const short8*)(qrow + lhi*8);
    short8 qf1 = *(const short8*)(qrow + 32 + lhi*8);

    f32x4 oacc[4] = {};          // O^T[d=cb*16+lhi*4+r][qrow=l15]
    f32x4 lacc = {};             // l for qrow=l15 (all regs identical)
    float m_run = -INFINITY;     // running max in log2 units
    const short ONE_BF = (short)0x3F80;   // bf16 1.0
    const short8 onesf = { ONE_BF, ONE_BF, ONE_BF, ONE_BF, ONE_BF, ONE_BF, ONE_BF, ONE_BF };

    int sr  = tid >> 3;                // staging row 0..63 (512 thr, 8 chunks/row)
    int scB = (tid & 7) * 16;          // staging col byte {0,16,..,112}
    int sce = (tid & 7) * 8;           // linear source col (elements)
    const __hip_bfloat16* kbase = kb  + (size_t)bk * T_ * HD_;
    const __hip_bfloat16* vbase = vbt + (size_t)bk * HD_ * T_;

    // prologue: stage tile 0
    {
        short8 ra = *(const short8*)(kbase + (size_t)sr*HD_ + sce);
        short8 rc = *(const short8*)(vbase + (size_t)sr*T_ + sce);
        *(short8*)(KsB + KSWZ(sr, scB)) = ra;
        *(short8*)(VsB + KSWZ(sr, scB)) = rc;
    }
    __syncthreads();
    const int NT = T_ / 64;

    for (int it = 0; it < NT; ++it) {
        short8 ra, rc;
        bool pfv = (it + 1 < NT);
        if (pfv) {
            int s0n = (it + 1) * 64;
            ra = *(const short8*)(kbase + (size_t)(s0n + sr)*HD_ + sce);
            rc = *(const short8*)(vbase + (size_t)sr*T_ + s0n + sce);
        }

        // S^T = K Q^T (scores in log2 units)
        f32x4 accs[4];
#pragma unroll
        for (int cb = 0; cb < 4; ++cb) {
            f32x4 z = {0.f, 0.f, 0.f, 0.f};
            short8 k0 = *(const short8*)(KsB + KSWZ(cb*16 + l15, lhi*16));
            short8 k1 = *(const short8*)(KsB + KSWZ(cb*16 + l15, 64 + lhi*16));
            __builtin_amdgcn_s_setprio(1);
            z = __builtin_amdgcn_mfma_f32_16x16x32_bf16(k0, qf0, z, 0, 0, 0);
            z = __builtin_amdgcn_mfma_f32_16x16x32_bf16(k1, qf1, z, 0, 0, 0);
            __builtin_amdgcn_s_setprio(0);
            accs[cb] = z;
        }

        // per-lane local max (no cross-lane reduce in common path)
        float mxl = -INFINITY;
#pragma unroll
        for (int cb = 0; cb < 4; ++cb)
#pragma unroll
            for (int r = 0; r < 4; ++r) mxl = fmaxf(mxl, accs[cb][r]);

        // defer-max (THR=8 in log2 units: P bounded by 2^8)
        if (!__all(mxl <= m_run + 8.0f)) {
            float mx = mxl;
            mx = fmaxf(mx, __shfl_xor(mx, 16));
            mx = fmaxf(mx, __shfl_xor(mx, 32));
            float mn = fmaxf(m_run, mx);
            float cr = EXP2(m_run - mn);
            m_run = mn;
#pragma unroll
            for (int r = 0; r < 4; ++r) lacc[r] *= cr;
#pragma unroll
            for (int cb = 0; cb < 4; ++cb)
#pragma unroll
                for (int r = 0; r < 4; ++r) oacc[cb][r] *= cr;
        }

        int pr = w*16 + l15;               // per-wave P row (0..127)
#pragma unroll
        for (int cb = 0; cb < 4; ++cb) {
            f32x4 p;
#pragma unroll
            for (int r = 0; r < 4; ++r) p[r] = EXP2(accs[cb][r] - m_run);
            short4v pk = { (short)f2bu(p[0]), (short)f2bu(p[1]),
                           (short)f2bu(p[2]), (short)f2bu(p[3]) };
            *(short4v*)(PsB + KSWZ(pr, cb*32 + lhi*8)) = pk;
        }

        // O^T += V^T P^T ; lacc += ones * P^T
#pragma unroll
        for (int kk = 0; kk < 2; ++kk) {
            short8 pf = *(const short8*)(PsB + KSWZ(w*16 + l15, kk*64 + lhi*16));
            __builtin_amdgcn_s_setprio(1);
            lacc = __builtin_amdgcn_mfma_f32_16x16x32_bf16(onesf, pf, lacc, 0, 0, 0);
#pragma unroll
            for (int cb = 0; cb < 4; ++cb) {
                short8 vf = *(const short8*)(VsB + KSWZ(cb*16 + l15, kk*64 + lhi*16));
                oacc[cb] = __builtin_amdgcn_mfma_f32_16x16x32_bf16(vf, pf, oacc[cb], 0, 0, 0);
            }
            __builtin_amdgcn_s_setprio(0);
        }

        __syncthreads();   // all waves done READING Ks/Vs for this tile
        if (pfv) {
            *(short8*)(KsB + KSWZ(sr, scB)) = ra;   // overwrite same buffer
            *(short8*)(VsB + KSWZ(sr, scB)) = rc;
        }
        __syncthreads();   // writes visible before next tile's reads
    }

    float inv = 1.0f / lacc[0];
    int t = qt0 + w*16 + l15;
    __hip_bfloat16* orow = ob + (size_t)(b*T_ + t) * D_ + h*HD_;
#pragma unroll
    for (int cb = 0; cb < 4; ++cb) {
        short4v okv = { (short)f2bu(oacc[cb][0] * inv), (short)f2bu(oacc[cb][1] * inv),
                        (short)f2bu(oacc[cb][2] * inv), (short)f2bu(oacc[cb][3] * inv) };
        *(short4v*)&orow[cb*16 + lhi*4] = okv;
    }
}

extern "C" void kernel_launch(void* const* d_in, const int* in_sizes, int n_in,
                              void* d_out, int out_size, void* d_ws, size_t ws_size,
                              hipStream_t stream) {
    const float* x    = (const float*)d_in[0];
    const float* cosb = (const float*)d_in[1];
    const float* sinb = (const float*)d_in[2];
    const float* Wq   = (const float*)d_in[3];
    const float* Wkv  = (const float*)d_in[4];
    const float* Wo   = (const float*)d_in[5];
    const float* ln1g = (const float*)d_in[6];
    const float* ln1b = (const float*)d_in[7];
    const float* ln2g = (const float*)d_in[8];
    const float* ln2b = (const float*)d_in[9];
    const float* W1   = (const float*)d_in[10];
    const float* b1   = (const float*)d_in[11];
    const float* W2   = (const float*)d_in[12];
    const float* b2   = (const float*)d_in[13];
    float* out = (float*)d_out;

    float* ws = (float*)d_ws;
    const size_t M = 1024 * 1024;
    __hip_bfloat16* hb   = (__hip_bfloat16*)(ws);
    __hip_bfloat16* x2b  = (__hip_bfloat16*)(ws + 4*M);    // bf16 residual x2
    __hip_bfloat16* gbuf = (__hip_bfloat16*)(ws + 12*M);
    __hip_bfloat16* ob   = (__hip_bfloat16*)(ws + 20*M);
    __hip_bfloat16* qb   = (__hip_bfloat16*)(ws + 24*M);
    __hip_bfloat16* kbb  = (__hip_bfloat16*)(ws + 28*M);
    __hip_bfloat16* vbt  = (__hip_bfloat16*)(ws + 29*M);
    __hip_bfloat16* Wqkvb= (__hip_bfloat16*)(ws + 30*M);
    __hip_bfloat16* Wob  = (__hip_bfloat16*)(ws + 30*M + 3*M/4);
    __hip_bfloat16* W1b  = (__hip_bfloat16*)(ws + 31*M + M/4);
    __hip_bfloat16* W2b  = (__hip_bfloat16*)(ws + 32*M + M/4);

    // 0+1. weight casts + LN1 fused
    prologue_cast_ln<<<6656 + R_, 256, 0, stream>>>(Wq, Wkv, Wo, W1, W2,
                                                    Wqkvb, Wob, W1b, W2b,
                                                    x, ln1g, ln1b, hb);

    // 2+3. qkv GEMM with fused RoPE -> qb/kbb/vbt (bf16), XCD-swizzled 1D grid (768 blocks)
    gemm_qkv_rope<<<(QKVW/128)*(R_/128), 512, 0, stream>>>(hb, Wqkvb, cosb, sinb, qb, kbb, vbt);
    // 4. attention -> ob (bf16), 8-wave blocks, QBLK=128, 32KB LDS
    attn_mfma<<<dim3(T_/128, B_*QH), 512, 0, stream>>>(qb, kbb, vbt, ob);
    // 5. x2b = x + ob @ Wob^T (bf16 out, 512 blocks)
    gemm_mfma<1><<<(D_/128)*(R_/128), 512, 0, stream>>>(ob, Wob, nullptr, x, nullptr, nullptr, x2b, R_, D_, D_);
    // 6. LN2 (bf16 in) -> hb (bf16)
    ln_bf16_in<<<R_, 256, 0, stream>>>(x2b, ln2g, ln2b, hb);
    // 7. gbuf = gelu(hb @ W1b^T + b1) (bf16 out, 1024 blocks)
    gemm_mfma<2><<<(DFF/128)*(R_/128), 512, 0, stream>>>(hb, W1b, b1, nullptr, nullptr, nullptr, gbuf, R_, DFF, D_);
    // 8. out = x2b + gbuf @ W2b^T + b2 (f32 out, 512 blocks)
    gemm_mfma<3><<<(D_/128)*(R_/128), 512, 0, stream>>>(gbuf, W2b, b2, nullptr, x2b, out, nullptr, R_, D_, DFF);
}